// Round 1
// baseline (4236.790 us; speedup 1.0000x reference)
//
#include <hip/hip_runtime.h>
#include <math.h>

#define DD 256
#define NHEADS 8
#define HHD 32
#define NPTS 4
#define NQQ 900
#define NBS 4
#define NLAYER 6
#define BEVH 200
#define BEVW 200
#define ROWS (NBS*NQQ)   // 3600

__device__ __forceinline__ float sigmoidf_(float x){ return 1.0f/(1.0f+expf(-x)); }
__device__ __forceinline__ float invsigf_(float x){
  x = fminf(fmaxf(x,0.0f),1.0f);
  float lo = fmaxf(x,1e-5f), hi = fmaxf(1.0f-x,1e-5f);
  return logf(lo/hi);
}

// ---------------------------------------------------------------------------
// Generic GEMM: Y[m,n] = act( (A[m,:] (+A2[m,:])) . W[n,:] + B[n] )
// A: M x K row-major, W: N x K row-major (torch Linear weight), Y ld = ldy.
// act: 0 none, 1 relu, 2 sigmoid
// ---------------------------------------------------------------------------
__global__ __launch_bounds__(256) void gemm_k(
    const float* __restrict__ A, const float* __restrict__ A2,
    const float* __restrict__ W, const float* __restrict__ B,
    float* __restrict__ Y, int M, int N, int K, int ldy, int act)
{
  __shared__ float As[16][68];
  __shared__ float Ws[16][68];
  const int t = threadIdx.x;
  const int m0 = blockIdx.x*64, n0 = blockIdx.y*64;
  const int lrow = t>>2, lk = (t&3)<<2;
  const int tx = t&15, ty = t>>4;
  float acc[4][4] = {};
  const bool aok = (m0+lrow) < M;
  const bool wok = (n0+lrow) < N;
  const float* ap  = A + (size_t)(m0+lrow)*K + lk;
  const float* a2p = A2 ? (A2 + (size_t)(m0+lrow)*K + lk) : (const float*)0;
  const float* wp  = W + (size_t)(n0+lrow)*K + lk;
  for (int k0=0; k0<K; k0+=16) {
    float4 av = {0,0,0,0}, wv = {0,0,0,0};
    if (aok) {
      av = *(const float4*)(ap+k0);
      if (a2p) { float4 a2 = *(const float4*)(a2p+k0); av.x+=a2.x; av.y+=a2.y; av.z+=a2.z; av.w+=a2.w; }
    }
    if (wok) wv = *(const float4*)(wp+k0);
    __syncthreads();
    As[lk+0][lrow]=av.x; As[lk+1][lrow]=av.y; As[lk+2][lrow]=av.z; As[lk+3][lrow]=av.w;
    Ws[lk+0][lrow]=wv.x; Ws[lk+1][lrow]=wv.y; Ws[lk+2][lrow]=wv.z; Ws[lk+3][lrow]=wv.w;
    __syncthreads();
    #pragma unroll
    for (int k=0;k<16;++k) {
      const float4 a4 = *(const float4*)&As[k][ty<<2];
      const float4 b4 = *(const float4*)&Ws[k][tx<<2];
      const float xa[4] = {a4.x,a4.y,a4.z,a4.w};
      const float xb[4] = {b4.x,b4.y,b4.z,b4.w};
      #pragma unroll
      for (int r=0;r<4;++r)
        #pragma unroll
        for (int c=0;c<4;++c) acc[r][c] += xa[r]*xb[c];
    }
  }
  #pragma unroll
  for (int r=0;r<4;++r) {
    const int gm = m0 + (ty<<2) + r;
    if (gm >= M) continue;
    #pragma unroll
    for (int c=0;c<4;++c) {
      const int gn = n0 + (tx<<2) + c;
      if (gn >= N) continue;
      float v = acc[r][c] + (B ? B[gn] : 0.0f);
      if (act==1) v = fmaxf(v, 0.0f);
      else if (act==2) v = 1.0f/(1.0f+expf(-v));
      Y[(size_t)gm*ldy + gn] = v;
    }
  }
}

// ---------------------------------------------------------------------------
// Flash-style MHA: thread-per-query-row, K/V chunks of 64 staged in LDS.
// QK buffer: rows (b*900+n), 512 wide: [0:256]=Q, [256:512]=K (head-major).
// V buffer: rows 256 wide. O: rows 256 wide (b,n,h,d).
// ---------------------------------------------------------------------------
__global__ __launch_bounds__(256) void attn_k(
    const float* __restrict__ QK, const float* __restrict__ V, float* __restrict__ O)
{
  const int bh = blockIdx.x; const int b = bh>>3, h = bh&7;
  const int qi = blockIdx.y*256 + threadIdx.x;
  const bool active = qi < NQQ;
  __shared__ float Ks[64][36];
  __shared__ float Vs[64][36];
  float Qr[32], Or[32];
  float m = -1e30f, l = 0.0f;
  const float* qp = QK + (size_t)(b*NQQ + (active?qi:0))*512 + h*32;
  #pragma unroll
  for (int j=0;j<32;j+=4){ float4 v4 = *(const float4*)(qp+j); Qr[j]=v4.x; Qr[j+1]=v4.y; Qr[j+2]=v4.z; Qr[j+3]=v4.w; }
  #pragma unroll
  for (int j=0;j<32;++j) Or[j]=0.0f;
  const int kr = threadIdx.x>>2, kc = (threadIdx.x&3)<<3;
  for (int k0=0;k0<NQQ;k0+=64) {
    const int len = min(64, NQQ-k0);
    __syncthreads();
    if (kr < len) {
      const float* kp = QK + (size_t)(b*NQQ + k0 + kr)*512 + 256 + h*32 + kc;
      const float* vp = V  + (size_t)(b*NQQ + k0 + kr)*256 + h*32 + kc;
      *(float4*)&Ks[kr][kc]   = *(const float4*)kp;
      *(float4*)&Ks[kr][kc+4] = *(const float4*)(kp+4);
      *(float4*)&Vs[kr][kc]   = *(const float4*)vp;
      *(float4*)&Vs[kr][kc+4] = *(const float4*)(vp+4);
    }
    __syncthreads();
    if (active) {
      for (int kk=0;kk<len;++kk) {
        float s = 0.0f;
        #pragma unroll
        for (int j=0;j<32;++j) s += Qr[j]*Ks[kk][j];
        s *= 0.17677669529663687f;   // 1/sqrt(32)
        const float mn = fmaxf(m, s);
        const float corr = __expf(m - mn);
        const float p = __expf(s - mn);
        l = l*corr + p;
        #pragma unroll
        for (int j=0;j<32;++j) Or[j] = Or[j]*corr + p*Vs[kk][j];
        m = mn;
      }
    }
  }
  if (active) {
    const float inv = 1.0f/l;
    float* op = O + (size_t)(b*NQQ+qi)*256 + h*32;
    #pragma unroll
    for (int j=0;j<32;j+=4){
      float4 v4; v4.x=Or[j]*inv; v4.y=Or[j+1]*inv; v4.z=Or[j+2]*inv; v4.w=Or[j+3]*inv;
      *(float4*)(op+j)=v4;
    }
  }
}

// ---------------------------------------------------------------------------
// LayerNorm over 256, wave per row. Y = act( LN(X (+R)) * w + b ). X/Y may alias.
// ---------------------------------------------------------------------------
__global__ __launch_bounds__(256) void ln_k(
    const float* X, const float* R,
    const float* __restrict__ w, const float* __restrict__ b, float* Y, int relu)
{
  const int row = blockIdx.x*4 + (threadIdx.x>>6);
  const int lane = threadIdx.x & 63;
  if (row >= ROWS) return;
  float4 x = *(const float4*)(X + (size_t)row*256 + (lane<<2));
  if (R) { const float4 r = *(const float4*)(R + (size_t)row*256 + (lane<<2)); x.x+=r.x; x.y+=r.y; x.z+=r.z; x.w+=r.w; }
  float s = x.x+x.y+x.z+x.w;
  #pragma unroll
  for (int o=32;o>0;o>>=1) s += __shfl_xor(s,o);
  const float mean = s * (1.0f/256.0f);
  float4 d; d.x=x.x-mean; d.y=x.y-mean; d.z=x.z-mean; d.w=x.w-mean;
  float s2 = d.x*d.x+d.y*d.y+d.z*d.z+d.w*d.w;
  #pragma unroll
  for (int o=32;o>0;o>>=1) s2 += __shfl_xor(s2,o);
  const float rs = rsqrtf(s2*(1.0f/256.0f) + 1e-5f);
  const float4 wv = *(const float4*)(w + (lane<<2));
  const float4 bv = *(const float4*)(b + (lane<<2));
  float4 y;
  y.x = d.x*rs*wv.x + bv.x; y.y = d.y*rs*wv.y + bv.y;
  y.z = d.z*rs*wv.z + bv.z; y.w = d.w*rs*wv.w + bv.w;
  if (relu) { y.x=fmaxf(y.x,0.f); y.y=fmaxf(y.y,0.f); y.z=fmaxf(y.z,0.f); y.w=fmaxf(y.w,0.f); }
  *(float4*)(Y + (size_t)row*256 + (lane<<2)) = y;
}

// ---------------------------------------------------------------------------
// Deformable sampling. Block per (b,q), wave per head.
// Linearity trick: accumulate rr[k] = sum_{p,corner} aw_p * w_c * bev[lin,k],
// s = sum of the weights; out32 = Wv_head . rr + vp_b_head * s.
// ---------------------------------------------------------------------------
__global__ __launch_bounds__(512) void deform_k(
    const float* __restrict__ bev, const float* __restrict__ offb,
    const float* __restrict__ awb, const float* __restrict__ ref,
    const float* __restrict__ vpw, const float* __restrict__ vpb,
    float* __restrict__ samp)
{
  const int row = blockIdx.x;          // b*900+q
  const int b = row / NQQ;
  const int h = threadIdx.x >> 6;
  const int lane = threadIdx.x & 63;
  __shared__ float rr[8][260];
  const float refx = ref[row*3+0], refy = ref[row*3+1];
  // attention-weight softmax over 4 points (redundant across lanes)
  float aw[4];
  {
    const float* apt = awb + (size_t)row*32 + h*4;
    float a0=apt[0], a1=apt[1], a2=apt[2], a3=apt[3];
    float mx = fmaxf(fmaxf(a0,a1), fmaxf(a2,a3));
    float e0=expf(a0-mx), e1=expf(a1-mx), e2=expf(a2-mx), e3=expf(a3-mx);
    float inv = 1.0f/(e0+e1+e2+e3);
    aw[0]=e0*inv; aw[1]=e1*inv; aw[2]=e2*inv; aw[3]=e3*inv;
  }
  float racc0=0.f, racc1=0.f, racc2=0.f, racc3=0.f;
  float sacc = 0.f;
  const float* bevb = bev + (size_t)b*BEVH*BEVW*DD;
  #pragma unroll
  for (int p=0;p<NPTS;++p) {
    const float ox = offb[(size_t)row*64 + h*8 + p*2 + 0];
    const float oy = offb[(size_t)row*64 + h*8 + p*2 + 1];
    const float x = (refx + ox*(1.0f/BEVW))*BEVW - 0.5f;
    const float y = (refy + oy*(1.0f/BEVH))*BEVH - 0.5f;
    const float x0f = floorf(x), y0f = floorf(y);
    const int x0 = (int)x0f, y0 = (int)y0f;
    const float fx = x - x0f, fy = y - y0f;
    #pragma unroll
    for (int dy=0;dy<2;++dy) {
      #pragma unroll
      for (int dx=0;dx<2;++dx) {
        const int xi = x0+dx, yi = y0+dy;
        if (xi < 0 || xi >= BEVW || yi < 0 || yi >= BEVH) continue; // uniform per wave
        const float wgt = (dx ? fx : 1.0f-fx) * (dy ? fy : 1.0f-fy) * aw[p];
        const float* gp = bevb + (size_t)(yi*BEVW + xi)*DD + (lane<<2);
        const float4 g = *(const float4*)gp;
        racc0 += wgt*g.x; racc1 += wgt*g.y; racc2 += wgt*g.z; racc3 += wgt*g.w;
        sacc += wgt;
      }
    }
  }
  rr[h][(lane<<2)+0]=racc0; rr[h][(lane<<2)+1]=racc1;
  rr[h][(lane<<2)+2]=racc2; rr[h][(lane<<2)+3]=racc3;
  __syncthreads();
  // projection: out[c] = Wv[h*32+c,:] . rr  (lane = c + 32*half, halves split K)
  const int c = lane & 31, half = lane >> 5;
  const float* wp = vpw + (size_t)(h*32+c)*DD + half*128;
  const float* rp = &rr[h][half*128];
  float acc = 0.f;
  #pragma unroll
  for (int j=0;j<128;j+=4) {
    const float4 wv4 = *(const float4*)(wp+j);
    acc += wv4.x*rp[j] + wv4.y*rp[j+1] + wv4.z*rp[j+2] + wv4.w*rp[j+3];
  }
  acc += __shfl_xor(acc, 32);
  if (lane < 32) samp[(size_t)row*256 + h*32 + c] = acc + vpb[h*32+c]*sacc;
}

// ---------------------------------------------------------------------------
// ref update + coord output for layer i
// ---------------------------------------------------------------------------
__global__ void refout_k(const float* __restrict__ tmp, float* __restrict__ ref,
                         float* __restrict__ outL)
{
  const int r = blockIdx.x*blockDim.x + threadIdx.x;
  if (r >= ROWS) return;
  const float* t = tmp + (size_t)r*10;
  const float rx = invsigf_(ref[r*3+0]);
  const float ry = invsigf_(ref[r*3+1]);
  const float rz = invsigf_(ref[r*3+2]);
  const float nx = sigmoidf_(t[0]+rx);
  const float ny = sigmoidf_(t[1]+ry);
  const float nz = sigmoidf_(t[4]+rz);
  ref[r*3+0]=nx; ref[r*3+1]=ny; ref[r*3+2]=nz;
  float* o = outL + (size_t)r*20 + 10;
  o[0]=nx*102.4f-51.2f; o[1]=ny*102.4f-51.2f; o[2]=t[2]; o[3]=t[3];
  o[4]=nz*8.0f-5.0f; o[5]=t[5]; o[6]=t[6]; o[7]=t[7]; o[8]=t[8]; o[9]=t[9];
}

// broadcast query_embed -> qpos (first 256) and q (last 256) over batch
__global__ void init_k(const float* __restrict__ qe, float* __restrict__ qpos, float* __restrict__ q)
{
  const int t = blockIdx.x*blockDim.x + threadIdx.x;   // 0 .. 3600*64-1
  const int row = t >> 6; const int cc = (t & 63) << 2;
  const int n = row % NQQ;
  *(float4*)(qpos + (size_t)row*256 + cc) = *(const float4*)(qe + (size_t)n*512 + cc);
  *(float4*)(q    + (size_t)row*256 + cc) = *(const float4*)(qe + (size_t)n*512 + 256 + cc);
}

extern "C" void kernel_launch(void* const* d_in, const int* in_sizes, int n_in,
                              void* d_out, int out_size, void* d_ws, size_t ws_size,
                              hipStream_t stream)
{
  const float* bev      = (const float*)d_in[0];
  const float* qe       = (const float*)d_in[1];
  const float* ref_w    = (const float*)d_in[2];
  const float* ref_b    = (const float*)d_in[3];
  const float* sa_in_w  = (const float*)d_in[4];
  const float* sa_in_b  = (const float*)d_in[5];
  const float* sa_out_w = (const float*)d_in[6];
  const float* sa_out_b = (const float*)d_in[7];
  const float* ln_w     = (const float*)d_in[8];
  const float* ln_b     = (const float*)d_in[9];
  const float* off_w    = (const float*)d_in[10];
  const float* off_b    = (const float*)d_in[11];
  const float* aw_w     = (const float*)d_in[12];
  const float* aw_b     = (const float*)d_in[13];
  const float* vproj_w  = (const float*)d_in[14];
  const float* vproj_b  = (const float*)d_in[15];
  const float* oproj_w  = (const float*)d_in[16];
  const float* oproj_b  = (const float*)d_in[17];
  const float* ffn_w1   = (const float*)d_in[18];
  const float* ffn_b1   = (const float*)d_in[19];
  const float* ffn_w2   = (const float*)d_in[20];
  const float* ffn_b2   = (const float*)d_in[21];
  const float* reg_w1   = (const float*)d_in[22];
  const float* reg_b1   = (const float*)d_in[23];
  const float* reg_w2   = (const float*)d_in[24];
  const float* reg_b2   = (const float*)d_in[25];
  const float* reg_w3   = (const float*)d_in[26];
  const float* reg_b3   = (const float*)d_in[27];
  const float* cls_w1   = (const float*)d_in[28];
  const float* cls_b1   = (const float*)d_in[29];
  const float* cls_w2   = (const float*)d_in[30];
  const float* cls_b2   = (const float*)d_in[31];
  const float* cls_w3   = (const float*)d_in[32];
  const float* cls_b3   = (const float*)d_in[33];
  const float* cls_ln_w = (const float*)d_in[34];
  const float* cls_ln_b = (const float*)d_in[35];
  float* out = (float*)d_out;

  float* ws = (float*)d_ws;
  float* qpos  = ws;                  // 3600x256
  float* q     = ws + 921600;         // 3600x256
  float* t0    = ws + 1843200;        // 3600x256
  float* QK    = ws + 2764800;        // 3600x512
  float* Vb    = ws + 4608000;        // 3600x256
  float* h512  = ws + 5529600;        // 3600x512
  float* offb  = ws + 7372800;        // 3600x64
  float* awb   = ws + 7603200;        // 3600x32
  float* samp  = ws + 7718400;        // 3600x256
  float* r1    = ws + 8640000;        // 3600x256
  float* r2    = ws + 9561600;        // 3600x256
  float* tmp10 = ws + 10483200;       // 3600x10
  float* ref   = ws + 10519200;       // 3600x3

  auto gemm = [&](const float* A, const float* A2, const float* W, const float* B,
                  float* Y, int M, int N, int K, int ldy, int act) {
    dim3 grid((M+63)/64, (N+63)/64);
    gemm_k<<<grid, 256, 0, stream>>>(A, A2, W, B, Y, M, N, K, ldy, act);
  };

  init_k<<<900, 256, 0, stream>>>(qe, qpos, q);
  gemm(qpos, nullptr, ref_w, ref_b, ref, ROWS, 3, 256, 3, 2);  // sigmoid

  for (int i=0;i<NLAYER;++i) {
    const float* siw = sa_in_w + (size_t)i*768*256;
    const float* sib = sa_in_b + (size_t)i*768;
    // ---- self-attention ----
    gemm(q, qpos, siw, sib, QK, ROWS, 512, 256, 512, 0);              // Q|K
    gemm(q, nullptr, siw + 512*256, sib + 512, Vb, ROWS, 256, 256, 256, 0); // V
    attn_k<<<dim3(32,4), 256, 0, stream>>>(QK, Vb, t0);
    gemm(t0, nullptr, sa_out_w + (size_t)i*65536, sa_out_b + (size_t)i*256, r1, ROWS, 256, 256, 256, 0);
    ln_k<<<900, 256, 0, stream>>>(r1, q, ln_w + (size_t)(i*3+0)*256, ln_b + (size_t)(i*3+0)*256, q, 0);
    // ---- deformable cross-attention ----
    gemm(q, qpos, off_w + (size_t)i*64*256, off_b + (size_t)i*64, offb, ROWS, 64, 256, 64, 0);
    gemm(q, qpos, aw_w + (size_t)i*32*256, aw_b + (size_t)i*32, awb, ROWS, 32, 256, 32, 0);
    deform_k<<<ROWS, 512, 0, stream>>>(bev, offb, awb, ref,
        vproj_w + (size_t)i*65536, vproj_b + (size_t)i*256, samp);
    gemm(samp, nullptr, oproj_w + (size_t)i*65536, oproj_b + (size_t)i*256, t0, ROWS, 256, 256, 256, 0);
    ln_k<<<900, 256, 0, stream>>>(t0, q, ln_w + (size_t)(i*3+1)*256, ln_b + (size_t)(i*3+1)*256, q, 0);
    // ---- FFN ----
    gemm(q, nullptr, ffn_w1 + (size_t)i*512*256, ffn_b1 + (size_t)i*512, h512, ROWS, 512, 256, 512, 1);
    gemm(h512, nullptr, ffn_w2 + (size_t)i*256*512, ffn_b2 + (size_t)i*256, t0, ROWS, 256, 512, 256, 0);
    ln_k<<<900, 256, 0, stream>>>(t0, q, ln_w + (size_t)(i*3+2)*256, ln_b + (size_t)(i*3+2)*256, q, 0);
    // ---- reg branch (used for ref update AND output coords) ----
    gemm(q, nullptr, reg_w1 + (size_t)i*65536, reg_b1 + (size_t)i*256, r1, ROWS, 256, 256, 256, 1);
    gemm(r1, nullptr, reg_w2 + (size_t)i*65536, reg_b2 + (size_t)i*256, r2, ROWS, 256, 256, 256, 1);
    gemm(r2, nullptr, reg_w3 + (size_t)i*2560, reg_b3 + (size_t)i*10, tmp10, ROWS, 10, 256, 10, 0);
    refout_k<<<(ROWS+255)/256, 256, 0, stream>>>(tmp10, ref, out + (size_t)i*ROWS*20);
    // ---- cls branch ----
    gemm(q, nullptr, cls_w1 + (size_t)i*65536, cls_b1 + (size_t)i*256, t0, ROWS, 256, 256, 256, 0);
    ln_k<<<900, 256, 0, stream>>>(t0, nullptr, cls_ln_w + (size_t)(i*2+0)*256, cls_ln_b + (size_t)(i*2+0)*256, t0, 1);
    gemm(t0, nullptr, cls_w2 + (size_t)i*65536, cls_b2 + (size_t)i*256, r1, ROWS, 256, 256, 256, 0);
    ln_k<<<900, 256, 0, stream>>>(r1, nullptr, cls_ln_w + (size_t)(i*2+1)*256, cls_ln_b + (size_t)(i*2+1)*256, r1, 1);
    gemm(r1, nullptr, cls_w3 + (size_t)i*2560, cls_b3 + (size_t)i*10, out + (size_t)i*ROWS*20, ROWS, 10, 256, 20, 0);
  }
}

// Round 2
// 4109.129 us; speedup vs baseline: 1.0311x; 1.0311x over previous
//
#include <hip/hip_runtime.h>
#include <math.h>

#define DD 256
#define NQQ 900
#define NBS 4
#define NLAYER 6
#define BEVH 200
#define BEVW 200
#define ROWS (NBS*NQQ)   // 3600

__device__ __forceinline__ float sigmoidf_(float x){ return 1.0f/(1.0f+expf(-x)); }
__device__ __forceinline__ float invsigf_(float x){
  x = fminf(fmaxf(x,0.0f),1.0f);
  float lo = fmaxf(x,1e-5f), hi = fmaxf(1.0f-x,1e-5f);
  return logf(lo/hi);
}

// ---------------------------------------------------------------------------
// GEMM: Y[m,n] = act( (A[m,:] (+A2[m,:])) . W[n,:] + B[n] )
// 64x64 tile, 128 threads (2 waves), 4x8 per thread, K-chunk 32, dbuf LDS.
// act: 0 none, 1 relu, 2 sigmoid, 3 relu only on n<256
// ---------------------------------------------------------------------------
__global__ __launch_bounds__(128) void gemm_k(
    const float* __restrict__ A, int lda, const float* __restrict__ A2,
    const float* __restrict__ W, const float* __restrict__ B,
    float* __restrict__ Y, int M, int N, int K, int ldy, int act)
{
  __shared__ float As[2][32][68];
  __shared__ float Ws[2][32][68];
  const int t = threadIdx.x;
  const int m0 = blockIdx.x*64, n0 = blockIdx.y*64;
  const int lr = t >> 1, kb4 = (t & 1) << 4;   // loader: row 0..63, k 0/16
  const int tx = t & 7, ty = t >> 3;           // compute: n-grp 0..7, m-grp 0..15
  const bool aok = (m0 + lr) < M;
  const bool wok = (n0 + lr) < N;
  const float* ap  = A + (size_t)(m0+lr)*lda + kb4;
  const float* a2p = A2 ? A2 + (size_t)(m0+lr)*256 + kb4 : (const float*)0;
  const float* wp  = W + (size_t)(n0+lr)*K + kb4;
  float4 pa[4], pw[4];

  auto loadch = [&](int kc) {
    #pragma unroll
    for (int i=0;i<4;++i) {
      pa[i] = aok ? *(const float4*)(ap + kc + i*4) : make_float4(0,0,0,0);
      pw[i] = wok ? *(const float4*)(wp + kc + i*4) : make_float4(0,0,0,0);
    }
    if (a2p && aok) {
      #pragma unroll
      for (int i=0;i<4;++i) {
        float4 x = *(const float4*)(a2p + kc + i*4);
        pa[i].x+=x.x; pa[i].y+=x.y; pa[i].z+=x.z; pa[i].w+=x.w;
      }
    }
  };
  auto storech = [&](int bf) {
    #pragma unroll
    for (int i=0;i<4;++i) {
      const int kk = kb4 + i*4;
      As[bf][kk+0][lr]=pa[i].x; As[bf][kk+1][lr]=pa[i].y;
      As[bf][kk+2][lr]=pa[i].z; As[bf][kk+3][lr]=pa[i].w;
      Ws[bf][kk+0][lr]=pw[i].x; Ws[bf][kk+1][lr]=pw[i].y;
      Ws[bf][kk+2][lr]=pw[i].z; Ws[bf][kk+3][lr]=pw[i].w;
    }
  };

  float acc[4][8] = {};
  loadch(0); storech(0); __syncthreads();
  const int NC = K >> 5;
  for (int c=0; c<NC; ++c) {
    if (c+1 < NC) loadch((c+1) << 5);
    const int bf = c & 1;
    #pragma unroll
    for (int k=0;k<32;++k) {
      const float4 a4  = *(const float4*)&As[bf][k][ty<<2];
      const float4 w4a = *(const float4*)&Ws[bf][k][tx<<3];
      const float4 w4b = *(const float4*)&Ws[bf][k][(tx<<3)+4];
      const float av[4] = {a4.x,a4.y,a4.z,a4.w};
      const float wv[8] = {w4a.x,w4a.y,w4a.z,w4a.w,w4b.x,w4b.y,w4b.z,w4b.w};
      #pragma unroll
      for (int r=0;r<4;++r)
        #pragma unroll
        for (int cc=0;cc<8;++cc) acc[r][cc] += av[r]*wv[cc];
    }
    if (c+1 < NC) storech((c+1)&1);
    __syncthreads();
  }
  #pragma unroll
  for (int r=0;r<4;++r) {
    const int gm = m0 + (ty<<2) + r;
    if (gm >= M) continue;
    #pragma unroll
    for (int cc=0;cc<8;++cc) {
      const int gn = n0 + (tx<<3) + cc;
      if (gn >= N) continue;
      float v = acc[r][cc] + (B ? B[gn] : 0.0f);
      if (act==1 || (act==3 && gn<256)) v = fmaxf(v,0.0f);
      else if (act==2) v = sigmoidf_(v);
      Y[(size_t)gm*ldy + gn] = v;
    }
  }
}

// ---------------------------------------------------------------------------
// MHA v2: grid (32 bh, 8 qg); block 256 = 4 waves = 4 key-splits of 225 keys.
// Each lane owns 2 queries (q0=qg*128+lane, q1=q0+64); Q,O in registers.
// K/V rows read with wave-uniform addresses (broadcast / scalarizable).
// In-block split combine via small LDS (wave-sequential weighted adds).
// ---------------------------------------------------------------------------
__global__ __launch_bounds__(256, 1) void attn2_k(
    const float* __restrict__ QK, const float* __restrict__ V, float* __restrict__ O)
{
  const int b = blockIdx.x >> 3, h = blockIdx.x & 7;
  const int qg = blockIdx.y;
  const int wv = threadIdx.x >> 6, lane = threadIdx.x & 63;
  const int t = threadIdx.x;
  __shared__ float pm[4][128];
  __shared__ float pl[4][128];
  __shared__ float oacc[128][36];

  const int q0 = qg*128 + lane, q1 = q0 + 64;
  const float* qb = QK + (size_t)b*NQQ*512 + h*32;
  float Q0[32], Q1[32], O0[32], O1[32];
  {
    const int i0 = (q0 < NQQ ? q0 : 0), i1 = (q1 < NQQ ? q1 : 0);
    #pragma unroll
    for (int j=0;j<32;j+=4) {
      *(float4*)&Q0[j] = *(const float4*)(qb + (size_t)i0*512 + j);
      *(float4*)&Q1[j] = *(const float4*)(qb + (size_t)i1*512 + j);
      O0[j]=O0[j+1]=O0[j+2]=O0[j+3]=0.0f;
      O1[j]=O1[j+1]=O1[j+2]=O1[j+3]=0.0f;
    }
  }
  float m0=-3e38f, m1=-3e38f, l0=0.0f, l1=0.0f;
  const float* kb = QK + (size_t)b*NQQ*512 + 256 + h*32;
  const float* vb = V  + (size_t)b*NQQ*256 + h*32;
  const int ks = wv*225, ke = ks + 225;
  #pragma unroll 2
  for (int kk=ks; kk<ke; ++kk) {
    float Kv[32];
    #pragma unroll
    for (int j=0;j<32;j+=4) *(float4*)&Kv[j] = *(const float4*)(kb + (size_t)kk*512 + j);
    float a0=0,a1=0,a2=0,a3=0, c0=0,c1=0,c2=0,c3=0;
    #pragma unroll
    for (int j=0;j<32;j+=4) {
      a0 += Q0[j+0]*Kv[j+0]; a1 += Q0[j+1]*Kv[j+1];
      a2 += Q0[j+2]*Kv[j+2]; a3 += Q0[j+3]*Kv[j+3];
      c0 += Q1[j+0]*Kv[j+0]; c1 += Q1[j+1]*Kv[j+1];
      c2 += Q1[j+2]*Kv[j+2]; c3 += Q1[j+3]*Kv[j+3];
    }
    const float s0 = (a0+a1+a2+a3)*0.17677669529663687f;
    const float s1 = (c0+c1+c2+c3)*0.17677669529663687f;
    float Vv[32];
    #pragma unroll
    for (int j=0;j<32;j+=4) *(float4*)&Vv[j] = *(const float4*)(vb + (size_t)kk*256 + j);
    const float mn0 = fmaxf(m0,s0), mn1 = fmaxf(m1,s1);
    const float cr0 = __expf(m0-mn0), p0 = __expf(s0-mn0);
    const float cr1 = __expf(m1-mn1), p1 = __expf(s1-mn1);
    l0 = l0*cr0 + p0; l1 = l1*cr1 + p1; m0 = mn0; m1 = mn1;
    #pragma unroll
    for (int j=0;j<32;++j) {
      O0[j] = O0[j]*cr0 + p0*Vv[j];
      O1[j] = O1[j]*cr1 + p1*Vv[j];
    }
  }
  pm[wv][lane] = m0; pm[wv][lane+64] = m1;
  pl[wv][lane] = l0; pl[wv][lane+64] = l1;
  for (int j=t; j<128*36; j+=256) ((float*)oacc)[j] = 0.0f;
  __syncthreads();
  const float mm0 = fmaxf(fmaxf(pm[0][lane],pm[1][lane]),fmaxf(pm[2][lane],pm[3][lane]));
  const float mm1 = fmaxf(fmaxf(pm[0][lane+64],pm[1][lane+64]),fmaxf(pm[2][lane+64],pm[3][lane+64]));
  const float w0 = __expf(m0 - mm0), w1 = __expf(m1 - mm1);
  #pragma unroll
  for (int s=0;s<4;++s) {
    if (wv == s) {
      #pragma unroll
      for (int j=0;j<32;++j) {
        oacc[lane][j]    += w0*O0[j];
        oacc[lane+64][j] += w1*O1[j];
      }
    }
    __syncthreads();
  }
  if (t < 128) {
    const int q = qg*128 + t;
    if (q < NQQ) {
      const float mm = fmaxf(fmaxf(pm[0][t],pm[1][t]),fmaxf(pm[2][t],pm[3][t]));
      const float e0=__expf(pm[0][t]-mm), e1=__expf(pm[1][t]-mm),
                  e2=__expf(pm[2][t]-mm), e3=__expf(pm[3][t]-mm);
      const float ll = e0*pl[0][t]+e1*pl[1][t]+e2*pl[2][t]+e3*pl[3][t];
      const float inv = 1.0f/ll;
      float* op = O + ((size_t)b*NQQ + q)*256 + h*32;
      #pragma unroll
      for (int j=0;j<32;j+=4) {
        float4 r;
        r.x = oacc[t][j+0]*inv; r.y = oacc[t][j+1]*inv;
        r.z = oacc[t][j+2]*inv; r.w = oacc[t][j+3]*inv;
        *(float4*)(op+j) = r;
      }
    }
  }
}

// ---------------------------------------------------------------------------
// LayerNorm over 256, wave per row. Y = act( LN(X (+R)) * w + b ).
// ---------------------------------------------------------------------------
__global__ __launch_bounds__(256) void ln_k(
    const float* X, int xld, const float* R,
    const float* __restrict__ w, const float* __restrict__ b, float* Y, int relu)
{
  const int row = blockIdx.x*4 + (threadIdx.x>>6);
  const int lane = threadIdx.x & 63;
  if (row >= ROWS) return;
  float4 x = *(const float4*)(X + (size_t)row*xld + (lane<<2));
  if (R) { const float4 r = *(const float4*)(R + (size_t)row*256 + (lane<<2)); x.x+=r.x; x.y+=r.y; x.z+=r.z; x.w+=r.w; }
  float s = x.x+x.y+x.z+x.w;
  #pragma unroll
  for (int o=32;o>0;o>>=1) s += __shfl_xor(s,o);
  const float mean = s * (1.0f/256.0f);
  float4 d; d.x=x.x-mean; d.y=x.y-mean; d.z=x.z-mean; d.w=x.w-mean;
  float s2 = d.x*d.x+d.y*d.y+d.z*d.z+d.w*d.w;
  #pragma unroll
  for (int o=32;o>0;o>>=1) s2 += __shfl_xor(s2,o);
  const float rs = rsqrtf(s2*(1.0f/256.0f) + 1e-5f);
  const float4 wv = *(const float4*)(w + (lane<<2));
  const float4 bv = *(const float4*)(b + (lane<<2));
  float4 y;
  y.x = d.x*rs*wv.x + bv.x; y.y = d.y*rs*wv.y + bv.y;
  y.z = d.z*rs*wv.z + bv.z; y.w = d.w*rs*wv.w + bv.w;
  if (relu) { y.x=fmaxf(y.x,0.f); y.y=fmaxf(y.y,0.f); y.z=fmaxf(y.z,0.f); y.w=fmaxf(y.w,0.f); }
  *(float4*)(Y + (size_t)row*256 + (lane<<2)) = y;
}

// ---------------------------------------------------------------------------
// Deformable sampling (linearity trick). Block per (b,q), wave per head.
// offaw: per row 96 floats = 64 offsets | 32 aw logits.
// ---------------------------------------------------------------------------
__global__ __launch_bounds__(512) void deform_k(
    const float* __restrict__ bev, const float* __restrict__ offaw,
    const float* __restrict__ ref,
    const float* __restrict__ vpw, const float* __restrict__ vpb,
    float* __restrict__ samp)
{
  const int row = blockIdx.x;          // b*900+q
  const int b = row / NQQ;
  const int h = threadIdx.x >> 6;
  const int lane = threadIdx.x & 63;
  __shared__ float rr[8][260];
  const float refx = ref[row*3+0], refy = ref[row*3+1];
  float aw[4];
  {
    const float* apt = offaw + (size_t)row*96 + 64 + h*4;
    float a0=apt[0], a1=apt[1], a2=apt[2], a3=apt[3];
    float mx = fmaxf(fmaxf(a0,a1), fmaxf(a2,a3));
    float e0=expf(a0-mx), e1=expf(a1-mx), e2=expf(a2-mx), e3=expf(a3-mx);
    float inv = 1.0f/(e0+e1+e2+e3);
    aw[0]=e0*inv; aw[1]=e1*inv; aw[2]=e2*inv; aw[3]=e3*inv;
  }
  float racc0=0.f, racc1=0.f, racc2=0.f, racc3=0.f;
  float sacc = 0.f;
  const float* bevb = bev + (size_t)b*BEVH*BEVW*DD;
  #pragma unroll
  for (int p=0;p<4;++p) {
    const float ox = offaw[(size_t)row*96 + h*8 + p*2 + 0];
    const float oy = offaw[(size_t)row*96 + h*8 + p*2 + 1];
    const float x = (refx + ox*(1.0f/BEVW))*BEVW - 0.5f;
    const float y = (refy + oy*(1.0f/BEVH))*BEVH - 0.5f;
    const float x0f = floorf(x), y0f = floorf(y);
    const int x0 = (int)x0f, y0 = (int)y0f;
    const float fx = x - x0f, fy = y - y0f;
    #pragma unroll
    for (int dy=0;dy<2;++dy) {
      #pragma unroll
      for (int dx=0;dx<2;++dx) {
        const int xi = x0+dx, yi = y0+dy;
        if (xi < 0 || xi >= BEVW || yi < 0 || yi >= BEVH) continue;
        const float wgt = (dx ? fx : 1.0f-fx) * (dy ? fy : 1.0f-fy) * aw[p];
        const float* gp = bevb + (size_t)(yi*BEVW + xi)*DD + (lane<<2);
        const float4 g = *(const float4*)gp;
        racc0 += wgt*g.x; racc1 += wgt*g.y; racc2 += wgt*g.z; racc3 += wgt*g.w;
        sacc += wgt;
      }
    }
  }
  rr[h][(lane<<2)+0]=racc0; rr[h][(lane<<2)+1]=racc1;
  rr[h][(lane<<2)+2]=racc2; rr[h][(lane<<2)+3]=racc3;
  __syncthreads();
  const int c = lane & 31, half = lane >> 5;
  const float* wp = vpw + (size_t)(h*32+c)*DD + half*128;
  const float* rp = &rr[h][half*128];
  float acc = 0.f;
  #pragma unroll
  for (int j=0;j<128;j+=4) {
    const float4 wv4 = *(const float4*)(wp+j);
    acc += wv4.x*rp[j] + wv4.y*rp[j+1] + wv4.z*rp[j+2] + wv4.w*rp[j+3];
  }
  acc += __shfl_xor(acc, 32);
  if (lane < 32) samp[(size_t)row*256 + h*32 + c] = acc + vpb[h*32+c]*sacc;
}

// ---------------------------------------------------------------------------
// ref update + coord output for layer i
// ---------------------------------------------------------------------------
__global__ void refout_k(const float* __restrict__ tmp, float* __restrict__ ref,
                         float* __restrict__ outL)
{
  const int r = blockIdx.x*blockDim.x + threadIdx.x;
  if (r >= ROWS) return;
  const float* tt = tmp + (size_t)r*10;
  const float rx = invsigf_(ref[r*3+0]);
  const float ry = invsigf_(ref[r*3+1]);
  const float rz = invsigf_(ref[r*3+2]);
  const float nx = sigmoidf_(tt[0]+rx);
  const float ny = sigmoidf_(tt[1]+ry);
  const float nz = sigmoidf_(tt[4]+rz);
  ref[r*3+0]=nx; ref[r*3+1]=ny; ref[r*3+2]=nz;
  float* o = outL + (size_t)r*20 + 10;
  o[0]=nx*102.4f-51.2f; o[1]=ny*102.4f-51.2f; o[2]=tt[2]; o[3]=tt[3];
  o[4]=nz*8.0f-5.0f; o[5]=tt[5]; o[6]=tt[6]; o[7]=tt[7]; o[8]=tt[8]; o[9]=tt[9];
}

__global__ void init_k(const float* __restrict__ qe, float* __restrict__ qpos, float* __restrict__ q)
{
  const int t = blockIdx.x*blockDim.x + threadIdx.x;   // 0 .. 3600*64-1
  const int row = t >> 6; const int cc = (t & 63) << 2;
  const int n = row % NQQ;
  *(float4*)(qpos + (size_t)row*256 + cc) = *(const float4*)(qe + (size_t)n*512 + cc);
  *(float4*)(q    + (size_t)row*256 + cc) = *(const float4*)(qe + (size_t)n*512 + 256 + cc);
}

// concat off_w|aw_w -> cwA (6x96x256), reg_w1|cls_w1 -> cwB (6x512x256), + biases
__global__ void prep_k(const float* __restrict__ ow, const float* __restrict__ ob,
                       const float* __restrict__ aw, const float* __restrict__ ab,
                       const float* __restrict__ rw, const float* __restrict__ rb,
                       const float* __restrict__ cw, const float* __restrict__ cb,
                       float* cwA, float* cbA, float* cwB, float* cbB)
{
  const int i = blockIdx.x*blockDim.x + threadIdx.x;
  if (i < 6*96*256) {
    const int l = i/(96*256), r = (i/256)%96, k = i%256;
    cwA[i] = (r<64) ? ow[((size_t)l*64 + r)*256 + k] : aw[((size_t)l*32 + (r-64))*256 + k];
  }
  if (i < 576) { const int l = i/96, r = i%96; cbA[i] = (r<64) ? ob[l*64+r] : ab[l*32 + r-64]; }
  if (i < 6*512*256) {
    const int l = i/(512*256), r = (i/256)%512, k = i%256;
    cwB[i] = (r<256) ? rw[((size_t)l*256+r)*256+k] : cw[((size_t)l*256 + (r-256))*256 + k];
  }
  if (i < 3072) { const int l = i/512, r = i%512; cbB[i] = (r<256) ? rb[l*256+r] : cb[l*256 + r-256]; }
}

extern "C" void kernel_launch(void* const* d_in, const int* in_sizes, int n_in,
                              void* d_out, int out_size, void* d_ws, size_t ws_size,
                              hipStream_t stream)
{
  const float* bev      = (const float*)d_in[0];
  const float* qe       = (const float*)d_in[1];
  const float* ref_w    = (const float*)d_in[2];
  const float* ref_b    = (const float*)d_in[3];
  const float* sa_in_w  = (const float*)d_in[4];
  const float* sa_in_b  = (const float*)d_in[5];
  const float* sa_out_w = (const float*)d_in[6];
  const float* sa_out_b = (const float*)d_in[7];
  const float* ln_w     = (const float*)d_in[8];
  const float* ln_b     = (const float*)d_in[9];
  const float* off_w    = (const float*)d_in[10];
  const float* off_b    = (const float*)d_in[11];
  const float* aw_w     = (const float*)d_in[12];
  const float* aw_b     = (const float*)d_in[13];
  const float* vproj_w  = (const float*)d_in[14];
  const float* vproj_b  = (const float*)d_in[15];
  const float* oproj_w  = (const float*)d_in[16];
  const float* oproj_b  = (const float*)d_in[17];
  const float* ffn_w1   = (const float*)d_in[18];
  const float* ffn_b1   = (const float*)d_in[19];
  const float* ffn_w2   = (const float*)d_in[20];
  const float* ffn_b2   = (const float*)d_in[21];
  const float* reg_w1   = (const float*)d_in[22];
  const float* reg_b1   = (const float*)d_in[23];
  const float* reg_w2   = (const float*)d_in[24];
  const float* reg_b2   = (const float*)d_in[25];
  const float* reg_w3   = (const float*)d_in[26];
  const float* reg_b3   = (const float*)d_in[27];
  const float* cls_w1   = (const float*)d_in[28];
  const float* cls_b1   = (const float*)d_in[29];
  const float* cls_w2   = (const float*)d_in[30];
  const float* cls_b2   = (const float*)d_in[31];
  const float* cls_w3   = (const float*)d_in[32];
  const float* cls_b3   = (const float*)d_in[33];
  const float* cls_ln_w = (const float*)d_in[34];
  const float* cls_ln_b = (const float*)d_in[35];
  float* out = (float*)d_out;

  float* ws   = (float*)d_ws;
  float* qpos = ws;                    // 3600x256
  float* q    = qpos + 921600;         // 3600x256
  float* tA   = q    + 921600;         // 3600x256 temp
  float* tB   = tA   + 921600;         // 3600x256 temp
  float* QK   = tB   + 921600;         // 3600x512
  float* W5   = QK   + 1843200;        // 3600x512 (ffn hidden / regcls1 out)
  float* offaw= W5   + 1843200;        // 3600x96
  float* samp = offaw+ 345600;         // 3600x256
  float* tmp10= samp + 921600;         // 3600x10
  float* ref  = tmp10+ 36000;          // 3600x3
  float* cwA  = ref  + 10800;          // 6x96x256
  float* cbA  = cwA  + 147456;         // 6x96
  float* cwB  = cbA  + 576;            // 6x512x256
  float* cbB  = cwB  + 786432;         // 6x512

  auto gemm = [&](const float* A, int lda, const float* A2, const float* W, const float* B,
                  float* Y, int M, int N, int K, int ldy, int act) {
    dim3 grid((M+63)/64, (N+63)/64);
    gemm_k<<<grid, 128, 0, stream>>>(A, lda, A2, W, B, Y, M, N, K, ldy, act);
  };

  prep_k<<<3072, 256, 0, stream>>>(off_w, off_b, aw_w, aw_b, reg_w1, reg_b1, cls_w1, cls_b1,
                                   cwA, cbA, cwB, cbB);
  init_k<<<900, 256, 0, stream>>>(qe, qpos, q);
  gemm(qpos, 256, nullptr, ref_w, ref_b, ref, ROWS, 3, 256, 3, 2);

  for (int i=0;i<NLAYER;++i) {
    const float* siw = sa_in_w + (size_t)i*768*256;
    const float* sib = sa_in_b + (size_t)i*768;
    // ---- self-attention ----
    gemm(q, 256, qpos, siw, sib, QK, ROWS, 512, 256, 512, 0);               // Q|K
    gemm(q, 256, nullptr, siw + 512*256, sib + 512, tB, ROWS, 256, 256, 256, 0); // V
    attn2_k<<<dim3(32,8), 256, 0, stream>>>(QK, tB, tA);
    gemm(tA, 256, nullptr, sa_out_w + (size_t)i*65536, sa_out_b + (size_t)i*256, tB, ROWS, 256, 256, 256, 0);
    ln_k<<<900, 256, 0, stream>>>(tB, 256, q, ln_w + (size_t)(i*3+0)*256, ln_b + (size_t)(i*3+0)*256, q, 0);
    // ---- deformable cross-attention ----
    gemm(q, 256, qpos, cwA + (size_t)i*96*256, cbA + i*96, offaw, ROWS, 96, 256, 96, 0);
    deform_k<<<ROWS, 512, 0, stream>>>(bev, offaw, ref,
        vproj_w + (size_t)i*65536, vproj_b + (size_t)i*256, samp);
    gemm(samp, 256, nullptr, oproj_w + (size_t)i*65536, oproj_b + (size_t)i*256, tA, ROWS, 256, 256, 256, 0);
    ln_k<<<900, 256, 0, stream>>>(tA, 256, q, ln_w + (size_t)(i*3+1)*256, ln_b + (size_t)(i*3+1)*256, q, 0);
    // ---- FFN ----
    gemm(q, 256, nullptr, ffn_w1 + (size_t)i*512*256, ffn_b1 + (size_t)i*512, W5, ROWS, 512, 256, 512, 1);
    gemm(W5, 512, nullptr, ffn_w2 + (size_t)i*256*512, ffn_b2 + (size_t)i*256, tA, ROWS, 256, 512, 256, 0);
    ln_k<<<900, 256, 0, stream>>>(tA, 256, q, ln_w + (size_t)(i*3+2)*256, ln_b + (size_t)(i*3+2)*256, q, 0);
    // ---- fused reg1|cls1 ----
    gemm(q, 256, nullptr, cwB + (size_t)i*512*256, cbB + i*512, W5, ROWS, 512, 256, 512, 3);
    // ---- reg branch ----
    gemm(W5, 512, nullptr, reg_w2 + (size_t)i*65536, reg_b2 + (size_t)i*256, tB, ROWS, 256, 256, 256, 1);
    gemm(tB, 256, nullptr, reg_w3 + (size_t)i*2560, reg_b3 + (size_t)i*10, tmp10, ROWS, 10, 256, 10, 0);
    refout_k<<<(ROWS+255)/256, 256, 0, stream>>>(tmp10, ref, out + (size_t)i*ROWS*20);
    // ---- cls branch ----
    ln_k<<<900, 256, 0, stream>>>(W5 + 256, 512, nullptr, cls_ln_w + (size_t)(i*2+0)*256, cls_ln_b + (size_t)(i*2+0)*256, samp, 1);
    gemm(samp, 256, nullptr, cls_w2 + (size_t)i*65536, cls_b2 + (size_t)i*256, tA, ROWS, 256, 256, 256, 0);
    ln_k<<<900, 256, 0, stream>>>(tA, 256, nullptr, cls_ln_w + (size_t)(i*2+1)*256, cls_ln_b + (size_t)(i*2+1)*256, tA, 1);
    gemm(tA, 256, nullptr, cls_w3 + (size_t)i*2560, cls_b3 + (size_t)i*10, out + (size_t)i*ROWS*20, ROWS, 10, 256, 20, 0);
  }
}

// Round 3
// 3422.107 us; speedup vs baseline: 1.2381x; 1.2008x over previous
//
#include <hip/hip_runtime.h>
#include <math.h>

#define DD 256
#define NQQ 900
#define NBS 4
#define NLAYER 6
#define BEVH 200
#define BEVW 200
#define ROWS (NBS*NQQ)   // 3600

__device__ __forceinline__ float sigmoidf_(float x){ return 1.0f/(1.0f+expf(-x)); }
__device__ __forceinline__ float invsigf_(float x){
  x = fminf(fmaxf(x,0.0f),1.0f);
  float lo = fmaxf(x,1e-5f), hi = fmaxf(1.0f-x,1e-5f);
  return logf(lo/hi);
}

// ---------------------------------------------------------------------------
// GEMM: Y[m,n] = act( (A[m,:] (+A2[m,:])) . W[n,:] + B[n] )
// 64x64 tile, 256 threads (4 waves), 4x4 per thread, K-chunk 32, dbuf LDS.
// act: 0 none, 1 relu, 2 sigmoid, 3 relu only on n<256
// ---------------------------------------------------------------------------
__global__ __launch_bounds__(256) void gemm_k(
    const float* __restrict__ A, int lda, const float* __restrict__ A2,
    const float* __restrict__ W, const float* __restrict__ B,
    float* __restrict__ Y, int M, int N, int K, int ldy, int act)
{
  __shared__ float As[2][32][66];
  __shared__ float Ws[2][32][66];
  const int t = threadIdx.x;
  const int m0 = blockIdx.x*64, n0 = blockIdx.y*64;
  const int lr = t >> 2, kq = (t & 3) << 3;    // loader: row 0..63, k base 0/8/16/24
  const int tx = t & 15, ty = t >> 4;          // compute: 4 cols, 4 rows each
  const bool aok = (m0 + lr) < M;
  const bool wok = (n0 + lr) < N;
  const float* ap  = A + (size_t)(m0+lr)*lda + kq;
  const float* a2p = A2 ? A2 + (size_t)(m0+lr)*256 + kq : (const float*)0;
  const float* wp  = W + (size_t)(n0+lr)*K + kq;
  float4 pa[2], pw[2];

  auto loadch = [&](int kc) {
    #pragma unroll
    for (int i=0;i<2;++i) {
      pa[i] = aok ? *(const float4*)(ap + kc + i*4) : make_float4(0,0,0,0);
      pw[i] = wok ? *(const float4*)(wp + kc + i*4) : make_float4(0,0,0,0);
    }
    if (a2p && aok) {
      #pragma unroll
      for (int i=0;i<2;++i) {
        float4 x = *(const float4*)(a2p + kc + i*4);
        pa[i].x+=x.x; pa[i].y+=x.y; pa[i].z+=x.z; pa[i].w+=x.w;
      }
    }
  };
  auto storech = [&](int bf) {
    #pragma unroll
    for (int i=0;i<2;++i) {
      const int kk = kq + i*4;
      As[bf][kk+0][lr]=pa[i].x; As[bf][kk+1][lr]=pa[i].y;
      As[bf][kk+2][lr]=pa[i].z; As[bf][kk+3][lr]=pa[i].w;
      Ws[bf][kk+0][lr]=pw[i].x; Ws[bf][kk+1][lr]=pw[i].y;
      Ws[bf][kk+2][lr]=pw[i].z; Ws[bf][kk+3][lr]=pw[i].w;
    }
  };

  float acc[4][4] = {};
  loadch(0); storech(0); __syncthreads();
  const int NC = K >> 5;
  for (int c=0; c<NC; ++c) {
    if (c+1 < NC) loadch((c+1) << 5);
    const int bf = c & 1;
    #pragma unroll
    for (int k=0;k<32;++k) {
      const float4 a4 = *(const float4*)&As[bf][k][ty<<2];
      const float4 w4 = *(const float4*)&Ws[bf][k][tx<<2];
      const float av[4] = {a4.x,a4.y,a4.z,a4.w};
      const float wv[4] = {w4.x,w4.y,w4.z,w4.w};
      #pragma unroll
      for (int r=0;r<4;++r)
        #pragma unroll
        for (int cc=0;cc<4;++cc) acc[r][cc] += av[r]*wv[cc];
    }
    if (c+1 < NC) { storech((c+1)&1); __syncthreads(); }
  }
  const int gn0 = n0 + (tx<<2);
  #pragma unroll
  for (int r=0;r<4;++r) {
    const int gm = m0 + (ty<<2) + r;
    if (gm >= M) continue;
    if (gn0 + 4 <= N) {
      float4 v;
      float* vv = (float*)&v;
      #pragma unroll
      for (int cc=0;cc<4;++cc) {
        float x = acc[r][cc] + (B ? B[gn0+cc] : 0.0f);
        if (act==1 || (act==3 && gn0+cc<256)) x = fmaxf(x,0.0f);
        else if (act==2) x = sigmoidf_(x);
        vv[cc] = x;
      }
      *(float4*)&Y[(size_t)gm*ldy + gn0] = v;
    } else {
      for (int cc=0; cc<4 && gn0+cc<N; ++cc) {
        float x = acc[r][cc] + (B ? B[gn0+cc] : 0.0f);
        if (act==1 || (act==3 && gn0+cc<256)) x = fmaxf(x,0.0f);
        else if (act==2) x = sigmoidf_(x);
        Y[(size_t)gm*ldy + gn0+cc] = x;
      }
    }
  }
}

// ---------------------------------------------------------------------------
// MHA: grid (32 bh, 8 qg); block 256 = 4 waves = 4 key-splits of 225 keys.
// ---------------------------------------------------------------------------
__global__ __launch_bounds__(256, 1) void attn2_k(
    const float* __restrict__ QK, const float* __restrict__ V, float* __restrict__ O)
{
  const int b = blockIdx.x >> 3, h = blockIdx.x & 7;
  const int qg = blockIdx.y;
  const int wv = threadIdx.x >> 6, lane = threadIdx.x & 63;
  const int t = threadIdx.x;
  __shared__ float pm[4][128];
  __shared__ float pl[4][128];
  __shared__ float oacc[128][36];

  const int q0 = qg*128 + lane, q1 = q0 + 64;
  const float* qb = QK + (size_t)b*NQQ*512 + h*32;
  float Q0[32], Q1[32], O0[32], O1[32];
  {
    const int i0 = (q0 < NQQ ? q0 : 0), i1 = (q1 < NQQ ? q1 : 0);
    #pragma unroll
    for (int j=0;j<32;j+=4) {
      *(float4*)&Q0[j] = *(const float4*)(qb + (size_t)i0*512 + j);
      *(float4*)&Q1[j] = *(const float4*)(qb + (size_t)i1*512 + j);
      O0[j]=O0[j+1]=O0[j+2]=O0[j+3]=0.0f;
      O1[j]=O1[j+1]=O1[j+2]=O1[j+3]=0.0f;
    }
  }
  float m0=-3e38f, m1=-3e38f, l0=0.0f, l1=0.0f;
  const float* kb = QK + (size_t)b*NQQ*512 + 256 + h*32;
  const float* vb = V  + (size_t)b*NQQ*256 + h*32;
  const int ks = wv*225, ke = ks + 225;
  #pragma unroll 2
  for (int kk=ks; kk<ke; ++kk) {
    float Kv[32];
    #pragma unroll
    for (int j=0;j<32;j+=4) *(float4*)&Kv[j] = *(const float4*)(kb + (size_t)kk*512 + j);
    float a0=0,a1=0,a2=0,a3=0, c0=0,c1=0,c2=0,c3=0;
    #pragma unroll
    for (int j=0;j<32;j+=4) {
      a0 += Q0[j+0]*Kv[j+0]; a1 += Q0[j+1]*Kv[j+1];
      a2 += Q0[j+2]*Kv[j+2]; a3 += Q0[j+3]*Kv[j+3];
      c0 += Q1[j+0]*Kv[j+0]; c1 += Q1[j+1]*Kv[j+1];
      c2 += Q1[j+2]*Kv[j+2]; c3 += Q1[j+3]*Kv[j+3];
    }
    const float s0 = (a0+a1+a2+a3)*0.17677669529663687f;
    const float s1 = (c0+c1+c2+c3)*0.17677669529663687f;
    float Vv[32];
    #pragma unroll
    for (int j=0;j<32;j+=4) *(float4*)&Vv[j] = *(const float4*)(vb + (size_t)kk*256 + j);
    const float mn0 = fmaxf(m0,s0), mn1 = fmaxf(m1,s1);
    const float cr0 = __expf(m0-mn0), p0 = __expf(s0-mn0);
    const float cr1 = __expf(m1-mn1), p1 = __expf(s1-mn1);
    l0 = l0*cr0 + p0; l1 = l1*cr1 + p1; m0 = mn0; m1 = mn1;
    #pragma unroll
    for (int j=0;j<32;++j) {
      O0[j] = O0[j]*cr0 + p0*Vv[j];
      O1[j] = O1[j]*cr1 + p1*Vv[j];
    }
  }
  pm[wv][lane] = m0; pm[wv][lane+64] = m1;
  pl[wv][lane] = l0; pl[wv][lane+64] = l1;
  for (int j=t; j<128*36; j+=256) ((float*)oacc)[j] = 0.0f;
  __syncthreads();
  const float mm0 = fmaxf(fmaxf(pm[0][lane],pm[1][lane]),fmaxf(pm[2][lane],pm[3][lane]));
  const float mm1 = fmaxf(fmaxf(pm[0][lane+64],pm[1][lane+64]),fmaxf(pm[2][lane+64],pm[3][lane+64]));
  const float w0 = __expf(m0 - mm0), w1 = __expf(m1 - mm1);
  #pragma unroll
  for (int s=0;s<4;++s) {
    if (wv == s) {
      #pragma unroll
      for (int j=0;j<32;++j) {
        oacc[lane][j]    += w0*O0[j];
        oacc[lane+64][j] += w1*O1[j];
      }
    }
    __syncthreads();
  }
  if (t < 128) {
    const int q = qg*128 + t;
    if (q < NQQ) {
      const float mm = fmaxf(fmaxf(pm[0][t],pm[1][t]),fmaxf(pm[2][t],pm[3][t]));
      const float e0=__expf(pm[0][t]-mm), e1=__expf(pm[1][t]-mm),
                  e2=__expf(pm[2][t]-mm), e3=__expf(pm[3][t]-mm);
      const float ll = e0*pl[0][t]+e1*pl[1][t]+e2*pl[2][t]+e3*pl[3][t];
      const float inv = 1.0f/ll;
      float* op = O + ((size_t)b*NQQ + q)*256 + h*32;
      #pragma unroll
      for (int j=0;j<32;j+=4) {
        float4 r;
        r.x = oacc[t][j+0]*inv; r.y = oacc[t][j+1]*inv;
        r.z = oacc[t][j+2]*inv; r.w = oacc[t][j+3]*inv;
        *(float4*)(op+j) = r;
      }
    }
  }
}

// ---------------------------------------------------------------------------
// LayerNorm over 256, wave per row. Y = act( LN(X (+R)) * w + b ).
// ---------------------------------------------------------------------------
__global__ __launch_bounds__(256) void ln_k(
    const float* X, int xld, const float* R,
    const float* __restrict__ w, const float* __restrict__ b, float* Y, int relu)
{
  const int row = blockIdx.x*4 + (threadIdx.x>>6);
  const int lane = threadIdx.x & 63;
  if (row >= ROWS) return;
  float4 x = *(const float4*)(X + (size_t)row*xld + (lane<<2));
  if (R) { const float4 r = *(const float4*)(R + (size_t)row*256 + (lane<<2)); x.x+=r.x; x.y+=r.y; x.z+=r.z; x.w+=r.w; }
  float s = x.x+x.y+x.z+x.w;
  #pragma unroll
  for (int o=32;o>0;o>>=1) s += __shfl_xor(s,o);
  const float mean = s * (1.0f/256.0f);
  float4 d; d.x=x.x-mean; d.y=x.y-mean; d.z=x.z-mean; d.w=x.w-mean;
  float s2 = d.x*d.x+d.y*d.y+d.z*d.z+d.w*d.w;
  #pragma unroll
  for (int o=32;o>0;o>>=1) s2 += __shfl_xor(s2,o);
  const float rs = rsqrtf(s2*(1.0f/256.0f) + 1e-5f);
  const float4 wv = *(const float4*)(w + (lane<<2));
  const float4 bv = *(const float4*)(b + (lane<<2));
  float4 y;
  y.x = d.x*rs*wv.x + bv.x; y.y = d.y*rs*wv.y + bv.y;
  y.z = d.z*rs*wv.z + bv.z; y.w = d.w*rs*wv.w + bv.w;
  if (relu) { y.x=fmaxf(y.x,0.f); y.y=fmaxf(y.y,0.f); y.z=fmaxf(y.z,0.f); y.w=fmaxf(y.w,0.f); }
  *(float4*)(Y + (size_t)row*256 + (lane<<2)) = y;
}

// ---------------------------------------------------------------------------
// Deformable attention, weight-stationary: grid (57 rowgroups, 8 heads),
// block 256 = 4 waves; Wv_head (32x256) staged once in LDS; per-row gather
// in registers -> per-wave LDS rr -> projection from LDS weights.
// ---------------------------------------------------------------------------
__global__ __launch_bounds__(256) void deform2_k(
    const float* __restrict__ bev, const float* __restrict__ offaw,
    const float* __restrict__ ref,
    const float* __restrict__ vpw, const float* __restrict__ vpb,
    float* __restrict__ samp)
{
  const int h = blockIdx.y;
  __shared__ float Ws[32*260];
  __shared__ float rrs[4][260];
  for (int i=threadIdx.x; i<8192; i+=256) {
    const int c = i>>8, k = i&255;
    Ws[c*260+k] = vpw[(size_t)((h<<5)+c)*256 + k];
  }
  __syncthreads();
  const int wv = threadIdx.x>>6, lane = threadIdx.x&63;
  const int c = lane&31, half = lane>>5;
  const float bias = vpb[(h<<5)+c];
  for (int j=0;j<16;++j) {
    const int r = blockIdx.x*64 + wv*16 + j;
    const bool act = r < ROWS;
    float r0=0,r1=0,r2=0,r3=0,sacc=0;
    if (act) {
      const int b = r/NQQ;
      const float refx = ref[r*3+0], refy = ref[r*3+1];
      const float* oa = offaw + (size_t)r*96;
      float aw[4];
      {
        const float a0=oa[64+h*4+0], a1=oa[64+h*4+1], a2=oa[64+h*4+2], a3=oa[64+h*4+3];
        const float mx = fmaxf(fmaxf(a0,a1), fmaxf(a2,a3));
        const float e0=__expf(a0-mx), e1=__expf(a1-mx), e2=__expf(a2-mx), e3=__expf(a3-mx);
        const float inv = 1.0f/(e0+e1+e2+e3);
        aw[0]=e0*inv; aw[1]=e1*inv; aw[2]=e2*inv; aw[3]=e3*inv;
      }
      const float* bevb = bev + (size_t)b*BEVH*BEVW*DD;
      #pragma unroll
      for (int p=0;p<4;++p) {
        const float ox = oa[h*8+p*2+0], oy = oa[h*8+p*2+1];
        const float x = (refx + ox*(1.0f/BEVW))*BEVW - 0.5f;
        const float y = (refy + oy*(1.0f/BEVH))*BEVH - 0.5f;
        const float x0f = floorf(x), y0f = floorf(y);
        const int x0 = (int)x0f, y0 = (int)y0f;
        const float fx = x - x0f, fy = y - y0f;
        #pragma unroll
        for (int dy=0;dy<2;++dy) {
          #pragma unroll
          for (int dx=0;dx<2;++dx) {
            const int xi = x0+dx, yi = y0+dy;
            if (xi < 0 || xi >= BEVW || yi < 0 || yi >= BEVH) continue;
            const float wgt = (dx ? fx : 1.0f-fx) * (dy ? fy : 1.0f-fy) * aw[p];
            const float4 g = *(const float4*)(bevb + (size_t)(yi*BEVW + xi)*DD + (lane<<2));
            r0 += wgt*g.x; r1 += wgt*g.y; r2 += wgt*g.z; r3 += wgt*g.w;
            sacc += wgt;
          }
        }
      }
    }
    *(float4*)&rrs[wv][lane<<2] = make_float4(r0,r1,r2,r3);
    __syncthreads();
    float acc = 0.0f;
    if (act) {
      const int kb = half<<7;
      #pragma unroll
      for (int jj=0;jj<32;++jj) {
        const float4 w4 = *(const float4*)&Ws[c*260 + kb + (jj<<2)];
        const float4 v4 = *(const float4*)&rrs[wv][kb + (jj<<2)];
        acc += w4.x*v4.x + w4.y*v4.y + w4.z*v4.z + w4.w*v4.w;
      }
    }
    acc += __shfl_xor(acc, 32);
    if (act && half==0) samp[(size_t)r*256 + (h<<5) + c] = acc + bias*sacc;
    __syncthreads();
  }
}

// ---------------------------------------------------------------------------
// Fused reg3 + cls3 + ref update + output write. Block: 32 rows, 256 thr:
// row = t>>3, g = (t>>2)&1 (0=reg,1=cls), sl = t&3 (K-slice of 64).
// ---------------------------------------------------------------------------
__global__ __launch_bounds__(256) void regcls3_k(
    const float* __restrict__ reg2o, const float* __restrict__ cls2o,
    const float* __restrict__ rw3, const float* __restrict__ rb3,
    const float* __restrict__ cw3, const float* __restrict__ cb3,
    float* __restrict__ ref, float* __restrict__ outL)
{
  __shared__ float Wr[10*272];
  __shared__ float Wc[10*272];
  for (int i=threadIdx.x; i<2560; i+=256) {
    const int o = i>>8, k = i&255;
    const int si = o*272 + (k>>6)*68 + (k&63);
    Wr[si] = rw3[i]; Wc[si] = cw3[i];
  }
  __syncthreads();
  const int t = threadIdx.x;
  const int row = t>>3, g = (t>>2)&1, sl = t&3;
  const int R = blockIdx.x*32 + row;
  const bool act = R < ROWS;
  const float* in = g ? cls2o : reg2o;
  const float* base = in + (size_t)(act?R:0)*256 + sl*64;
  const float* Wg = g ? Wc : Wr;
  float acc[10] = {};
  #pragma unroll
  for (int jj=0;jj<16;++jj) {
    const float4 v = *(const float4*)(base + 4*jj);
    #pragma unroll
    for (int o=0;o<10;++o) {
      const float4 w = *(const float4*)&Wg[o*272 + sl*68 + 4*jj];
      acc[o] += v.x*w.x + v.y*w.y + v.z*w.z + v.w*w.w;
    }
  }
  #pragma unroll
  for (int o=0;o<10;++o) {
    acc[o] += __shfl_xor(acc[o], 1);
    acc[o] += __shfl_xor(acc[o], 2);
  }
  if (act && sl == 0) {
    if (g) {
      float* oc = outL + (size_t)R*20;
      #pragma unroll
      for (int o=0;o<10;++o) oc[o] = acc[o] + cb3[o];
    } else {
      float tt[10];
      #pragma unroll
      for (int o=0;o<10;++o) tt[o] = acc[o] + rb3[o];
      const float rx = invsigf_(ref[R*3+0]);
      const float ry = invsigf_(ref[R*3+1]);
      const float rz = invsigf_(ref[R*3+2]);
      const float nx = sigmoidf_(tt[0]+rx);
      const float ny = sigmoidf_(tt[1]+ry);
      const float nz = sigmoidf_(tt[4]+rz);
      ref[R*3+0]=nx; ref[R*3+1]=ny; ref[R*3+2]=nz;
      float* o = outL + (size_t)R*20 + 10;
      o[0]=nx*102.4f-51.2f; o[1]=ny*102.4f-51.2f; o[2]=tt[2]; o[3]=tt[3];
      o[4]=nz*8.0f-5.0f; o[5]=tt[5]; o[6]=tt[6]; o[7]=tt[7]; o[8]=tt[8]; o[9]=tt[9];
    }
  }
}

__global__ void init_k(const float* __restrict__ qe, float* __restrict__ qpos, float* __restrict__ q)
{
  const int t = blockIdx.x*blockDim.x + threadIdx.x;
  const int row = t >> 6; const int cc = (t & 63) << 2;
  const int n = row % NQQ;
  *(float4*)(qpos + (size_t)row*256 + cc) = *(const float4*)(qe + (size_t)n*512 + cc);
  *(float4*)(q    + (size_t)row*256 + cc) = *(const float4*)(qe + (size_t)n*512 + 256 + cc);
}

// concat off_w|aw_w -> cwA (6x96x256), reg_w1|cls_w1 -> cwB (6x512x256), + biases
__global__ void prep_k(const float* __restrict__ ow, const float* __restrict__ ob,
                       const float* __restrict__ aw, const float* __restrict__ ab,
                       const float* __restrict__ rw, const float* __restrict__ rb,
                       const float* __restrict__ cw, const float* __restrict__ cb,
                       float* cwA, float* cbA, float* cwB, float* cbB)
{
  const int i = blockIdx.x*blockDim.x + threadIdx.x;
  if (i < 6*96*256) {
    const int l = i/(96*256), r = (i/256)%96, k = i%256;
    cwA[i] = (r<64) ? ow[((size_t)l*64 + r)*256 + k] : aw[((size_t)l*32 + (r-64))*256 + k];
  }
  if (i < 576) { const int l = i/96, r = i%96; cbA[i] = (r<64) ? ob[l*64+r] : ab[l*32 + r-64]; }
  if (i < 6*512*256) {
    const int l = i/(512*256), r = (i/256)%512, k = i%256;
    cwB[i] = (r<256) ? rw[((size_t)l*256+r)*256+k] : cw[((size_t)l*256 + (r-256))*256 + k];
  }
  if (i < 3072) { const int l = i/512, r = i%512; cbB[i] = (r<256) ? rb[l*256+r] : cb[l*256 + r-256]; }
}

extern "C" void kernel_launch(void* const* d_in, const int* in_sizes, int n_in,
                              void* d_out, int out_size, void* d_ws, size_t ws_size,
                              hipStream_t stream)
{
  const float* bev      = (const float*)d_in[0];
  const float* qe       = (const float*)d_in[1];
  const float* ref_w    = (const float*)d_in[2];
  const float* ref_b    = (const float*)d_in[3];
  const float* sa_in_w  = (const float*)d_in[4];
  const float* sa_in_b  = (const float*)d_in[5];
  const float* sa_out_w = (const float*)d_in[6];
  const float* sa_out_b = (const float*)d_in[7];
  const float* ln_w     = (const float*)d_in[8];
  const float* ln_b     = (const float*)d_in[9];
  const float* off_w    = (const float*)d_in[10];
  const float* off_b    = (const float*)d_in[11];
  const float* aw_w     = (const float*)d_in[12];
  const float* aw_b     = (const float*)d_in[13];
  const float* vproj_w  = (const float*)d_in[14];
  const float* vproj_b  = (const float*)d_in[15];
  const float* oproj_w  = (const float*)d_in[16];
  const float* oproj_b  = (const float*)d_in[17];
  const float* ffn_w1   = (const float*)d_in[18];
  const float* ffn_b1   = (const float*)d_in[19];
  const float* ffn_w2   = (const float*)d_in[20];
  const float* ffn_b2   = (const float*)d_in[21];
  const float* reg_w1   = (const float*)d_in[22];
  const float* reg_b1   = (const float*)d_in[23];
  const float* reg_w2   = (const float*)d_in[24];
  const float* reg_b2   = (const float*)d_in[25];
  const float* reg_w3   = (const float*)d_in[26];
  const float* reg_b3   = (const float*)d_in[27];
  const float* cls_w1   = (const float*)d_in[28];
  const float* cls_b1   = (const float*)d_in[29];
  const float* cls_w2   = (const float*)d_in[30];
  const float* cls_b2   = (const float*)d_in[31];
  const float* cls_w3   = (const float*)d_in[32];
  const float* cls_b3   = (const float*)d_in[33];
  const float* cls_ln_w = (const float*)d_in[34];
  const float* cls_ln_b = (const float*)d_in[35];
  float* out = (float*)d_out;

  float* ws   = (float*)d_ws;
  float* qpos = ws;                    // 3600x256
  float* q    = qpos + 921600;         // 3600x256
  float* tA   = q    + 921600;         // 3600x256 temp
  float* tB   = tA   + 921600;         // 3600x256 temp
  float* QK   = tB   + 921600;         // 3600x512
  float* W5   = QK   + 1843200;        // 3600x512 (ffn hidden / regcls1 out)
  float* offaw= W5   + 1843200;        // 3600x96
  float* samp = offaw+ 345600;         // 3600x256
  float* ref  = samp + 921600;         // 3600x3
  float* cwA  = ref  + 10800;          // 6x96x256
  float* cbA  = cwA  + 147456;         // 6x96
  float* cwB  = cbA  + 576;            // 6x512x256
  float* cbB  = cwB  + 786432;         // 6x512

  auto gemm = [&](const float* A, int lda, const float* A2, const float* W, const float* B,
                  float* Y, int M, int N, int K, int ldy, int act) {
    dim3 grid((M+63)/64, (N+63)/64);
    gemm_k<<<grid, 256, 0, stream>>>(A, lda, A2, W, B, Y, M, N, K, ldy, act);
  };

  prep_k<<<3072, 256, 0, stream>>>(off_w, off_b, aw_w, aw_b, reg_w1, reg_b1, cls_w1, cls_b1,
                                   cwA, cbA, cwB, cbB);
  init_k<<<900, 256, 0, stream>>>(qe, qpos, q);
  gemm(qpos, 256, nullptr, ref_w, ref_b, ref, ROWS, 3, 256, 3, 2);

  for (int i=0;i<NLAYER;++i) {
    const float* siw = sa_in_w + (size_t)i*768*256;
    const float* sib = sa_in_b + (size_t)i*768;
    // ---- self-attention ----
    gemm(q, 256, qpos, siw, sib, QK, ROWS, 512, 256, 512, 0);               // Q|K
    gemm(q, 256, nullptr, siw + 512*256, sib + 512, tB, ROWS, 256, 256, 256, 0); // V
    attn2_k<<<dim3(32,8), 256, 0, stream>>>(QK, tB, tA);
    gemm(tA, 256, nullptr, sa_out_w + (size_t)i*65536, sa_out_b + (size_t)i*256, tB, ROWS, 256, 256, 256, 0);
    ln_k<<<900, 256, 0, stream>>>(tB, 256, q, ln_w + (size_t)(i*3+0)*256, ln_b + (size_t)(i*3+0)*256, q, 0);
    // ---- deformable cross-attention ----
    gemm(q, 256, qpos, cwA + (size_t)i*96*256, cbA + i*96, offaw, ROWS, 96, 256, 96, 0);
    deform2_k<<<dim3(57,8), 256, 0, stream>>>(bev, offaw, ref,
        vproj_w + (size_t)i*65536, vproj_b + (size_t)i*256, samp);
    gemm(samp, 256, nullptr, oproj_w + (size_t)i*65536, oproj_b + (size_t)i*256, tA, ROWS, 256, 256, 256, 0);
    ln_k<<<900, 256, 0, stream>>>(tA, 256, q, ln_w + (size_t)(i*3+1)*256, ln_b + (size_t)(i*3+1)*256, q, 0);
    // ---- FFN ----
    gemm(q, 256, nullptr, ffn_w1 + (size_t)i*512*256, ffn_b1 + (size_t)i*512, W5, ROWS, 512, 256, 512, 1);
    gemm(W5, 512, nullptr, ffn_w2 + (size_t)i*256*512, ffn_b2 + (size_t)i*256, tA, ROWS, 256, 512, 256, 0);
    ln_k<<<900, 256, 0, stream>>>(tA, 256, q, ln_w + (size_t)(i*3+2)*256, ln_b + (size_t)(i*3+2)*256, q, 0);
    // ---- fused reg1|cls1 ----
    gemm(q, 256, nullptr, cwB + (size_t)i*512*256, cbB + i*512, W5, ROWS, 512, 256, 512, 3);
    // ---- reg branch ----
    gemm(W5, 512, nullptr, reg_w2 + (size_t)i*65536, reg_b2 + (size_t)i*256, tB, ROWS, 256, 256, 256, 1);
    // ---- cls branch ----
    ln_k<<<900, 256, 0, stream>>>(W5 + 256, 512, nullptr, cls_ln_w + (size_t)(i*2+0)*256, cls_ln_b + (size_t)(i*2+0)*256, samp, 1);
    gemm(samp, 256, nullptr, cls_w2 + (size_t)i*65536, cls_b2 + (size_t)i*256, tA, ROWS, 256, 256, 256, 0);
    ln_k<<<900, 256, 0, stream>>>(tA, 256, nullptr, cls_ln_w + (size_t)(i*2+1)*256, cls_ln_b + (size_t)(i*2+1)*256, tA, 1);
    // ---- fused reg3+cls3+refupdate+output ----
    regcls3_k<<<(ROWS+31)/32, 256, 0, stream>>>(tB, tA,
        reg_w3 + (size_t)i*2560, reg_b3 + (size_t)i*10,
        cls_w3 + (size_t)i*2560, cls_b3 + (size_t)i*10,
        ref, out + (size_t)i*ROWS*20);
  }
}

// Round 4
// 3110.143 us; speedup vs baseline: 1.3622x; 1.1003x over previous
//
#include <hip/hip_runtime.h>
#include <math.h>

#define DD 256
#define NQQ 900
#define NBS 4
#define NLAYER 6
#define BEVH 200
#define BEVW 200
#define ROWS (NBS*NQQ)   // 3600

typedef __attribute__((ext_vector_type(8))) short bf16x8;
typedef __attribute__((ext_vector_type(4))) float f32x4;

__device__ __forceinline__ float sigmoidf_(float x){ return 1.0f/(1.0f+expf(-x)); }
__device__ __forceinline__ float invsigf_(float x){
  x = fminf(fmaxf(x,0.0f),1.0f);
  float lo = fmaxf(x,1e-5f), hi = fmaxf(1.0f-x,1e-5f);
  return logf(lo/hi);
}
__device__ __forceinline__ unsigned f2bf1(float x){
  unsigned u = __float_as_uint(x);
  return (u + 0x7fffu + ((u>>16)&1u)) >> 16;
}
__device__ __forceinline__ unsigned pk2(float a, float b){
  return f2bf1(a) | (f2bf1(b)<<16);
}

// ---------------------------------------------------------------------------
// GEMM: Y[m,n] = act( (A[m,:] (+A2[m,:])) . W[n,:] + B[n] )
// 64x64 tile, 256 threads (4 waves), 4x4 per thread, K-chunk 32, dbuf LDS.
// act: 0 none, 1 relu, 2 sigmoid, 3 relu only on n<256
// ---------------------------------------------------------------------------
__global__ __launch_bounds__(256) void gemm_k(
    const float* __restrict__ A, int lda, const float* __restrict__ A2,
    const float* __restrict__ W, const float* __restrict__ B,
    float* __restrict__ Y, int M, int N, int K, int ldy, int act)
{
  __shared__ float As[2][32][66];
  __shared__ float Ws[2][32][66];
  const int t = threadIdx.x;
  const int m0 = blockIdx.x*64, n0 = blockIdx.y*64;
  const int lr = t >> 2, kq = (t & 3) << 3;
  const int tx = t & 15, ty = t >> 4;
  const bool aok = (m0 + lr) < M;
  const bool wok = (n0 + lr) < N;
  const float* ap  = A + (size_t)(m0+lr)*lda + kq;
  const float* a2p = A2 ? A2 + (size_t)(m0+lr)*256 + kq : (const float*)0;
  const float* wp  = W + (size_t)(n0+lr)*K + kq;
  float4 pa[2], pw[2];

  auto loadch = [&](int kc) {
    #pragma unroll
    for (int i=0;i<2;++i) {
      pa[i] = aok ? *(const float4*)(ap + kc + i*4) : make_float4(0,0,0,0);
      pw[i] = wok ? *(const float4*)(wp + kc + i*4) : make_float4(0,0,0,0);
    }
    if (a2p && aok) {
      #pragma unroll
      for (int i=0;i<2;++i) {
        float4 x = *(const float4*)(a2p + kc + i*4);
        pa[i].x+=x.x; pa[i].y+=x.y; pa[i].z+=x.z; pa[i].w+=x.w;
      }
    }
  };
  auto storech = [&](int bf) {
    #pragma unroll
    for (int i=0;i<2;++i) {
      const int kk = kq + i*4;
      As[bf][kk+0][lr]=pa[i].x; As[bf][kk+1][lr]=pa[i].y;
      As[bf][kk+2][lr]=pa[i].z; As[bf][kk+3][lr]=pa[i].w;
      Ws[bf][kk+0][lr]=pw[i].x; Ws[bf][kk+1][lr]=pw[i].y;
      Ws[bf][kk+2][lr]=pw[i].z; Ws[bf][kk+3][lr]=pw[i].w;
    }
  };

  float acc[4][4] = {};
  loadch(0); storech(0); __syncthreads();
  const int NC = K >> 5;
  for (int c=0; c<NC; ++c) {
    if (c+1 < NC) loadch((c+1) << 5);
    const int bf = c & 1;
    #pragma unroll
    for (int k=0;k<32;++k) {
      const float4 a4 = *(const float4*)&As[bf][k][ty<<2];
      const float4 w4 = *(const float4*)&Ws[bf][k][tx<<2];
      const float av[4] = {a4.x,a4.y,a4.z,a4.w};
      const float wv[4] = {w4.x,w4.y,w4.z,w4.w};
      #pragma unroll
      for (int r=0;r<4;++r)
        #pragma unroll
        for (int cc=0;cc<4;++cc) acc[r][cc] += av[r]*wv[cc];
    }
    if (c+1 < NC) { storech((c+1)&1); __syncthreads(); }
  }
  const int gn0 = n0 + (tx<<2);
  #pragma unroll
  for (int r=0;r<4;++r) {
    const int gm = m0 + (ty<<2) + r;
    if (gm >= M) continue;
    if (gn0 + 4 <= N) {
      float4 v;
      float* vv = (float*)&v;
      #pragma unroll
      for (int cc=0;cc<4;++cc) {
        float x = acc[r][cc] + (B ? B[gn0+cc] : 0.0f);
        if (act==1 || (act==3 && gn0+cc<256)) x = fmaxf(x,0.0f);
        else if (act==2) x = sigmoidf_(x);
        vv[cc] = x;
      }
      *(float4*)&Y[(size_t)gm*ldy + gn0] = v;
    } else {
      for (int cc=0; cc<4 && gn0+cc<N; ++cc) {
        float x = acc[r][cc] + (B ? B[gn0+cc] : 0.0f);
        if (act==1 || (act==3 && gn0+cc<256)) x = fmaxf(x,0.0f);
        else if (act==2) x = sigmoidf_(x);
        Y[(size_t)gm*ldy + gn0+cc] = x;
      }
    }
  }
}

// ---------------------------------------------------------------------------
// MFMA bf16 flash attention. Grid (32 bh, 15 qtiles), block 256 = 4 indep
// waves, 16 queries per wave. Swapped operands: S^T = mfma(K, Q) so each
// lane owns one query's scores; P repacked to PV B-layout via ds_bpermute;
// O^T accumulated in regs (8 f32/lane), epilogue = 2 float4 stores per lane.
// ---------------------------------------------------------------------------
__global__ __launch_bounds__(256) void attn3_k(
    const float* __restrict__ QK, const float* __restrict__ V, float* __restrict__ O)
{
  const int b = blockIdx.x >> 3, h = blockIdx.x & 7;
  const int wv = threadIdx.x >> 6, lane = threadIdx.x & 63;
  const int qt = blockIdx.y*64 + wv*16;
  if (qt >= NQQ) return;
  const int lq = lane & 15, lg = lane >> 4;
  const int q = qt + lq;

  // Q B-frag: lane holds Q[qt+lq][d = lg*8 + j]
  bf16x8 qf;
  {
    const float* qp = QK + (size_t)(b*NQQ + min(q, NQQ-1))*512 + h*32 + lg*8;
    const float4 a = *(const float4*)qp, c = *(const float4*)(qp+4);
    union { bf16x8 v; unsigned u[4]; } uu;
    uu.u[0]=pk2(a.x,a.y); uu.u[1]=pk2(a.z,a.w); uu.u[2]=pk2(c.x,c.y); uu.u[3]=pk2(c.z,c.w);
    qf = uu.v;
  }
  f32x4 ot0 = {0.f,0.f,0.f,0.f}, ot1 = {0.f,0.f,0.f,0.f};
  float m = -3e38f, l = 0.0f;

  const float* kb = QK + (size_t)b*NQQ*512 + 256 + h*32 + lg*8;
  const float* vb = V  + (size_t)b*NQQ*256 + h*32;
  const int pbase = (lq + ((lg&1)<<5)) << 2;   // byte addr of src lane, t>>1==0
  const bool hiC = (lg >> 1);

  for (int k0 = 0; k0 < NQQ; k0 += 32) {
    // K A-frags (rows = keys)
    bf16x8 kf0, kf1;
    {
      const int r0 = min(k0 + lq, NQQ-1), r1 = min(k0 + 16 + lq, NQQ-1);
      const float4 a = *(const float4*)(kb + (size_t)r0*512);
      const float4 c = *(const float4*)(kb + (size_t)r0*512 + 4);
      const float4 d = *(const float4*)(kb + (size_t)r1*512);
      const float4 e = *(const float4*)(kb + (size_t)r1*512 + 4);
      union { bf16x8 v; unsigned u[4]; } u0, u1;
      u0.u[0]=pk2(a.x,a.y); u0.u[1]=pk2(a.z,a.w); u0.u[2]=pk2(c.x,c.y); u0.u[3]=pk2(c.z,c.w);
      u1.u[0]=pk2(d.x,d.y); u1.u[1]=pk2(d.z,d.w); u1.u[2]=pk2(e.x,e.y); u1.u[3]=pk2(e.z,e.w);
      kf0 = u0.v; kf1 = u1.v;
    }
    const f32x4 z = {0.f,0.f,0.f,0.f};
    f32x4 s0 = __builtin_amdgcn_mfma_f32_16x16x32_bf16(kf0, qf, z, 0, 0, 0);
    f32x4 s1 = __builtin_amdgcn_mfma_f32_16x16x32_bf16(kf1, qf, z, 0, 0, 0);
    const float sc = 0.17677669529663687f;
    float p0[4], p1[4];
    #pragma unroll
    for (int r=0;r<4;++r) { p0[r] = s0[r]*sc; p1[r] = s1[r]*sc; }
    if (k0 + 32 > NQQ) {   // mask padded keys
      #pragma unroll
      for (int r=0;r<4;++r) {
        if (k0 + 4*lg + r      >= NQQ) p0[r] = -3e38f;
        if (k0 + 16 + 4*lg + r >= NQQ) p1[r] = -3e38f;
      }
    }
    float cm = fmaxf(fmaxf(fmaxf(p0[0],p0[1]),fmaxf(p0[2],p0[3])),
                     fmaxf(fmaxf(p1[0],p1[1]),fmaxf(p1[2],p1[3])));
    cm = fmaxf(cm, __shfl_xor(cm, 16));
    cm = fmaxf(cm, __shfl_xor(cm, 32));
    const float mn = fmaxf(m, cm);
    const float corr = __expf(m - mn);
    m = mn;
    float rs = 0.0f;
    #pragma unroll
    for (int r=0;r<4;++r) { p0[r] = __expf(p0[r]-mn); rs += p0[r]; }
    #pragma unroll
    for (int r=0;r<4;++r) { p1[r] = __expf(p1[r]-mn); rs += p1[r]; }
    rs += __shfl_xor(rs, 16);
    rs += __shfl_xor(rs, 32);
    l = l*corr + rs;
    ot0 *= corr; ot1 *= corr;

    // repack P (D-layout) -> PV B-frag layout via bpermute
    const int c00 = (int)pk2(p0[0],p0[1]), c01 = (int)pk2(p0[2],p0[3]);
    const int c10 = (int)pk2(p1[0],p1[1]), c11 = (int)pk2(p1[2],p1[3]);
    const int A0 = __builtin_amdgcn_ds_bpermute(pbase,    c00);
    const int B0 = __builtin_amdgcn_ds_bpermute(pbase,    c10);
    const int A1 = __builtin_amdgcn_ds_bpermute(pbase,    c01);
    const int B1 = __builtin_amdgcn_ds_bpermute(pbase,    c11);
    const int A2 = __builtin_amdgcn_ds_bpermute(pbase+64, c00);
    const int B2 = __builtin_amdgcn_ds_bpermute(pbase+64, c10);
    const int A3 = __builtin_amdgcn_ds_bpermute(pbase+64, c01);
    const int B3 = __builtin_amdgcn_ds_bpermute(pbase+64, c11);
    union { bf16x8 v; int u[4]; } pv;
    pv.u[0] = hiC ? B0 : A0; pv.u[1] = hiC ? B1 : A1;
    pv.u[2] = hiC ? B2 : A2; pv.u[3] = hiC ? B3 : A3;

    // V^T A-frags: lane holds V[k0+8*lg+j][d=lq] (frag0) and d=16+lq (frag1)
    bf16x8 vf0, vf1;
    {
      union { bf16x8 v; unsigned u[4]; } u0, u1;
      const int kvb = k0 + 8*lg;
      #pragma unroll
      for (int jj=0;jj<4;++jj) {
        const int ra = min(kvb + 2*jj,   NQQ-1);
        const int rb = min(kvb + 2*jj+1, NQQ-1);
        const float a0 = vb[(size_t)ra*256 + lq];
        const float a1 = vb[(size_t)rb*256 + lq];
        const float b0 = vb[(size_t)ra*256 + 16 + lq];
        const float b1 = vb[(size_t)rb*256 + 16 + lq];
        u0.u[jj] = pk2(a0,a1); u1.u[jj] = pk2(b0,b1);
      }
      vf0 = u0.v; vf1 = u1.v;
    }
    ot0 = __builtin_amdgcn_mfma_f32_16x16x32_bf16(vf0, pv.v, ot0, 0, 0, 0);
    ot1 = __builtin_amdgcn_mfma_f32_16x16x32_bf16(vf1, pv.v, ot1, 0, 0, 0);
  }
  if (q < NQQ) {
    const float inv = 1.0f / l;
    float* op = O + (size_t)(b*NQQ + q)*256 + h*32;
    float4 w0, w1;
    w0.x = ot0[0]*inv; w0.y = ot0[1]*inv; w0.z = ot0[2]*inv; w0.w = ot0[3]*inv;
    w1.x = ot1[0]*inv; w1.y = ot1[1]*inv; w1.z = ot1[2]*inv; w1.w = ot1[3]*inv;
    *(float4*)(op + 4*lg)      = w0;
    *(float4*)(op + 16 + 4*lg) = w1;
  }
}

// ---------------------------------------------------------------------------
// LayerNorm over 256, wave per row. Y = act( LN(X (+R)) * w + b ).
// ---------------------------------------------------------------------------
__global__ __launch_bounds__(256) void ln_k(
    const float* X, int xld, const float* R,
    const float* __restrict__ w, const float* __restrict__ b, float* Y, int relu)
{
  const int row = blockIdx.x*4 + (threadIdx.x>>6);
  const int lane = threadIdx.x & 63;
  if (row >= ROWS) return;
  float4 x = *(const float4*)(X + (size_t)row*xld + (lane<<2));
  if (R) { const float4 r = *(const float4*)(R + (size_t)row*256 + (lane<<2)); x.x+=r.x; x.y+=r.y; x.z+=r.z; x.w+=r.w; }
  float s = x.x+x.y+x.z+x.w;
  #pragma unroll
  for (int o=32;o>0;o>>=1) s += __shfl_xor(s,o);
  const float mean = s * (1.0f/256.0f);
  float4 d; d.x=x.x-mean; d.y=x.y-mean; d.z=x.z-mean; d.w=x.w-mean;
  float s2 = d.x*d.x+d.y*d.y+d.z*d.z+d.w*d.w;
  #pragma unroll
  for (int o=32;o>0;o>>=1) s2 += __shfl_xor(s2,o);
  const float rs = rsqrtf(s2*(1.0f/256.0f) + 1e-5f);
  const float4 wv = *(const float4*)(w + (lane<<2));
  const float4 bv = *(const float4*)(b + (lane<<2));
  float4 y;
  y.x = d.x*rs*wv.x + bv.x; y.y = d.y*rs*wv.y + bv.y;
  y.z = d.z*rs*wv.z + bv.z; y.w = d.w*rs*wv.w + bv.w;
  if (relu) { y.x=fmaxf(y.x,0.f); y.y=fmaxf(y.y,0.f); y.z=fmaxf(y.z,0.f); y.w=fmaxf(y.w,0.f); }
  *(float4*)(Y + (size_t)row*256 + (lane<<2)) = y;
}

// ---------------------------------------------------------------------------
// Deformable attention, weight-stationary: grid (57 rowgroups, 8 heads),
// block 256 = 4 waves; Wv_head (32x256) staged once in LDS.
// ---------------------------------------------------------------------------
__global__ __launch_bounds__(256) void deform2_k(
    const float* __restrict__ bev, const float* __restrict__ offaw,
    const float* __restrict__ ref,
    const float* __restrict__ vpw, const float* __restrict__ vpb,
    float* __restrict__ samp)
{
  const int h = blockIdx.y;
  __shared__ float Ws[32*260];
  __shared__ float rrs[4][260];
  for (int i=threadIdx.x; i<8192; i+=256) {
    const int c = i>>8, k = i&255;
    Ws[c*260+k] = vpw[(size_t)((h<<5)+c)*256 + k];
  }
  __syncthreads();
  const int wv = threadIdx.x>>6, lane = threadIdx.x&63;
  const int c = lane&31, half = lane>>5;
  const float bias = vpb[(h<<5)+c];
  for (int j=0;j<16;++j) {
    const int r = blockIdx.x*64 + wv*16 + j;
    const bool act = r < ROWS;
    float r0=0,r1=0,r2=0,r3=0,sacc=0;
    if (act) {
      const int b = r/NQQ;
      const float refx = ref[r*3+0], refy = ref[r*3+1];
      const float* oa = offaw + (size_t)r*96;
      float aw[4];
      {
        const float a0=oa[64+h*4+0], a1=oa[64+h*4+1], a2=oa[64+h*4+2], a3=oa[64+h*4+3];
        const float mx = fmaxf(fmaxf(a0,a1), fmaxf(a2,a3));
        const float e0=__expf(a0-mx), e1=__expf(a1-mx), e2=__expf(a2-mx), e3=__expf(a3-mx);
        const float inv = 1.0f/(e0+e1+e2+e3);
        aw[0]=e0*inv; aw[1]=e1*inv; aw[2]=e2*inv; aw[3]=e3*inv;
      }
      const float* bevb = bev + (size_t)b*BEVH*BEVW*DD;
      #pragma unroll
      for (int p=0;p<4;++p) {
        const float ox = oa[h*8+p*2+0], oy = oa[h*8+p*2+1];
        const float x = (refx + ox*(1.0f/BEVW))*BEVW - 0.5f;
        const float y = (refy + oy*(1.0f/BEVH))*BEVH - 0.5f;
        const float x0f = floorf(x), y0f = floorf(y);
        const int x0 = (int)x0f, y0 = (int)y0f;
        const float fx = x - x0f, fy = y - y0f;
        #pragma unroll
        for (int dy=0;dy<2;++dy) {
          #pragma unroll
          for (int dx=0;dx<2;++dx) {
            const int xi = x0+dx, yi = y0+dy;
            if (xi < 0 || xi >= BEVW || yi < 0 || yi >= BEVH) continue;
            const float wgt = (dx ? fx : 1.0f-fx) * (dy ? fy : 1.0f-fy) * aw[p];
            const float4 g = *(const float4*)(bevb + (size_t)(yi*BEVW + xi)*DD + (lane<<2));
            r0 += wgt*g.x; r1 += wgt*g.y; r2 += wgt*g.z; r3 += wgt*g.w;
            sacc += wgt;
          }
        }
      }
    }
    *(float4*)&rrs[wv][lane<<2] = make_float4(r0,r1,r2,r3);
    __syncthreads();
    float acc = 0.0f;
    if (act) {
      const int kb = half<<7;
      #pragma unroll
      for (int jj=0;jj<32;++jj) {
        const float4 w4 = *(const float4*)&Ws[c*260 + kb + (jj<<2)];
        const float4 v4 = *(const float4*)&rrs[wv][kb + (jj<<2)];
        acc += w4.x*v4.x + w4.y*v4.y + w4.z*v4.z + w4.w*v4.w;
      }
    }
    acc += __shfl_xor(acc, 32);
    if (act && half==0) samp[(size_t)r*256 + (h<<5) + c] = acc + bias*sacc;
    __syncthreads();
  }
}

// ---------------------------------------------------------------------------
// Fused reg3 + cls3 + ref update + output write.
// ---------------------------------------------------------------------------
__global__ __launch_bounds__(256) void regcls3_k(
    const float* __restrict__ reg2o, const float* __restrict__ cls2o,
    const float* __restrict__ rw3, const float* __restrict__ rb3,
    const float* __restrict__ cw3, const float* __restrict__ cb3,
    float* __restrict__ ref, float* __restrict__ outL)
{
  __shared__ float Wr[10*272];
  __shared__ float Wc[10*272];
  for (int i=threadIdx.x; i<2560; i+=256) {
    const int o = i>>8, k = i&255;
    const int si = o*272 + (k>>6)*68 + (k&63);
    Wr[si] = rw3[i]; Wc[si] = cw3[i];
  }
  __syncthreads();
  const int t = threadIdx.x;
  const int row = t>>3, g = (t>>2)&1, sl = t&3;
  const int R = blockIdx.x*32 + row;
  const bool act = R < ROWS;
  const float* in = g ? cls2o : reg2o;
  const float* base = in + (size_t)(act?R:0)*256 + sl*64;
  const float* Wg = g ? Wc : Wr;
  float acc[10] = {};
  #pragma unroll
  for (int jj=0;jj<16;++jj) {
    const float4 v = *(const float4*)(base + 4*jj);
    #pragma unroll
    for (int o=0;o<10;++o) {
      const float4 w = *(const float4*)&Wg[o*272 + sl*68 + 4*jj];
      acc[o] += v.x*w.x + v.y*w.y + v.z*w.z + v.w*w.w;
    }
  }
  #pragma unroll
  for (int o=0;o<10;++o) {
    acc[o] += __shfl_xor(acc[o], 1);
    acc[o] += __shfl_xor(acc[o], 2);
  }
  if (act && sl == 0) {
    if (g) {
      float* oc = outL + (size_t)R*20;
      #pragma unroll
      for (int o=0;o<10;++o) oc[o] = acc[o] + cb3[o];
    } else {
      float tt[10];
      #pragma unroll
      for (int o=0;o<10;++o) tt[o] = acc[o] + rb3[o];
      const float rx = invsigf_(ref[R*3+0]);
      const float ry = invsigf_(ref[R*3+1]);
      const float rz = invsigf_(ref[R*3+2]);
      const float nx = sigmoidf_(tt[0]+rx);
      const float ny = sigmoidf_(tt[1]+ry);
      const float nz = sigmoidf_(tt[4]+rz);
      ref[R*3+0]=nx; ref[R*3+1]=ny; ref[R*3+2]=nz;
      float* o = outL + (size_t)R*20 + 10;
      o[0]=nx*102.4f-51.2f; o[1]=ny*102.4f-51.2f; o[2]=tt[2]; o[3]=tt[3];
      o[4]=nz*8.0f-5.0f; o[5]=tt[5]; o[6]=tt[6]; o[7]=tt[7]; o[8]=tt[8]; o[9]=tt[9];
    }
  }
}

__global__ void init_k(const float* __restrict__ qe, float* __restrict__ qpos, float* __restrict__ q)
{
  const int t = blockIdx.x*blockDim.x + threadIdx.x;
  const int row = t >> 6; const int cc = (t & 63) << 2;
  const int n = row % NQQ;
  *(float4*)(qpos + (size_t)row*256 + cc) = *(const float4*)(qe + (size_t)n*512 + cc);
  *(float4*)(q    + (size_t)row*256 + cc) = *(const float4*)(qe + (size_t)n*512 + 256 + cc);
}

__global__ void prep_k(const float* __restrict__ ow, const float* __restrict__ ob,
                       const float* __restrict__ aw, const float* __restrict__ ab,
                       const float* __restrict__ rw, const float* __restrict__ rb,
                       const float* __restrict__ cw, const float* __restrict__ cb,
                       float* cwA, float* cbA, float* cwB, float* cbB)
{
  const int i = blockIdx.x*blockDim.x + threadIdx.x;
  if (i < 6*96*256) {
    const int l = i/(96*256), r = (i/256)%96, k = i%256;
    cwA[i] = (r<64) ? ow[((size_t)l*64 + r)*256 + k] : aw[((size_t)l*32 + (r-64))*256 + k];
  }
  if (i < 576) { const int l = i/96, r = i%96; cbA[i] = (r<64) ? ob[l*64+r] : ab[l*32 + r-64]; }
  if (i < 6*512*256) {
    const int l = i/(512*256), r = (i/256)%512, k = i%256;
    cwB[i] = (r<256) ? rw[((size_t)l*256+r)*256+k] : cw[((size_t)l*256 + (r-256))*256 + k];
  }
  if (i < 3072) { const int l = i/512, r = i%512; cbB[i] = (r<256) ? rb[l*256+r] : cb[l*256 + r-256]; }
}

extern "C" void kernel_launch(void* const* d_in, const int* in_sizes, int n_in,
                              void* d_out, int out_size, void* d_ws, size_t ws_size,
                              hipStream_t stream)
{
  const float* bev      = (const float*)d_in[0];
  const float* qe       = (const float*)d_in[1];
  const float* ref_w    = (const float*)d_in[2];
  const float* ref_b    = (const float*)d_in[3];
  const float* sa_in_w  = (const float*)d_in[4];
  const float* sa_in_b  = (const float*)d_in[5];
  const float* sa_out_w = (const float*)d_in[6];
  const float* sa_out_b = (const float*)d_in[7];
  const float* ln_w     = (const float*)d_in[8];
  const float* ln_b     = (const float*)d_in[9];
  const float* off_w    = (const float*)d_in[10];
  const float* off_b    = (const float*)d_in[11];
  const float* aw_w     = (const float*)d_in[12];
  const float* aw_b     = (const float*)d_in[13];
  const float* vproj_w  = (const float*)d_in[14];
  const float* vproj_b  = (const float*)d_in[15];
  const float* oproj_w  = (const float*)d_in[16];
  const float* oproj_b  = (const float*)d_in[17];
  const float* ffn_w1   = (const float*)d_in[18];
  const float* ffn_b1   = (const float*)d_in[19];
  const float* ffn_w2   = (const float*)d_in[20];
  const float* ffn_b2   = (const float*)d_in[21];
  const float* reg_w1   = (const float*)d_in[22];
  const float* reg_b1   = (const float*)d_in[23];
  const float* reg_w2   = (const float*)d_in[24];
  const float* reg_b2   = (const float*)d_in[25];
  const float* reg_w3   = (const float*)d_in[26];
  const float* reg_b3   = (const float*)d_in[27];
  const float* cls_w1   = (const float*)d_in[28];
  const float* cls_b1   = (const float*)d_in[29];
  const float* cls_w2   = (const float*)d_in[30];
  const float* cls_b2   = (const float*)d_in[31];
  const float* cls_w3   = (const float*)d_in[32];
  const float* cls_b3   = (const float*)d_in[33];
  const float* cls_ln_w = (const float*)d_in[34];
  const float* cls_ln_b = (const float*)d_in[35];
  float* out = (float*)d_out;

  float* ws   = (float*)d_ws;
  float* qpos = ws;                    // 3600x256
  float* q    = qpos + 921600;         // 3600x256
  float* tA   = q    + 921600;         // 3600x256 temp
  float* tB   = tA   + 921600;         // 3600x256 temp
  float* QK   = tB   + 921600;         // 3600x512
  float* W5   = QK   + 1843200;        // 3600x512
  float* offaw= W5   + 1843200;        // 3600x96
  float* samp = offaw+ 345600;         // 3600x256
  float* ref  = samp + 921600;         // 3600x3
  float* cwA  = ref  + 10800;          // 6x96x256
  float* cbA  = cwA  + 147456;         // 6x96
  float* cwB  = cbA  + 576;            // 6x512x256
  float* cbB  = cwB  + 786432;         // 6x512

  auto gemm = [&](const float* A, int lda, const float* A2, const float* W, const float* B,
                  float* Y, int M, int N, int K, int ldy, int act) {
    dim3 grid((M+63)/64, (N+63)/64);
    gemm_k<<<grid, 256, 0, stream>>>(A, lda, A2, W, B, Y, M, N, K, ldy, act);
  };

  prep_k<<<3072, 256, 0, stream>>>(off_w, off_b, aw_w, aw_b, reg_w1, reg_b1, cls_w1, cls_b1,
                                   cwA, cbA, cwB, cbB);
  init_k<<<900, 256, 0, stream>>>(qe, qpos, q);
  gemm(qpos, 256, nullptr, ref_w, ref_b, ref, ROWS, 3, 256, 3, 2);

  for (int i=0;i<NLAYER;++i) {
    const float* siw = sa_in_w + (size_t)i*768*256;
    const float* sib = sa_in_b + (size_t)i*768;
    // ---- self-attention ----
    gemm(q, 256, qpos, siw, sib, QK, ROWS, 512, 256, 512, 0);               // Q|K
    gemm(q, 256, nullptr, siw + 512*256, sib + 512, tB, ROWS, 256, 256, 256, 0); // V
    attn3_k<<<dim3(32,15), 256, 0, stream>>>(QK, tB, tA);
    gemm(tA, 256, nullptr, sa_out_w + (size_t)i*65536, sa_out_b + (size_t)i*256, tB, ROWS, 256, 256, 256, 0);
    ln_k<<<900, 256, 0, stream>>>(tB, 256, q, ln_w + (size_t)(i*3+0)*256, ln_b + (size_t)(i*3+0)*256, q, 0);
    // ---- deformable cross-attention ----
    gemm(q, 256, qpos, cwA + (size_t)i*96*256, cbA + i*96, offaw, ROWS, 96, 256, 96, 0);
    deform2_k<<<dim3(57,8), 256, 0, stream>>>(bev, offaw, ref,
        vproj_w + (size_t)i*65536, vproj_b + (size_t)i*256, samp);
    gemm(samp, 256, nullptr, oproj_w + (size_t)i*65536, oproj_b + (size_t)i*256, tA, ROWS, 256, 256, 256, 0);
    ln_k<<<900, 256, 0, stream>>>(tA, 256, q, ln_w + (size_t)(i*3+1)*256, ln_b + (size_t)(i*3+1)*256, q, 0);
    // ---- FFN ----
    gemm(q, 256, nullptr, ffn_w1 + (size_t)i*512*256, ffn_b1 + (size_t)i*512, W5, ROWS, 512, 256, 512, 1);
    gemm(W5, 512, nullptr, ffn_w2 + (size_t)i*256*512, ffn_b2 + (size_t)i*256, tA, ROWS, 256, 512, 256, 0);
    ln_k<<<900, 256, 0, stream>>>(tA, 256, q, ln_w + (size_t)(i*3+2)*256, ln_b + (size_t)(i*3+2)*256, q, 0);
    // ---- fused reg1|cls1 ----
    gemm(q, 256, nullptr, cwB + (size_t)i*512*256, cbB + i*512, W5, ROWS, 512, 256, 512, 3);
    // ---- reg branch ----
    gemm(W5, 512, nullptr, reg_w2 + (size_t)i*65536, reg_b2 + (size_t)i*256, tB, ROWS, 256, 256, 256, 1);
    // ---- cls branch ----
    ln_k<<<900, 256, 0, stream>>>(W5 + 256, 512, nullptr, cls_ln_w + (size_t)(i*2+0)*256, cls_ln_b + (size_t)(i*2+0)*256, samp, 1);
    gemm(samp, 256, nullptr, cls_w2 + (size_t)i*65536, cls_b2 + (size_t)i*256, tA, ROWS, 256, 256, 256, 0);
    ln_k<<<900, 256, 0, stream>>>(tA, 256, nullptr, cls_ln_w + (size_t)(i*2+1)*256, cls_ln_b + (size_t)(i*2+1)*256, tA, 1);
    // ---- fused reg3+cls3+refupdate+output ----
    regcls3_k<<<(ROWS+31)/32, 256, 0, stream>>>(tB, tA,
        reg_w3 + (size_t)i*2560, reg_b3 + (size_t)i*10,
        cls_w3 + (size_t)i*2560, cls_b3 + (size_t)i*10,
        ref, out + (size_t)i*ROWS*20);
  }
}

// Round 5
// 1805.244 us; speedup vs baseline: 2.3469x; 1.7228x over previous
//
#include <hip/hip_runtime.h>
#include <math.h>

#define DD 256
#define NQQ 900
#define NBS 4
#define NLAYER 6
#define BEVH 200
#define BEVW 200
#define ROWS (NBS*NQQ)   // 3600

typedef __attribute__((ext_vector_type(8))) short bf16x8;
typedef __attribute__((ext_vector_type(4))) float f32x4;

__device__ __forceinline__ float sigmoidf_(float x){ return 1.0f/(1.0f+expf(-x)); }
__device__ __forceinline__ float invsigf_(float x){
  x = fminf(fmaxf(x,0.0f),1.0f);
  float lo = fmaxf(x,1e-5f), hi = fmaxf(1.0f-x,1e-5f);
  return logf(lo/hi);
}
__device__ __forceinline__ unsigned f2bf1(float x){
  unsigned u = __float_as_uint(x);
  return (u + 0x7fffu + ((u>>16)&1u)) >> 16;
}
__device__ __forceinline__ unsigned pk2(float a, float b){
  return f2bf1(a) | (f2bf1(b)<<16);
}
__device__ __forceinline__ float bf2f(unsigned u){ return __uint_as_float(u<<16); }

// ---------------------------------------------------------------------------
// fp32 GEMM (small/special cases: ref head). Same as round 3.
// ---------------------------------------------------------------------------
__global__ __launch_bounds__(256) void gemm_k(
    const float* __restrict__ A, int lda, const float* __restrict__ A2,
    const float* __restrict__ W, const float* __restrict__ B,
    float* __restrict__ Y, int M, int N, int K, int ldy, int act)
{
  __shared__ float As[2][32][66];
  __shared__ float Ws[2][32][66];
  const int t = threadIdx.x;
  const int m0 = blockIdx.x*64, n0 = blockIdx.y*64;
  const int lr = t >> 2, kq = (t & 3) << 3;
  const int tx = t & 15, ty = t >> 4;
  const bool aok = (m0 + lr) < M;
  const bool wok = (n0 + lr) < N;
  const float* ap  = A + (size_t)(m0+lr)*lda + kq;
  const float* a2p = A2 ? A2 + (size_t)(m0+lr)*256 + kq : (const float*)0;
  const float* wp  = W + (size_t)(n0+lr)*K + kq;
  float4 pa[2], pw[2];
  auto loadch = [&](int kc) {
    #pragma unroll
    for (int i=0;i<2;++i) {
      pa[i] = aok ? *(const float4*)(ap + kc + i*4) : make_float4(0,0,0,0);
      pw[i] = wok ? *(const float4*)(wp + kc + i*4) : make_float4(0,0,0,0);
    }
    if (a2p && aok) {
      #pragma unroll
      for (int i=0;i<2;++i) {
        float4 x = *(const float4*)(a2p + kc + i*4);
        pa[i].x+=x.x; pa[i].y+=x.y; pa[i].z+=x.z; pa[i].w+=x.w;
      }
    }
  };
  auto storech = [&](int bf) {
    #pragma unroll
    for (int i=0;i<2;++i) {
      const int kk = kq + i*4;
      As[bf][kk+0][lr]=pa[i].x; As[bf][kk+1][lr]=pa[i].y;
      As[bf][kk+2][lr]=pa[i].z; As[bf][kk+3][lr]=pa[i].w;
      Ws[bf][kk+0][lr]=pw[i].x; Ws[bf][kk+1][lr]=pw[i].y;
      Ws[bf][kk+2][lr]=pw[i].z; Ws[bf][kk+3][lr]=pw[i].w;
    }
  };
  float acc[4][4] = {};
  loadch(0); storech(0); __syncthreads();
  const int NC = K >> 5;
  for (int c=0; c<NC; ++c) {
    if (c+1 < NC) loadch((c+1) << 5);
    const int bf = c & 1;
    #pragma unroll
    for (int k=0;k<32;++k) {
      const float4 a4 = *(const float4*)&As[bf][k][ty<<2];
      const float4 w4 = *(const float4*)&Ws[bf][k][tx<<2];
      const float av[4] = {a4.x,a4.y,a4.z,a4.w};
      const float wv[4] = {w4.x,w4.y,w4.z,w4.w};
      #pragma unroll
      for (int r=0;r<4;++r)
        #pragma unroll
        for (int cc=0;cc<4;++cc) acc[r][cc] += av[r]*wv[cc];
    }
    if (c+1 < NC) { storech((c+1)&1); __syncthreads(); }
  }
  const int gn0 = n0 + (tx<<2);
  #pragma unroll
  for (int r=0;r<4;++r) {
    const int gm = m0 + (ty<<2) + r;
    if (gm >= M) continue;
    for (int cc=0; cc<4 && gn0+cc<N; ++cc) {
      float x = acc[r][cc] + (B ? B[gn0+cc] : 0.0f);
      if (act==1 || (act==3 && gn0+cc<256)) x = fmaxf(x,0.0f);
      else if (act==2) x = sigmoidf_(x);
      Y[(size_t)gm*ldy + gn0+cc] = x;
    }
  }
}

// ---------------------------------------------------------------------------
// bf16 MFMA GEMM: Y = act((A(+A2)) . W^T + B). 64x64 tile, 4 waves, each wave
// 32x32 = 2x2 frags of 16x16x32. fp32->bf16 in staging. XOR-swizzled LDS.
// ---------------------------------------------------------------------------
__global__ __launch_bounds__(256) void gemmb_k(
    const float* __restrict__ A, int lda, const float* __restrict__ A2,
    const float* __restrict__ W, const float* __restrict__ Bb,
    float* __restrict__ Y, int M, int N, int K, int ldy, int act)
{
  __shared__ ushort As[2][2048];
  __shared__ ushort Bs[2][2048];
  const int t = threadIdx.x;
  const int m0 = blockIdx.x*64, n0 = blockIdx.y*64;
  const int srow = t>>2, scb = t&3;
  const bool aok = (m0+srow) < M;
  const bool wok = (n0+srow) < N;
  const float* ap  = A + (size_t)(m0+srow)*lda + scb*8;
  const float* a2p = A2 ? A2 + (size_t)(m0+srow)*256 + scb*8 : (const float*)0;
  const float* wp  = W + (size_t)(n0+srow)*K + scb*8;
  const int sidx = srow*32 + ((scb ^ (srow&3))<<3);

  float4 ra0, ra1, rw0, rw1;
  auto loadg = [&](int kc){
    ra0 = aok ? *(const float4*)(ap+kc)   : make_float4(0,0,0,0);
    ra1 = aok ? *(const float4*)(ap+kc+4) : make_float4(0,0,0,0);
    if (a2p && aok) {
      float4 x = *(const float4*)(a2p+kc);   ra0.x+=x.x; ra0.y+=x.y; ra0.z+=x.z; ra0.w+=x.w;
      float4 y = *(const float4*)(a2p+kc+4); ra1.x+=y.x; ra1.y+=y.y; ra1.z+=y.z; ra1.w+=y.w;
    }
    rw0 = wok ? *(const float4*)(wp+kc)   : make_float4(0,0,0,0);
    rw1 = wok ? *(const float4*)(wp+kc+4) : make_float4(0,0,0,0);
  };
  auto writes = [&](int bf){
    union {bf16x8 v; unsigned u[4];} ua, uw;
    ua.u[0]=pk2(ra0.x,ra0.y); ua.u[1]=pk2(ra0.z,ra0.w);
    ua.u[2]=pk2(ra1.x,ra1.y); ua.u[3]=pk2(ra1.z,ra1.w);
    uw.u[0]=pk2(rw0.x,rw0.y); uw.u[1]=pk2(rw0.z,rw0.w);
    uw.u[2]=pk2(rw1.x,rw1.y); uw.u[3]=pk2(rw1.z,rw1.w);
    *(bf16x8*)&As[bf][sidx] = ua.v;
    *(bf16x8*)&Bs[bf][sidx] = uw.v;
  };

  const int wv = t>>6, lane = t&63;
  const int wr = wv>>1, wc = wv&1;
  const int fm = lane&15, kb = lane>>4;
  const int arow0 = wr*32 + fm, arow1 = arow0 + 16;
  const int bcol0 = wc*32 + fm, bcol1 = bcol0 + 16;
  const int ai0 = arow0*32 + ((kb^(arow0&3))<<3);
  const int ai1 = arow1*32 + ((kb^(arow1&3))<<3);
  const int bi0 = bcol0*32 + ((kb^(bcol0&3))<<3);
  const int bi1 = bcol1*32 + ((kb^(bcol1&3))<<3);
  f32x4 acc00={0,0,0,0}, acc01={0,0,0,0}, acc10={0,0,0,0}, acc11={0,0,0,0};

  loadg(0); writes(0); __syncthreads();
  const int NS = K>>5;
  for (int s=0; s<NS; ++s) {
    if (s+1<NS) loadg((s+1)<<5);
    const int bf = s&1;
    bf16x8 a0 = *(bf16x8*)&As[bf][ai0];
    bf16x8 a1 = *(bf16x8*)&As[bf][ai1];
    bf16x8 b0 = *(bf16x8*)&Bs[bf][bi0];
    bf16x8 b1 = *(bf16x8*)&Bs[bf][bi1];
    acc00 = __builtin_amdgcn_mfma_f32_16x16x32_bf16(a0,b0,acc00,0,0,0);
    acc01 = __builtin_amdgcn_mfma_f32_16x16x32_bf16(a0,b1,acc01,0,0,0);
    acc10 = __builtin_amdgcn_mfma_f32_16x16x32_bf16(a1,b0,acc10,0,0,0);
    acc11 = __builtin_amdgcn_mfma_f32_16x16x32_bf16(a1,b1,acc11,0,0,0);
    if (s+1<NS) { __syncthreads(); writes((s+1)&1); __syncthreads(); }
  }

  #pragma unroll
  for (int fr=0; fr<2; ++fr) {
    #pragma unroll
    for (int fc=0; fc<2; ++fc) {
      const f32x4 av = fr ? (fc ? acc11 : acc10) : (fc ? acc01 : acc00);
      const int col = n0 + wc*32 + fc*16 + fm;
      if (col >= N) continue;
      const float bias = Bb ? Bb[col] : 0.0f;
      #pragma unroll
      for (int r=0; r<4; ++r) {
        const int row = m0 + wr*32 + fr*16 + kb*4 + r;
        if (row >= M) continue;
        float x = av[r] + bias;
        if (act==1 || (act==3 && col<256)) x = fmaxf(x,0.0f);
        else if (act==2) x = sigmoidf_(x);
        Y[(size_t)row*ldy + col] = x;
      }
    }
  }
}

// ---------------------------------------------------------------------------
// MFMA bf16 flash attention (round-3 design, verified).
// ---------------------------------------------------------------------------
__global__ __launch_bounds__(256) void attn3_k(
    const float* __restrict__ QK, const float* __restrict__ V, float* __restrict__ O)
{
  const int b = blockIdx.x >> 3, h = blockIdx.x & 7;
  const int wv = threadIdx.x >> 6, lane = threadIdx.x & 63;
  const int qt = blockIdx.y*64 + wv*16;
  if (qt >= NQQ) return;
  const int lq = lane & 15, lg = lane >> 4;
  const int q = qt + lq;

  bf16x8 qf;
  {
    const float* qp = QK + (size_t)(b*NQQ + min(q, NQQ-1))*512 + h*32 + lg*8;
    const float4 a = *(const float4*)qp, c = *(const float4*)(qp+4);
    union { bf16x8 v; unsigned u[4]; } uu;
    uu.u[0]=pk2(a.x,a.y); uu.u[1]=pk2(a.z,a.w); uu.u[2]=pk2(c.x,c.y); uu.u[3]=pk2(c.z,c.w);
    qf = uu.v;
  }
  f32x4 ot0 = {0.f,0.f,0.f,0.f}, ot1 = {0.f,0.f,0.f,0.f};
  float m = -3e38f, l = 0.0f;

  const float* kb = QK + (size_t)b*NQQ*512 + 256 + h*32 + lg*8;
  const float* vb = V  + (size_t)b*NQQ*256 + h*32;
  const int pbase = (lq + ((lg&1)<<5)) << 2;
  const bool hiC = (lg >> 1);

  for (int k0 = 0; k0 < NQQ; k0 += 32) {
    bf16x8 kf0, kf1;
    {
      const int r0 = min(k0 + lq, NQQ-1), r1 = min(k0 + 16 + lq, NQQ-1);
      const float4 a = *(const float4*)(kb + (size_t)r0*512);
      const float4 c = *(const float4*)(kb + (size_t)r0*512 + 4);
      const float4 d = *(const float4*)(kb + (size_t)r1*512);
      const float4 e = *(const float4*)(kb + (size_t)r1*512 + 4);
      union { bf16x8 v; unsigned u[4]; } u0, u1;
      u0.u[0]=pk2(a.x,a.y); u0.u[1]=pk2(a.z,a.w); u0.u[2]=pk2(c.x,c.y); u0.u[3]=pk2(c.z,c.w);
      u1.u[0]=pk2(d.x,d.y); u1.u[1]=pk2(d.z,d.w); u1.u[2]=pk2(e.x,e.y); u1.u[3]=pk2(e.z,e.w);
      kf0 = u0.v; kf1 = u1.v;
    }
    const f32x4 z = {0.f,0.f,0.f,0.f};
    f32x4 s0 = __builtin_amdgcn_mfma_f32_16x16x32_bf16(kf0, qf, z, 0, 0, 0);
    f32x4 s1 = __builtin_amdgcn_mfma_f32_16x16x32_bf16(kf1, qf, z, 0, 0, 0);
    const float sc = 0.17677669529663687f;
    float p0[4], p1[4];
    #pragma unroll
    for (int r=0;r<4;++r) { p0[r] = s0[r]*sc; p1[r] = s1[r]*sc; }
    if (k0 + 32 > NQQ) {
      #pragma unroll
      for (int r=0;r<4;++r) {
        if (k0 + 4*lg + r      >= NQQ) p0[r] = -3e38f;
        if (k0 + 16 + 4*lg + r >= NQQ) p1[r] = -3e38f;
      }
    }
    float cm = fmaxf(fmaxf(fmaxf(p0[0],p0[1]),fmaxf(p0[2],p0[3])),
                     fmaxf(fmaxf(p1[0],p1[1]),fmaxf(p1[2],p1[3])));
    cm = fmaxf(cm, __shfl_xor(cm, 16));
    cm = fmaxf(cm, __shfl_xor(cm, 32));
    const float mn = fmaxf(m, cm);
    const float corr = __expf(m - mn);
    m = mn;
    float rs = 0.0f;
    #pragma unroll
    for (int r=0;r<4;++r) { p0[r] = __expf(p0[r]-mn); rs += p0[r]; }
    #pragma unroll
    for (int r=0;r<4;++r) { p1[r] = __expf(p1[r]-mn); rs += p1[r]; }
    rs += __shfl_xor(rs, 16);
    rs += __shfl_xor(rs, 32);
    l = l*corr + rs;
    ot0 *= corr; ot1 *= corr;

    const int c00 = (int)pk2(p0[0],p0[1]), c01 = (int)pk2(p0[2],p0[3]);
    const int c10 = (int)pk2(p1[0],p1[1]), c11 = (int)pk2(p1[2],p1[3]);
    const int A0 = __builtin_amdgcn_ds_bpermute(pbase,    c00);
    const int B0 = __builtin_amdgcn_ds_bpermute(pbase,    c10);
    const int A1 = __builtin_amdgcn_ds_bpermute(pbase,    c01);
    const int B1 = __builtin_amdgcn_ds_bpermute(pbase,    c11);
    const int A2 = __builtin_amdgcn_ds_bpermute(pbase+64, c00);
    const int B2 = __builtin_amdgcn_ds_bpermute(pbase+64, c10);
    const int A3 = __builtin_amdgcn_ds_bpermute(pbase+64, c01);
    const int B3 = __builtin_amdgcn_ds_bpermute(pbase+64, c11);
    union { bf16x8 v; int u[4]; } pv;
    pv.u[0] = hiC ? B0 : A0; pv.u[1] = hiC ? B1 : A1;
    pv.u[2] = hiC ? B2 : A2; pv.u[3] = hiC ? B3 : A3;

    bf16x8 vf0, vf1;
    {
      union { bf16x8 v; unsigned u[4]; } u0, u1;
      const int kvb = k0 + 8*lg;
      #pragma unroll
      for (int jj=0;jj<4;++jj) {
        const int ra = min(kvb + 2*jj,   NQQ-1);
        const int rb = min(kvb + 2*jj+1, NQQ-1);
        const float a0 = vb[(size_t)ra*256 + lq];
        const float a1 = vb[(size_t)rb*256 + lq];
        const float b0 = vb[(size_t)ra*256 + 16 + lq];
        const float b1 = vb[(size_t)rb*256 + 16 + lq];
        u0.u[jj] = pk2(a0,a1); u1.u[jj] = pk2(b0,b1);
      }
      vf0 = u0.v; vf1 = u1.v;
    }
    ot0 = __builtin_amdgcn_mfma_f32_16x16x32_bf16(vf0, pv.v, ot0, 0, 0, 0);
    ot1 = __builtin_amdgcn_mfma_f32_16x16x32_bf16(vf1, pv.v, ot1, 0, 0, 0);
  }
  if (q < NQQ) {
    const float inv = 1.0f / l;
    float* op = O + (size_t)(b*NQQ + q)*256 + h*32;
    float4 w0, w1;
    w0.x = ot0[0]*inv; w0.y = ot0[1]*inv; w0.z = ot0[2]*inv; w0.w = ot0[3]*inv;
    w1.x = ot1[0]*inv; w1.y = ot1[1]*inv; w1.z = ot1[2]*inv; w1.w = ot1[3]*inv;
    *(float4*)(op + 4*lg)      = w0;
    *(float4*)(op + 16 + 4*lg) = w1;
  }
}

// ---------------------------------------------------------------------------
// LayerNorm over 256, wave per row.
// ---------------------------------------------------------------------------
__global__ __launch_bounds__(256) void ln_k(
    const float* X, int xld, const float* R,
    const float* __restrict__ w, const float* __restrict__ b, float* Y, int relu)
{
  const int row = blockIdx.x*4 + (threadIdx.x>>6);
  const int lane = threadIdx.x & 63;
  if (row >= ROWS) return;
  float4 x = *(const float4*)(X + (size_t)row*xld + (lane<<2));
  if (R) { const float4 r = *(const float4*)(R + (size_t)row*256 + (lane<<2)); x.x+=r.x; x.y+=r.y; x.z+=r.z; x.w+=r.w; }
  float s = x.x+x.y+x.z+x.w;
  #pragma unroll
  for (int o=32;o>0;o>>=1) s += __shfl_xor(s,o);
  const float mean = s * (1.0f/256.0f);
  float4 d; d.x=x.x-mean; d.y=x.y-mean; d.z=x.z-mean; d.w=x.w-mean;
  float s2 = d.x*d.x+d.y*d.y+d.z*d.z+d.w*d.w;
  #pragma unroll
  for (int o=32;o>0;o>>=1) s2 += __shfl_xor(s2,o);
  const float rs = rsqrtf(s2*(1.0f/256.0f) + 1e-5f);
  const float4 wv = *(const float4*)(w + (lane<<2));
  const float4 bv = *(const float4*)(b + (lane<<2));
  float4 y;
  y.x = d.x*rs*wv.x + bv.x; y.y = d.y*rs*wv.y + bv.y;
  y.z = d.z*rs*wv.z + bv.z; y.w = d.w*rs*wv.w + bv.w;
  if (relu) { y.x=fmaxf(y.x,0.f); y.y=fmaxf(y.y,0.f); y.z=fmaxf(y.z,0.f); y.w=fmaxf(y.w,0.f); }
  *(float4*)(Y + (size_t)row*256 + (lane<<2)) = y;
}

// ---------------------------------------------------------------------------
// Deformable gather: grid 3600, block 512 (wave = head). No LDS, no barriers.
// rr is bf16, head-major [8][3600][256]; sumw fp32 [8][3600].
// ---------------------------------------------------------------------------
__global__ __launch_bounds__(512) void gather_k(
    const float* __restrict__ bev, const float* __restrict__ offaw,
    const float* __restrict__ ref, ushort* __restrict__ rr, float* __restrict__ sumw)
{
  const int row = blockIdx.x;
  const int h = threadIdx.x >> 6, lane = threadIdx.x & 63;
  const int b = row / NQQ;
  const float refx = ref[row*3+0], refy = ref[row*3+1];
  const float* oa = offaw + (size_t)row*96;
  float aw[4];
  {
    const float a0=oa[64+h*4+0], a1=oa[64+h*4+1], a2=oa[64+h*4+2], a3=oa[64+h*4+3];
    const float mx = fmaxf(fmaxf(a0,a1), fmaxf(a2,a3));
    const float e0=__expf(a0-mx), e1=__expf(a1-mx), e2=__expf(a2-mx), e3=__expf(a3-mx);
    const float inv = 1.0f/(e0+e1+e2+e3);
    aw[0]=e0*inv; aw[1]=e1*inv; aw[2]=e2*inv; aw[3]=e3*inv;
  }
  float r0=0.f, r1=0.f, r2=0.f, r3=0.f, sacc=0.f;
  const float* bevb = bev + (size_t)b*BEVH*BEVW*DD;
  #pragma unroll
  for (int p=0;p<4;++p) {
    const float ox = oa[h*8+p*2+0], oy = oa[h*8+p*2+1];
    const float x = (refx + ox*(1.0f/BEVW))*BEVW - 0.5f;
    const float y = (refy + oy*(1.0f/BEVH))*BEVH - 0.5f;
    const float x0f = floorf(x), y0f = floorf(y);
    const int x0 = (int)x0f, y0 = (int)y0f;
    const float fx = x - x0f, fy = y - y0f;
    #pragma unroll
    for (int dy=0;dy<2;++dy) {
      #pragma unroll
      for (int dx=0;dx<2;++dx) {
        const int xi = x0+dx, yi = y0+dy;
        if (xi < 0 || xi >= BEVW || yi < 0 || yi >= BEVH) continue;
        const float wgt = (dx ? fx : 1.0f-fx) * (dy ? fy : 1.0f-fy) * aw[p];
        const float4 g = *(const float4*)(bevb + (size_t)(yi*BEVW + xi)*DD + (lane<<2));
        r0 += wgt*g.x; r1 += wgt*g.y; r2 += wgt*g.z; r3 += wgt*g.w;
        sacc += wgt;
      }
    }
  }
  ushort4 o;
  o.x = (ushort)f2bf1(r0); o.y = (ushort)f2bf1(r1);
  o.z = (ushort)f2bf1(r2); o.w = (ushort)f2bf1(r3);
  *(ushort4*)&rr[((size_t)h*ROWS + row)*256 + (lane<<2)] = o;
  if (lane == 0) sumw[h*ROWS + row] = sacc;
}

// ---------------------------------------------------------------------------
// Deformable projection: grid (113, 8 heads), block 256 = 4 waves x 8 rows.
// Wv_head staged in LDS (pitch 257, conflict-free); rr read via broadcast.
// ---------------------------------------------------------------------------
__global__ __launch_bounds__(256) void proj_k(
    const ushort* __restrict__ rr, const float* __restrict__ sumw,
    const float* __restrict__ vpw, const float* __restrict__ vpb,
    float* __restrict__ samp)
{
  const int h = blockIdx.y;
  __shared__ float Ws[32*257];
  for (int i=threadIdx.x; i<8192; i+=256) {
    const int c = i>>8, k = i&255;
    Ws[c*257+k] = vpw[(size_t)((h<<5)+c)*256 + k];
  }
  __syncthreads();
  const int wv = threadIdx.x>>6, lane = threadIdx.x&63;
  const int c = lane&31, half = lane>>5;
  const float bias = vpb[(h<<5)+c];
  #pragma unroll
  for (int j=0;j<8;++j) {
    const int r = blockIdx.x*32 + wv*8 + j;
    if (r >= ROWS) break;
    const ushort* rp = rr + ((size_t)h*ROWS + r)*256 + half*128;
    const float* wb = &Ws[c*257 + half*128];
    float acc = 0.0f;
    #pragma unroll
    for (int jj=0;jj<32;++jj) {
      const uint2 u = *(const uint2*)(rp + jj*4);
      acc += bf2f(u.x & 0xffffu) * wb[jj*4+0];
      acc += bf2f(u.x >> 16)     * wb[jj*4+1];
      acc += bf2f(u.y & 0xffffu) * wb[jj*4+2];
      acc += bf2f(u.y >> 16)     * wb[jj*4+3];
    }
    acc += __shfl_xor(acc, 32);
    if (half == 0) samp[(size_t)r*256 + (h<<5) + c] = acc + bias*sumw[h*ROWS + r];
  }
}

// ---------------------------------------------------------------------------
// Fused reg3 + cls3 + ref update + output write.
// ---------------------------------------------------------------------------
__global__ __launch_bounds__(256) void regcls3_k(
    const float* __restrict__ reg2o, const float* __restrict__ cls2o,
    const float* __restrict__ rw3, const float* __restrict__ rb3,
    const float* __restrict__ cw3, const float* __restrict__ cb3,
    float* __restrict__ ref, float* __restrict__ outL)
{
  __shared__ float Wr[10*272];
  __shared__ float Wc[10*272];
  for (int i=threadIdx.x; i<2560; i+=256) {
    const int o = i>>8, k = i&255;
    const int si = o*272 + (k>>6)*68 + (k&63);
    Wr[si] = rw3[i]; Wc[si] = cw3[i];
  }
  __syncthreads();
  const int t = threadIdx.x;
  const int row = t>>3, g = (t>>2)&1, sl = t&3;
  const int R = blockIdx.x*32 + row;
  const bool act = R < ROWS;
  const float* in = g ? cls2o : reg2o;
  const float* base = in + (size_t)(act?R:0)*256 + sl*64;
  const float* Wg = g ? Wc : Wr;
  float acc[10] = {};
  #pragma unroll
  for (int jj=0;jj<16;++jj) {
    const float4 v = *(const float4*)(base + 4*jj);
    #pragma unroll
    for (int o=0;o<10;++o) {
      const float4 w = *(const float4*)&Wg[o*272 + sl*68 + 4*jj];
      acc[o] += v.x*w.x + v.y*w.y + v.z*w.z + v.w*w.w;
    }
  }
  #pragma unroll
  for (int o=0;o<10;++o) {
    acc[o] += __shfl_xor(acc[o], 1);
    acc[o] += __shfl_xor(acc[o], 2);
  }
  if (act && sl == 0) {
    if (g) {
      float* oc = outL + (size_t)R*20;
      #pragma unroll
      for (int o=0;o<10;++o) oc[o] = acc[o] + cb3[o];
    } else {
      float tt[10];
      #pragma unroll
      for (int o=0;o<10;++o) tt[o] = acc[o] + rb3[o];
      const float rx = invsigf_(ref[R*3+0]);
      const float ry = invsigf_(ref[R*3+1]);
      const float rz = invsigf_(ref[R*3+2]);
      const float nx = sigmoidf_(tt[0]+rx);
      const float ny = sigmoidf_(tt[1]+ry);
      const float nz = sigmoidf_(tt[4]+rz);
      ref[R*3+0]=nx; ref[R*3+1]=ny; ref[R*3+2]=nz;
      float* o = outL + (size_t)R*20 + 10;
      o[0]=nx*102.4f-51.2f; o[1]=ny*102.4f-51.2f; o[2]=tt[2]; o[3]=tt[3];
      o[4]=nz*8.0f-5.0f; o[5]=tt[5]; o[6]=tt[6]; o[7]=tt[7]; o[8]=tt[8]; o[9]=tt[9];
    }
  }
}

__global__ void init_k(const float* __restrict__ qe, float* __restrict__ qpos, float* __restrict__ q)
{
  const int t = blockIdx.x*blockDim.x + threadIdx.x;
  const int row = t >> 6; const int cc = (t & 63) << 2;
  const int n = row % NQQ;
  *(float4*)(qpos + (size_t)row*256 + cc) = *(const float4*)(qe + (size_t)n*512 + cc);
  *(float4*)(q    + (size_t)row*256 + cc) = *(const float4*)(qe + (size_t)n*512 + 256 + cc);
}

__global__ void prep_k(const float* __restrict__ ow, const float* __restrict__ ob,
                       const float* __restrict__ aw, const float* __restrict__ ab,
                       const float* __restrict__ rw, const float* __restrict__ rb,
                       const float* __restrict__ cw, const float* __restrict__ cb,
                       float* cwA, float* cbA, float* cwB, float* cbB)
{
  const int i = blockIdx.x*blockDim.x + threadIdx.x;
  if (i < 6*96*256) {
    const int l = i/(96*256), r = (i/256)%96, k = i%256;
    cwA[i] = (r<64) ? ow[((size_t)l*64 + r)*256 + k] : aw[((size_t)l*32 + (r-64))*256 + k];
  }
  if (i < 576) { const int l = i/96, r = i%96; cbA[i] = (r<64) ? ob[l*64+r] : ab[l*32 + r-64]; }
  if (i < 6*512*256) {
    const int l = i/(512*256), r = (i/256)%512, k = i%256;
    cwB[i] = (r<256) ? rw[((size_t)l*256+r)*256+k] : cw[((size_t)l*256 + (r-256))*256 + k];
  }
  if (i < 3072) { const int l = i/512, r = i%512; cbB[i] = (r<256) ? rb[l*256+r] : cb[l*256 + r-256]; }
}

extern "C" void kernel_launch(void* const* d_in, const int* in_sizes, int n_in,
                              void* d_out, int out_size, void* d_ws, size_t ws_size,
                              hipStream_t stream)
{
  const float* bev      = (const float*)d_in[0];
  const float* qe       = (const float*)d_in[1];
  const float* ref_w    = (const float*)d_in[2];
  const float* ref_b    = (const float*)d_in[3];
  const float* sa_in_w  = (const float*)d_in[4];
  const float* sa_in_b  = (const float*)d_in[5];
  const float* sa_out_w = (const float*)d_in[6];
  const float* sa_out_b = (const float*)d_in[7];
  const float* ln_w     = (const float*)d_in[8];
  const float* ln_b     = (const float*)d_in[9];
  const float* off_w    = (const float*)d_in[10];
  const float* off_b    = (const float*)d_in[11];
  const float* aw_w     = (const float*)d_in[12];
  const float* aw_b     = (const float*)d_in[13];
  const float* vproj_w  = (const float*)d_in[14];
  const float* vproj_b  = (const float*)d_in[15];
  const float* oproj_w  = (const float*)d_in[16];
  const float* oproj_b  = (const float*)d_in[17];
  const float* ffn_w1   = (const float*)d_in[18];
  const float* ffn_b1   = (const float*)d_in[19];
  const float* ffn_w2   = (const float*)d_in[20];
  const float* ffn_b2   = (const float*)d_in[21];
  const float* reg_w1   = (const float*)d_in[22];
  const float* reg_b1   = (const float*)d_in[23];
  const float* reg_w2   = (const float*)d_in[24];
  const float* reg_b2   = (const float*)d_in[25];
  const float* reg_w3   = (const float*)d_in[26];
  const float* reg_b3   = (const float*)d_in[27];
  const float* cls_w1   = (const float*)d_in[28];
  const float* cls_b1   = (const float*)d_in[29];
  const float* cls_w2   = (const float*)d_in[30];
  const float* cls_b2   = (const float*)d_in[31];
  const float* cls_w3   = (const float*)d_in[32];
  const float* cls_b3   = (const float*)d_in[33];
  const float* cls_ln_w = (const float*)d_in[34];
  const float* cls_ln_b = (const float*)d_in[35];
  float* out = (float*)d_out;

  float* ws   = (float*)d_ws;
  float* qpos = ws;                    // 3600x256
  float* q    = qpos + 921600;         // 3600x256
  float* tA   = q    + 921600;         // 3600x256 temp
  float* tB   = tA   + 921600;         // 3600x256 temp
  float* QK   = tB   + 921600;         // 3600x512
  float* W5   = QK   + 1843200;        // 3600x512
  float* offaw= W5   + 1843200;        // 3600x96
  float* samp = offaw+ 345600;         // 3600x256
  float* ref  = samp + 921600;         // 3600x3
  float* cwA  = ref  + 10800;          // 6x96x256
  float* cbA  = cwA  + 147456;         // 6x96
  float* cwB  = cbA  + 576;            // 6x512x256
  float* cbB  = cwB  + 786432;         // 6x512
  float* sumw = cbB  + 3072;           // 8x3600
  // rr (bf16, 8x3600x256) aliases QK+W5 (dead during deform phase)
  ushort* rr  = (ushort*)QK;

  auto gemm = [&](const float* A, int lda, const float* A2, const float* W, const float* B,
                  float* Y, int M, int N, int K, int ldy, int act) {
    dim3 grid((M+63)/64, (N+63)/64);
    gemm_k<<<grid, 256, 0, stream>>>(A, lda, A2, W, B, Y, M, N, K, ldy, act);
  };
  auto gemmb = [&](const float* A, int lda, const float* A2, const float* W, const float* B,
                   float* Y, int M, int N, int K, int ldy, int act) {
    dim3 grid((M+63)/64, (N+63)/64);
    gemmb_k<<<grid, 256, 0, stream>>>(A, lda, A2, W, B, Y, M, N, K, ldy, act);
  };

  prep_k<<<3072, 256, 0, stream>>>(off_w, off_b, aw_w, aw_b, reg_w1, reg_b1, cls_w1, cls_b1,
                                   cwA, cbA, cwB, cbB);
  init_k<<<900, 256, 0, stream>>>(qe, qpos, q);
  gemm(qpos, 256, nullptr, ref_w, ref_b, ref, ROWS, 3, 256, 3, 2);

  for (int i=0;i<NLAYER;++i) {
    const float* siw = sa_in_w + (size_t)i*768*256;
    const float* sib = sa_in_b + (size_t)i*768;
    // ---- self-attention ----
    gemmb(q, 256, qpos, siw, sib, QK, ROWS, 512, 256, 512, 0);               // Q|K
    gemmb(q, 256, nullptr, siw + 512*256, sib + 512, tB, ROWS, 256, 256, 256, 0); // V
    attn3_k<<<dim3(32,15), 256, 0, stream>>>(QK, tB, tA);
    gemmb(tA, 256, nullptr, sa_out_w + (size_t)i*65536, sa_out_b + (size_t)i*256, tB, ROWS, 256, 256, 256, 0);
    ln_k<<<900, 256, 0, stream>>>(tB, 256, q, ln_w + (size_t)(i*3+0)*256, ln_b + (size_t)(i*3+0)*256, q, 0);
    // ---- deformable cross-attention ----
    gemmb(q, 256, qpos, cwA + (size_t)i*96*256, cbA + i*96, offaw, ROWS, 96, 256, 96, 0);
    gather_k<<<ROWS, 512, 0, stream>>>(bev, offaw, ref, rr, sumw);
    proj_k<<<dim3(113,8), 256, 0, stream>>>(rr, sumw,
        vproj_w + (size_t)i*65536, vproj_b + (size_t)i*256, samp);
    gemmb(samp, 256, nullptr, oproj_w + (size_t)i*65536, oproj_b + (size_t)i*256, tA, ROWS, 256, 256, 256, 0);
    ln_k<<<900, 256, 0, stream>>>(tA, 256, q, ln_w + (size_t)(i*3+1)*256, ln_b + (size_t)(i*3+1)*256, q, 0);
    // ---- FFN ----
    gemmb(q, 256, nullptr, ffn_w1 + (size_t)i*512*256, ffn_b1 + (size_t)i*512, W5, ROWS, 512, 256, 512, 1);
    gemmb(W5, 512, nullptr, ffn_w2 + (size_t)i*256*512, ffn_b2 + (size_t)i*256, tA, ROWS, 256, 512, 256, 0);
    ln_k<<<900, 256, 0, stream>>>(tA, 256, q, ln_w + (size_t)(i*3+2)*256, ln_b + (size_t)(i*3+2)*256, q, 0);
    // ---- fused reg1|cls1 ----
    gemmb(q, 256, nullptr, cwB + (size_t)i*512*256, cbB + i*512, W5, ROWS, 512, 256, 512, 3);
    // ---- reg branch ----
    gemmb(W5, 512, nullptr, reg_w2 + (size_t)i*65536, reg_b2 + (size_t)i*256, tB, ROWS, 256, 256, 256, 1);
    // ---- cls branch ----
    ln_k<<<900, 256, 0, stream>>>(W5 + 256, 512, nullptr, cls_ln_w + (size_t)(i*2+0)*256, cls_ln_b + (size_t)(i*2+0)*256, samp, 1);
    gemmb(samp, 256, nullptr, cls_w2 + (size_t)i*65536, cls_b2 + (size_t)i*256, tA, ROWS, 256, 256, 256, 0);
    ln_k<<<900, 256, 0, stream>>>(tA, 256, nullptr, cls_ln_w + (size_t)(i*2+1)*256, cls_ln_b + (size_t)(i*2+1)*256, tA, 1);
    // ---- fused reg3+cls3+refupdate+output ----
    regcls3_k<<<(ROWS+31)/32, 256, 0, stream>>>(tB, tA,
        reg_w3 + (size_t)i*2560, reg_b3 + (size_t)i*10,
        cls_w3 + (size_t)i*2560, cls_b3 + (size_t)i*10,
        ref, out + (size_t)i*ROWS*20);
  }
}

// Round 6
// 1572.673 us; speedup vs baseline: 2.6940x; 1.1479x over previous
//
#include <hip/hip_runtime.h>
#include <math.h>

#define DD 256
#define NQQ 900
#define NBS 4
#define NLAYER 6
#define BEVH 200
#define BEVW 200
#define ROWS (NBS*NQQ)   // 3600

typedef __attribute__((ext_vector_type(8))) short bf16x8;
typedef __attribute__((ext_vector_type(4))) float f32x4;

__device__ __forceinline__ float sigmoidf_(float x){ return 1.0f/(1.0f+expf(-x)); }
__device__ __forceinline__ float invsigf_(float x){
  x = fminf(fmaxf(x,0.0f),1.0f);
  float lo = fmaxf(x,1e-5f), hi = fmaxf(1.0f-x,1e-5f);
  return logf(lo/hi);
}
__device__ __forceinline__ unsigned f2bf1(float x){
  unsigned u = __float_as_uint(x);
  return (u + 0x7fffu + ((u>>16)&1u)) >> 16;
}
__device__ __forceinline__ unsigned pk2(float a, float b){
  return f2bf1(a) | (f2bf1(b)<<16);
}
__device__ __forceinline__ float bf2f(unsigned u){ return __uint_as_float(u<<16); }
__device__ __forceinline__ ushort4 pk4(float4 y){
  ushort4 o; o.x=(ushort)f2bf1(y.x); o.y=(ushort)f2bf1(y.y);
  o.z=(ushort)f2bf1(y.z); o.w=(ushort)f2bf1(y.w); return o;
}

// ---------------------------------------------------------------------------
// fp32 GEMM (ref head only).
// ---------------------------------------------------------------------------
__global__ __launch_bounds__(256) void gemm_k(
    const float* __restrict__ A, int lda,
    const float* __restrict__ W, const float* __restrict__ B,
    float* __restrict__ Y, int M, int N, int K, int ldy, int act)
{
  __shared__ float As[2][32][66];
  __shared__ float Ws[2][32][66];
  const int t = threadIdx.x;
  const int m0 = blockIdx.x*64, n0 = blockIdx.y*64;
  const int lr = t >> 2, kq = (t & 3) << 3;
  const int tx = t & 15, ty = t >> 4;
  const bool aok = (m0 + lr) < M;
  const bool wok = (n0 + lr) < N;
  const float* ap  = A + (size_t)(m0+lr)*lda + kq;
  const float* wp  = W + (size_t)(n0+lr)*K + kq;
  float4 pa[2], pw[2];
  auto loadch = [&](int kc) {
    #pragma unroll
    for (int i=0;i<2;++i) {
      pa[i] = aok ? *(const float4*)(ap + kc + i*4) : make_float4(0,0,0,0);
      pw[i] = wok ? *(const float4*)(wp + kc + i*4) : make_float4(0,0,0,0);
    }
  };
  auto storech = [&](int bf) {
    #pragma unroll
    for (int i=0;i<2;++i) {
      const int kk = kq + i*4;
      As[bf][kk+0][lr]=pa[i].x; As[bf][kk+1][lr]=pa[i].y;
      As[bf][kk+2][lr]=pa[i].z; As[bf][kk+3][lr]=pa[i].w;
      Ws[bf][kk+0][lr]=pw[i].x; Ws[bf][kk+1][lr]=pw[i].y;
      Ws[bf][kk+2][lr]=pw[i].z; Ws[bf][kk+3][lr]=pw[i].w;
    }
  };
  float acc[4][4] = {};
  loadch(0); storech(0); __syncthreads();
  const int NC = K >> 5;
  for (int c=0; c<NC; ++c) {
    if (c+1 < NC) loadch((c+1) << 5);
    const int bf = c & 1;
    #pragma unroll
    for (int k=0;k<32;++k) {
      const float4 a4 = *(const float4*)&As[bf][k][ty<<2];
      const float4 w4 = *(const float4*)&Ws[bf][k][tx<<2];
      const float av[4] = {a4.x,a4.y,a4.z,a4.w};
      const float wv[4] = {w4.x,w4.y,w4.z,w4.w};
      #pragma unroll
      for (int r=0;r<4;++r)
        #pragma unroll
        for (int cc=0;cc<4;++cc) acc[r][cc] += av[r]*wv[cc];
    }
    if (c+1 < NC) { storech((c+1)&1); __syncthreads(); }
  }
  const int gn0 = n0 + (tx<<2);
  #pragma unroll
  for (int r=0;r<4;++r) {
    const int gm = m0 + (ty<<2) + r;
    if (gm >= M) continue;
    for (int cc=0; cc<4 && gn0+cc<N; ++cc) {
      float x = acc[r][cc] + (B ? B[gn0+cc] : 0.0f);
      if (act==1) x = fmaxf(x,0.0f);
      else if (act==2) x = sigmoidf_(x);
      Y[(size_t)gm*ldy + gn0+cc] = x;
    }
  }
}

// ---------------------------------------------------------------------------
// bf16 MFMA GEMM v2: A bf16 or f32 (abf), W bf16, out f32 or bf16 (obf).
// 64x64 tile, 4 waves, 2x2 frags of 16x16x32, XOR-swizzled LDS, dbuf.
// act: 0 none, 1 relu, 2 sigmoid, 3 relu on n<256
// ---------------------------------------------------------------------------
__global__ __launch_bounds__(256) void gemmb_k(
    const void* __restrict__ A, int lda, int abf,
    const ushort* __restrict__ W, const float* __restrict__ Bb,
    void* __restrict__ Y, int M, int N, int K, int ldy, int act, int obf)
{
  __shared__ ushort As[2][2048];
  __shared__ ushort Bs[2][2048];
  const int t = threadIdx.x;
  const int m0 = blockIdx.x*64, n0 = blockIdx.y*64;
  const int srow = t>>2, scb = t&3;
  const bool aok = (m0+srow) < M;
  const bool wok = (n0+srow) < N;
  const float*  apf = (const float*)A  + (size_t)(m0+srow)*lda + scb*8;
  const ushort* apb = (const ushort*)A + (size_t)(m0+srow)*lda + scb*8;
  const ushort* wp  = W + (size_t)(n0+srow)*K + scb*8;
  const int sidx = srow*32 + ((scb ^ (srow&3))<<3);
  const bf16x8 zf = {0,0,0,0,0,0,0,0};

  bf16x8 pa, pw;
  auto loadg = [&](int kc){
    if (abf) {
      pa = aok ? *(const bf16x8*)(apb+kc) : zf;
    } else if (aok) {
      const float4 a = *(const float4*)(apf+kc);
      const float4 c = *(const float4*)(apf+kc+4);
      union {bf16x8 v; unsigned u[4];} ua;
      ua.u[0]=pk2(a.x,a.y); ua.u[1]=pk2(a.z,a.w);
      ua.u[2]=pk2(c.x,c.y); ua.u[3]=pk2(c.z,c.w);
      pa = ua.v;
    } else pa = zf;
    pw = wok ? *(const bf16x8*)(wp+kc) : zf;
  };
  auto writes = [&](int bf){
    *(bf16x8*)&As[bf][sidx] = pa;
    *(bf16x8*)&Bs[bf][sidx] = pw;
  };

  const int wv = t>>6, lane = t&63;
  const int wr = wv>>1, wc = wv&1;
  const int fm = lane&15, kb = lane>>4;
  const int arow0 = wr*32 + fm, arow1 = arow0 + 16;
  const int bcol0 = wc*32 + fm, bcol1 = bcol0 + 16;
  const int ai0 = arow0*32 + ((kb^(arow0&3))<<3);
  const int ai1 = arow1*32 + ((kb^(arow1&3))<<3);
  const int bi0 = bcol0*32 + ((kb^(bcol0&3))<<3);
  const int bi1 = bcol1*32 + ((kb^(bcol1&3))<<3);
  f32x4 acc00={0,0,0,0}, acc01={0,0,0,0}, acc10={0,0,0,0}, acc11={0,0,0,0};

  loadg(0); writes(0); __syncthreads();
  const int NS = K>>5;
  for (int s=0; s<NS; ++s) {
    if (s+1<NS) loadg((s+1)<<5);
    const int bf = s&1;
    bf16x8 a0 = *(bf16x8*)&As[bf][ai0];
    bf16x8 a1 = *(bf16x8*)&As[bf][ai1];
    bf16x8 b0 = *(bf16x8*)&Bs[bf][bi0];
    bf16x8 b1 = *(bf16x8*)&Bs[bf][bi1];
    acc00 = __builtin_amdgcn_mfma_f32_16x16x32_bf16(a0,b0,acc00,0,0,0);
    acc01 = __builtin_amdgcn_mfma_f32_16x16x32_bf16(a0,b1,acc01,0,0,0);
    acc10 = __builtin_amdgcn_mfma_f32_16x16x32_bf16(a1,b0,acc10,0,0,0);
    acc11 = __builtin_amdgcn_mfma_f32_16x16x32_bf16(a1,b1,acc11,0,0,0);
    if (s+1<NS) { __syncthreads(); writes((s+1)&1); __syncthreads(); }
  }

  #pragma unroll
  for (int fr=0; fr<2; ++fr) {
    #pragma unroll
    for (int fc=0; fc<2; ++fc) {
      const f32x4 av = fr ? (fc ? acc11 : acc10) : (fc ? acc01 : acc00);
      const int col = n0 + wc*32 + fc*16 + fm;
      if (col >= N) continue;
      const float bias = Bb ? Bb[col] : 0.0f;
      #pragma unroll
      for (int r=0; r<4; ++r) {
        const int row = m0 + wr*32 + fr*16 + kb*4 + r;
        if (row >= M) continue;
        float x = av[r] + bias;
        if (act==1 || (act==3 && col<256)) x = fmaxf(x,0.0f);
        else if (act==2) x = sigmoidf_(x);
        if (obf) ((ushort*)Y)[(size_t)row*ldy + col] = (ushort)f2bf1(x);
        else     ((float*)Y)[(size_t)row*ldy + col] = x;
      }
    }
  }
}

// ---------------------------------------------------------------------------
// MFMA bf16 flash attention, bf16 I/O.
// ---------------------------------------------------------------------------
__global__ __launch_bounds__(256) void attn3_k(
    const ushort* __restrict__ QKb, const ushort* __restrict__ Vb, ushort* __restrict__ Ob)
{
  const int b = blockIdx.x >> 3, h = blockIdx.x & 7;
  const int wv = threadIdx.x >> 6, lane = threadIdx.x & 63;
  const int qt = blockIdx.y*64 + wv*16;
  if (qt >= NQQ) return;
  const int lq = lane & 15, lg = lane >> 4;
  const int q = qt + lq;

  bf16x8 qf = *(const bf16x8*)(QKb + (size_t)(b*NQQ + min(q, NQQ-1))*512 + h*32 + lg*8);
  f32x4 ot0 = {0.f,0.f,0.f,0.f}, ot1 = {0.f,0.f,0.f,0.f};
  float m = -3e38f, l = 0.0f;

  const ushort* kb = QKb + (size_t)b*NQQ*512 + 256 + h*32 + lg*8;
  const ushort* vb = Vb  + (size_t)b*NQQ*256 + h*32;
  const int pbase = (lq + ((lg&1)<<5)) << 2;
  const bool hiC = (lg >> 1);

  for (int k0 = 0; k0 < NQQ; k0 += 32) {
    const int r0 = min(k0 + lq, NQQ-1), r1 = min(k0 + 16 + lq, NQQ-1);
    bf16x8 kf0 = *(const bf16x8*)(kb + (size_t)r0*512);
    bf16x8 kf1 = *(const bf16x8*)(kb + (size_t)r1*512);
    const f32x4 z = {0.f,0.f,0.f,0.f};
    f32x4 s0 = __builtin_amdgcn_mfma_f32_16x16x32_bf16(kf0, qf, z, 0, 0, 0);
    f32x4 s1 = __builtin_amdgcn_mfma_f32_16x16x32_bf16(kf1, qf, z, 0, 0, 0);
    const float sc = 0.17677669529663687f;
    float p0[4], p1[4];
    #pragma unroll
    for (int r=0;r<4;++r) { p0[r] = s0[r]*sc; p1[r] = s1[r]*sc; }
    if (k0 + 32 > NQQ) {
      #pragma unroll
      for (int r=0;r<4;++r) {
        if (k0 + 4*lg + r      >= NQQ) p0[r] = -3e38f;
        if (k0 + 16 + 4*lg + r >= NQQ) p1[r] = -3e38f;
      }
    }
    float cm = fmaxf(fmaxf(fmaxf(p0[0],p0[1]),fmaxf(p0[2],p0[3])),
                     fmaxf(fmaxf(p1[0],p1[1]),fmaxf(p1[2],p1[3])));
    cm = fmaxf(cm, __shfl_xor(cm, 16));
    cm = fmaxf(cm, __shfl_xor(cm, 32));
    const float mn = fmaxf(m, cm);
    const float corr = __expf(m - mn);
    m = mn;
    float rs = 0.0f;
    #pragma unroll
    for (int r=0;r<4;++r) { p0[r] = __expf(p0[r]-mn); rs += p0[r]; }
    #pragma unroll
    for (int r=0;r<4;++r) { p1[r] = __expf(p1[r]-mn); rs += p1[r]; }
    rs += __shfl_xor(rs, 16);
    rs += __shfl_xor(rs, 32);
    l = l*corr + rs;
    ot0 *= corr; ot1 *= corr;

    const int c00 = (int)pk2(p0[0],p0[1]), c01 = (int)pk2(p0[2],p0[3]);
    const int c10 = (int)pk2(p1[0],p1[1]), c11 = (int)pk2(p1[2],p1[3]);
    const int A0 = __builtin_amdgcn_ds_bpermute(pbase,    c00);
    const int B0 = __builtin_amdgcn_ds_bpermute(pbase,    c10);
    const int A1 = __builtin_amdgcn_ds_bpermute(pbase,    c01);
    const int B1 = __builtin_amdgcn_ds_bpermute(pbase,    c11);
    const int A2 = __builtin_amdgcn_ds_bpermute(pbase+64, c00);
    const int B2 = __builtin_amdgcn_ds_bpermute(pbase+64, c10);
    const int A3 = __builtin_amdgcn_ds_bpermute(pbase+64, c01);
    const int B3 = __builtin_amdgcn_ds_bpermute(pbase+64, c11);
    union { bf16x8 v; int u[4]; } pv;
    pv.u[0] = hiC ? B0 : A0; pv.u[1] = hiC ? B1 : A1;
    pv.u[2] = hiC ? B2 : A2; pv.u[3] = hiC ? B3 : A3;

    bf16x8 vf0, vf1;
    {
      union { bf16x8 v; unsigned u[4]; } u0, u1;
      const int kvb = k0 + 8*lg;
      #pragma unroll
      for (int jj=0;jj<4;++jj) {
        const int ra = min(kvb + 2*jj,   NQQ-1);
        const int rb = min(kvb + 2*jj+1, NQQ-1);
        u0.u[jj] = (unsigned)vb[(size_t)ra*256 + lq]      | ((unsigned)vb[(size_t)rb*256 + lq]<<16);
        u1.u[jj] = (unsigned)vb[(size_t)ra*256 + 16 + lq] | ((unsigned)vb[(size_t)rb*256 + 16 + lq]<<16);
      }
      vf0 = u0.v; vf1 = u1.v;
    }
    ot0 = __builtin_amdgcn_mfma_f32_16x16x32_bf16(vf0, pv.v, ot0, 0, 0, 0);
    ot1 = __builtin_amdgcn_mfma_f32_16x16x32_bf16(vf1, pv.v, ot1, 0, 0, 0);
  }
  if (q < NQQ) {
    const float inv = 1.0f / l;
    ushort* op = Ob + (size_t)(b*NQQ + q)*256 + h*32;
    uint2 w0, w1;
    w0.x = pk2(ot0[0]*inv, ot0[1]*inv); w0.y = pk2(ot0[2]*inv, ot0[3]*inv);
    w1.x = pk2(ot1[0]*inv, ot1[1]*inv); w1.y = pk2(ot1[2]*inv, ot1[3]*inv);
    *(uint2*)(op + 4*lg)      = w0;
    *(uint2*)(op + 16 + 4*lg) = w1;
  }
}

// ---------------------------------------------------------------------------
// LayerNorm: Y=f32 out (opt), Yb=bf16 out (opt), Ypb=bf16(out+qpos) (opt).
// ---------------------------------------------------------------------------
__global__ __launch_bounds__(256) void ln_k(
    const float* X, int xld, const float* R,
    const float* __restrict__ w, const float* __restrict__ b,
    float* Y, ushort* Yb, const float* qpos, ushort* Ypb, int relu)
{
  const int row = blockIdx.x*4 + (threadIdx.x>>6);
  const int lane = threadIdx.x & 63;
  if (row >= ROWS) return;
  float4 x = *(const float4*)(X + (size_t)row*xld + (lane<<2));
  if (R) { const float4 r = *(const float4*)(R + (size_t)row*256 + (lane<<2)); x.x+=r.x; x.y+=r.y; x.z+=r.z; x.w+=r.w; }
  float s = x.x+x.y+x.z+x.w;
  #pragma unroll
  for (int o=32;o>0;o>>=1) s += __shfl_xor(s,o);
  const float mean = s * (1.0f/256.0f);
  float4 d; d.x=x.x-mean; d.y=x.y-mean; d.z=x.z-mean; d.w=x.w-mean;
  float s2 = d.x*d.x+d.y*d.y+d.z*d.z+d.w*d.w;
  #pragma unroll
  for (int o=32;o>0;o>>=1) s2 += __shfl_xor(s2,o);
  const float rs = rsqrtf(s2*(1.0f/256.0f) + 1e-5f);
  const float4 wv = *(const float4*)(w + (lane<<2));
  const float4 bv = *(const float4*)(b + (lane<<2));
  float4 y;
  y.x = d.x*rs*wv.x + bv.x; y.y = d.y*rs*wv.y + bv.y;
  y.z = d.z*rs*wv.z + bv.z; y.w = d.w*rs*wv.w + bv.w;
  if (relu) { y.x=fmaxf(y.x,0.f); y.y=fmaxf(y.y,0.f); y.z=fmaxf(y.z,0.f); y.w=fmaxf(y.w,0.f); }
  if (Y)  *(float4*)(Y + (size_t)row*256 + (lane<<2)) = y;
  if (Yb) *(ushort4*)(Yb + (size_t)row*256 + (lane<<2)) = pk4(y);
  if (Ypb) {
    const float4 qp = *(const float4*)(qpos + (size_t)row*256 + (lane<<2));
    float4 z; z.x=y.x+qp.x; z.y=y.y+qp.y; z.z=y.z+qp.z; z.w=y.w+qp.w;
    *(ushort4*)(Ypb + (size_t)row*256 + (lane<<2)) = pk4(z);
  }
}

// ---------------------------------------------------------------------------
// Deformable gather over bf16 bev. Grid 3600, block 512 (wave = head).
// ---------------------------------------------------------------------------
__global__ __launch_bounds__(512) void gather_k(
    const ushort* __restrict__ bevb, const float* __restrict__ offaw,
    const float* __restrict__ ref, ushort* __restrict__ rr, float* __restrict__ sumw)
{
  const int row = blockIdx.x;
  const int h = threadIdx.x >> 6, lane = threadIdx.x & 63;
  const int b = row / NQQ;
  const float refx = ref[row*3+0], refy = ref[row*3+1];
  const float* oa = offaw + (size_t)row*96;
  float aw[4];
  {
    const float a0=oa[64+h*4+0], a1=oa[64+h*4+1], a2=oa[64+h*4+2], a3=oa[64+h*4+3];
    const float mx = fmaxf(fmaxf(a0,a1), fmaxf(a2,a3));
    const float e0=__expf(a0-mx), e1=__expf(a1-mx), e2=__expf(a2-mx), e3=__expf(a3-mx);
    const float inv = 1.0f/(e0+e1+e2+e3);
    aw[0]=e0*inv; aw[1]=e1*inv; aw[2]=e2*inv; aw[3]=e3*inv;
  }
  float r0=0.f, r1=0.f, r2=0.f, r3=0.f, sacc=0.f;
  const ushort* bb = bevb + (size_t)b*BEVH*BEVW*DD;
  #pragma unroll
  for (int p=0;p<4;++p) {
    const float ox = oa[h*8+p*2+0], oy = oa[h*8+p*2+1];
    const float x = (refx + ox*(1.0f/BEVW))*BEVW - 0.5f;
    const float y = (refy + oy*(1.0f/BEVH))*BEVH - 0.5f;
    const float x0f = floorf(x), y0f = floorf(y);
    const int x0 = (int)x0f, y0 = (int)y0f;
    const float fx = x - x0f, fy = y - y0f;
    #pragma unroll
    for (int dy=0;dy<2;++dy) {
      #pragma unroll
      for (int dx=0;dx<2;++dx) {
        const int xi = x0+dx, yi = y0+dy;
        if (xi < 0 || xi >= BEVW || yi < 0 || yi >= BEVH) continue;
        const float wgt = (dx ? fx : 1.0f-fx) * (dy ? fy : 1.0f-fy) * aw[p];
        const ushort4 g = *(const ushort4*)(bb + (size_t)(yi*BEVW + xi)*DD + (lane<<2));
        r0 += wgt*bf2f(g.x); r1 += wgt*bf2f(g.y);
        r2 += wgt*bf2f(g.z); r3 += wgt*bf2f(g.w);
        sacc += wgt;
      }
    }
  }
  ushort4 o;
  o.x = (ushort)f2bf1(r0); o.y = (ushort)f2bf1(r1);
  o.z = (ushort)f2bf1(r2); o.w = (ushort)f2bf1(r3);
  *(ushort4*)&rr[((size_t)h*ROWS + row)*256 + (lane<<2)] = o;
  if (lane == 0) sumw[h*ROWS + row] = sacc;
}

// ---------------------------------------------------------------------------
// Deformable projection -> bf16 samp.
// ---------------------------------------------------------------------------
__global__ __launch_bounds__(256) void proj_k(
    const ushort* __restrict__ rr, const float* __restrict__ sumw,
    const float* __restrict__ vpw, const float* __restrict__ vpb,
    ushort* __restrict__ sampb)
{
  const int h = blockIdx.y;
  __shared__ float Ws[32*257];
  for (int i=threadIdx.x; i<8192; i+=256) {
    const int c = i>>8, k = i&255;
    Ws[c*257+k] = vpw[(size_t)((h<<5)+c)*256 + k];
  }
  __syncthreads();
  const int wv = threadIdx.x>>6, lane = threadIdx.x&63;
  const int c = lane&31, half = lane>>5;
  const float bias = vpb[(h<<5)+c];
  #pragma unroll
  for (int j=0;j<8;++j) {
    const int r = blockIdx.x*32 + wv*8 + j;
    if (r >= ROWS) break;
    const ushort* rp = rr + ((size_t)h*ROWS + r)*256 + half*128;
    const float* wb = &Ws[c*257 + half*128];
    float acc = 0.0f;
    #pragma unroll
    for (int jj=0;jj<32;++jj) {
      const uint2 u = *(const uint2*)(rp + jj*4);
      acc += bf2f(u.x & 0xffffu) * wb[jj*4+0];
      acc += bf2f(u.x >> 16)     * wb[jj*4+1];
      acc += bf2f(u.y & 0xffffu) * wb[jj*4+2];
      acc += bf2f(u.y >> 16)     * wb[jj*4+3];
    }
    acc += __shfl_xor(acc, 32);
    if (half == 0) sampb[(size_t)r*256 + (h<<5) + c] = (ushort)f2bf1(acc + bias*sumw[h*ROWS + r]);
  }
}

// ---------------------------------------------------------------------------
// Fused reg3 + cls3 + ref update + output write.
// ---------------------------------------------------------------------------
__global__ __launch_bounds__(256) void regcls3_k(
    const float* __restrict__ reg2o, const float* __restrict__ cls2o,
    const float* __restrict__ rw3, const float* __restrict__ rb3,
    const float* __restrict__ cw3, const float* __restrict__ cb3,
    float* __restrict__ ref, float* __restrict__ outL)
{
  __shared__ float Wr[10*272];
  __shared__ float Wc[10*272];
  for (int i=threadIdx.x; i<2560; i+=256) {
    const int o = i>>8, k = i&255;
    const int si = o*272 + (k>>6)*68 + (k&63);
    Wr[si] = rw3[i]; Wc[si] = cw3[i];
  }
  __syncthreads();
  const int t = threadIdx.x;
  const int row = t>>3, g = (t>>2)&1, sl = t&3;
  const int R = blockIdx.x*32 + row;
  const bool act = R < ROWS;
  const float* in = g ? cls2o : reg2o;
  const float* base = in + (size_t)(act?R:0)*256 + sl*64;
  const float* Wg = g ? Wc : Wr;
  float acc[10] = {};
  #pragma unroll
  for (int jj=0;jj<16;++jj) {
    const float4 v = *(const float4*)(base + 4*jj);
    #pragma unroll
    for (int o=0;o<10;++o) {
      const float4 w = *(const float4*)&Wg[o*272 + sl*68 + 4*jj];
      acc[o] += v.x*w.x + v.y*w.y + v.z*w.z + v.w*w.w;
    }
  }
  #pragma unroll
  for (int o=0;o<10;++o) {
    acc[o] += __shfl_xor(acc[o], 1);
    acc[o] += __shfl_xor(acc[o], 2);
  }
  if (act && sl == 0) {
    if (g) {
      float* oc = outL + (size_t)R*20;
      #pragma unroll
      for (int o=0;o<10;++o) oc[o] = acc[o] + cb3[o];
    } else {
      float tt[10];
      #pragma unroll
      for (int o=0;o<10;++o) tt[o] = acc[o] + rb3[o];
      const float rx = invsigf_(ref[R*3+0]);
      const float ry = invsigf_(ref[R*3+1]);
      const float rz = invsigf_(ref[R*3+2]);
      const float nx = sigmoidf_(tt[0]+rx);
      const float ny = sigmoidf_(tt[1]+ry);
      const float nz = sigmoidf_(tt[4]+rz);
      ref[R*3+0]=nx; ref[R*3+1]=ny; ref[R*3+2]=nz;
      float* o = outL + (size_t)R*20 + 10;
      o[0]=nx*102.4f-51.2f; o[1]=ny*102.4f-51.2f; o[2]=tt[2]; o[3]=tt[3];
      o[4]=nz*8.0f-5.0f; o[5]=tt[5]; o[6]=tt[6]; o[7]=tt[7]; o[8]=tt[8]; o[9]=tt[9];
    }
  }
}

__global__ void init_k(const float* __restrict__ qe, float* __restrict__ qpos,
                       float* __restrict__ q, ushort* __restrict__ qb, ushort* __restrict__ qpb)
{
  const int t = blockIdx.x*blockDim.x + threadIdx.x;
  const int row = t >> 6; const int cc = (t & 63) << 2;
  const int n = row % NQQ;
  const float4 vp = *(const float4*)(qe + (size_t)n*512 + cc);
  const float4 vq = *(const float4*)(qe + (size_t)n*512 + 256 + cc);
  *(float4*)(qpos + (size_t)row*256 + cc) = vp;
  *(float4*)(q    + (size_t)row*256 + cc) = vq;
  *(ushort4*)(qb  + (size_t)row*256 + cc) = pk4(vq);
  float4 s; s.x=vq.x+vp.x; s.y=vq.y+vp.y; s.z=vq.z+vp.z; s.w=vq.w+vp.w;
  *(ushort4*)(qpb + (size_t)row*256 + cc) = pk4(s);
}

// concat off_w|aw_w -> cwAb (bf16), reg_w1|cls_w1 -> cwBb (bf16), + f32 biases
__global__ void prep_k(const float* __restrict__ ow, const float* __restrict__ ob,
                       const float* __restrict__ aw, const float* __restrict__ ab,
                       const float* __restrict__ rw, const float* __restrict__ rb,
                       const float* __restrict__ cw, const float* __restrict__ cb,
                       ushort* cwAb, float* cbA, ushort* cwBb, float* cbB)
{
  const int i = blockIdx.x*blockDim.x + threadIdx.x;
  if (i < 6*96*256) {
    const int l = i/(96*256), r = (i/256)%96, k = i%256;
    const float v = (r<64) ? ow[((size_t)l*64 + r)*256 + k] : aw[((size_t)l*32 + (r-64))*256 + k];
    cwAb[i] = (ushort)f2bf1(v);
  }
  if (i < 576) { const int l = i/96, r = i%96; cbA[i] = (r<64) ? ob[l*64+r] : ab[l*32 + r-64]; }
  if (i < 6*512*256) {
    const int l = i/(512*256), r = (i/256)%512, k = i%256;
    const float v = (r<256) ? rw[((size_t)l*256+r)*256+k] : cw[((size_t)l*256 + (r-256))*256 + k];
    cwBb[i] = (ushort)f2bf1(v);
  }
  if (i < 3072) { const int l = i/512, r = i%512; cbB[i] = (r<256) ? rb[l*256+r] : cb[l*256 + r-256]; }
}

// convert 7 weight tensors to bf16 into one contiguous dst
__global__ void cvtw_k(const float* __restrict__ s1, const float* __restrict__ s2,
                       const float* __restrict__ s3, const float* __restrict__ s4,
                       const float* __restrict__ s5, const float* __restrict__ s6,
                       const float* __restrict__ s7, ushort* __restrict__ dst)
{
  const int i4 = (blockIdx.x*256 + threadIdx.x)*4;
  if (i4 >= 4325376) return;
  const float* src; int lo;
  if      (i4 < 1179648) { src=s1; lo=i4; }
  else if (i4 < 1572864) { src=s2; lo=i4-1179648; }
  else if (i4 < 1966080) { src=s3; lo=i4-1572864; }
  else if (i4 < 2752512) { src=s4; lo=i4-1966080; }
  else if (i4 < 3538944) { src=s5; lo=i4-2752512; }
  else if (i4 < 3932160) { src=s6; lo=i4-3538944; }
  else                   { src=s7; lo=i4-3932160; }
  const float4 v = *(const float4*)(src+lo);
  *(ushort4*)(dst+i4) = pk4(v);
}

__global__ void cvtbev_k(const float* __restrict__ bev, ushort* __restrict__ bevb)
{
  const size_t i = ((size_t)blockIdx.x*256 + threadIdx.x)*8;
  const float4 a = *(const float4*)(bev+i);
  const float4 b = *(const float4*)(bev+i+4);
  *(ushort4*)(bevb+i)   = pk4(a);
  *(ushort4*)(bevb+i+4) = pk4(b);
}

extern "C" void kernel_launch(void* const* d_in, const int* in_sizes, int n_in,
                              void* d_out, int out_size, void* d_ws, size_t ws_size,
                              hipStream_t stream)
{
  const float* bev      = (const float*)d_in[0];
  const float* qe       = (const float*)d_in[1];
  const float* ref_w    = (const float*)d_in[2];
  const float* ref_b    = (const float*)d_in[3];
  const float* sa_in_w  = (const float*)d_in[4];
  const float* sa_in_b  = (const float*)d_in[5];
  const float* sa_out_w = (const float*)d_in[6];
  const float* sa_out_b = (const float*)d_in[7];
  const float* ln_w     = (const float*)d_in[8];
  const float* ln_b     = (const float*)d_in[9];
  const float* off_w    = (const float*)d_in[10];
  const float* off_b    = (const float*)d_in[11];
  const float* aw_w     = (const float*)d_in[12];
  const float* aw_b     = (const float*)d_in[13];
  const float* vproj_w  = (const float*)d_in[14];
  const float* vproj_b  = (const float*)d_in[15];
  const float* oproj_w  = (const float*)d_in[16];
  const float* oproj_b  = (const float*)d_in[17];
  const float* ffn_w1   = (const float*)d_in[18];
  const float* ffn_b1   = (const float*)d_in[19];
  const float* ffn_w2   = (const float*)d_in[20];
  const float* ffn_b2   = (const float*)d_in[21];
  const float* reg_w1   = (const float*)d_in[22];
  const float* reg_b1   = (const float*)d_in[23];
  const float* reg_w2   = (const float*)d_in[24];
  const float* reg_b2   = (const float*)d_in[25];
  const float* reg_w3   = (const float*)d_in[26];
  const float* reg_b3   = (const float*)d_in[27];
  const float* cls_w1   = (const float*)d_in[28];
  const float* cls_b1   = (const float*)d_in[29];
  const float* cls_w2   = (const float*)d_in[30];
  const float* cls_b2   = (const float*)d_in[31];
  const float* cls_w3   = (const float*)d_in[32];
  const float* cls_b3   = (const float*)d_in[33];
  const float* cls_ln_w = (const float*)d_in[34];
  const float* cls_ln_b = (const float*)d_in[35];
  float* out = (float*)d_out;

  float* ws   = (float*)d_ws;
  float* qpos = ws;                    // 921600
  float* q    = qpos + 921600;
  float* tA   = q    + 921600;
  float* tB   = tA   + 921600;
  float* W5   = tB   + 921600;         // 1843200
  float* offaw= W5   + 1843200;        // 345600
  float* ref  = offaw+ 345600;         // 10800
  float* sumw = ref  + 10800;          // 28800
  float* cbA  = sumw + 28800;          // 576
  float* cbB  = cbA  + 576;            // 3072
  // ushort region (16B aligned: 5918448*4 bytes)
  ushort* usb  = (ushort*)(ws + 5918448);
  ushort* QKb  = usb;                  // 1843200
  ushort* Vb   = usb + 1843200;        // 921600
  ushort* tAb  = usb + 2764800;        // 921600
  ushort* W5b  = usb + 3686400;        // 1843200
  ushort* sampb= usb + 5529600;        // 921600
  ushort* qb   = usb + 6451200;        // 921600
  ushort* qpb  = usb + 7372800;        // 921600
  ushort* clsb = usb + 8294400;        // 921600
  ushort* rr   = usb + 9216000;        // 7372800
  ushort* bevb = usb + 16588800;       // 40960000
  ushort* wbf  = usb + 57548800;       // 4325376 + 147456 + 786432
  ushort* siwb = wbf;
  ushort* sowb = wbf + 1179648;
  ushort* opwb = wbf + 1572864;
  ushort* f1wb = wbf + 1966080;
  ushort* f2wb = wbf + 2752512;
  ushort* r2wb = wbf + 3538944;
  ushort* c2wb = wbf + 3932160;
  ushort* cwAb = wbf + 4325376;
  ushort* cwBb = wbf + 4472832;

  auto gemmb = [&](const void* A, int lda, int abf, const ushort* W, const float* B,
                   void* Y, int M, int N, int K, int ldy, int act, int obf) {
    dim3 grid((M+63)/64, (N+63)/64);
    gemmb_k<<<grid, 256, 0, stream>>>(A, lda, abf, W, B, Y, M, N, K, ldy, act, obf);
  };

  // one-time converts + prep
  cvtbev_k<<<20000, 256, 0, stream>>>(bev, bevb);
  cvtw_k<<<4224, 256, 0, stream>>>(sa_in_w, sa_out_w, oproj_w, ffn_w1, ffn_w2, reg_w2, cls_w2, wbf);
  prep_k<<<3072, 256, 0, stream>>>(off_w, off_b, aw_w, aw_b, reg_w1, reg_b1, cls_w1, cls_b1,
                                   cwAb, cbA, cwBb, cbB);
  init_k<<<900, 256, 0, stream>>>(qe, qpos, q, qb, qpb);
  {
    dim3 grid((ROWS+63)/64, 1);
    gemm_k<<<grid, 256, 0, stream>>>(qpos, 256, ref_w, ref_b, ref, ROWS, 3, 256, 3, 2);
  }

  for (int i=0;i<NLAYER;++i) {
    const float* sib = sa_in_b + (size_t)i*768;
    // ---- self-attention ----
    gemmb(qpb, 256, 1, siwb + (size_t)i*196608, sib, QKb, ROWS, 512, 256, 512, 0, 1);
    gemmb(qb,  256, 1, siwb + (size_t)i*196608 + 512*256, sib + 512, Vb, ROWS, 256, 256, 256, 0, 1);
    attn3_k<<<dim3(32,15), 256, 0, stream>>>(QKb, Vb, tAb);
    gemmb(tAb, 256, 1, sowb + (size_t)i*65536, sa_out_b + (size_t)i*256, tB, ROWS, 256, 256, 256, 0, 0);
    ln_k<<<900, 256, 0, stream>>>(tB, 256, q, ln_w + (size_t)(i*3+0)*256, ln_b + (size_t)(i*3+0)*256,
                                  q, nullptr, qpos, qpb, 0);
    // ---- deformable cross-attention ----
    gemmb(qpb, 256, 1, cwAb + (size_t)i*24576, cbA + i*96, offaw, ROWS, 96, 256, 96, 0, 0);
    gather_k<<<ROWS, 512, 0, stream>>>(bevb, offaw, ref, rr, sumw);
    proj_k<<<dim3(113,8), 256, 0, stream>>>(rr, sumw,
        vproj_w + (size_t)i*65536, vproj_b + (size_t)i*256, sampb);
    gemmb(sampb, 256, 1, opwb + (size_t)i*65536, oproj_b + (size_t)i*256, tA, ROWS, 256, 256, 256, 0, 0);
    ln_k<<<900, 256, 0, stream>>>(tA, 256, q, ln_w + (size_t)(i*3+1)*256, ln_b + (size_t)(i*3+1)*256,
                                  q, qb, nullptr, nullptr, 0);
    // ---- FFN ----
    gemmb(qb, 256, 1, f1wb + (size_t)i*131072, ffn_b1 + (size_t)i*512, W5b, ROWS, 512, 256, 512, 1, 1);
    gemmb(W5b, 512, 1, f2wb + (size_t)i*131072, ffn_b2 + (size_t)i*256, tA, ROWS, 256, 512, 256, 0, 0);
    ln_k<<<900, 256, 0, stream>>>(tA, 256, q, ln_w + (size_t)(i*3+2)*256, ln_b + (size_t)(i*3+2)*256,
                                  q, qb, qpos, qpb, 0);
    // ---- fused reg1|cls1 ----
    gemmb(qb, 256, 1, cwBb + (size_t)i*131072, cbB + i*512, W5, ROWS, 512, 256, 512, 3, 0);
    // ---- reg branch ----
    gemmb(W5, 512, 0, r2wb + (size_t)i*65536, reg_b2 + (size_t)i*256, tB, ROWS, 256, 256, 256, 1, 0);
    // ---- cls branch ----
    ln_k<<<900, 256, 0, stream>>>(W5 + 256, 512, nullptr,
                                  cls_ln_w + (size_t)(i*2+0)*256, cls_ln_b + (size_t)(i*2+0)*256,
                                  nullptr, clsb, nullptr, nullptr, 1);
    gemmb(clsb, 256, 1, c2wb + (size_t)i*65536, cls_b2 + (size_t)i*256, tA, ROWS, 256, 256, 256, 0, 0);
    ln_k<<<900, 256, 0, stream>>>(tA, 256, nullptr,
                                  cls_ln_w + (size_t)(i*2+1)*256, cls_ln_b + (size_t)(i*2+1)*256,
                                  tA, nullptr, nullptr, nullptr, 1);
    // ---- fused reg3+cls3+refupdate+output ----
    regcls3_k<<<(ROWS+31)/32, 256, 0, stream>>>(tB, tA,
        reg_w3 + (size_t)i*2560, reg_b3 + (size_t)i*10,
        cls_w3 + (size_t)i*2560, cls_b3 + (size_t)i*10,
        ref, out + (size_t)i*ROWS*20);
  }
}

// Round 7
// 1380.150 us; speedup vs baseline: 3.0698x; 1.1395x over previous
//
#include <hip/hip_runtime.h>
#include <math.h>

#define DD 256
#define NQQ 900
#define NBS 4
#define NLAYER 6
#define BEVH 200
#define BEVW 200
#define ROWS (NBS*NQQ)   // 3600
#define BIGN (1<<30)

typedef __attribute__((ext_vector_type(8))) short bf16x8;
typedef __attribute__((ext_vector_type(4))) float f32x4;

__device__ __forceinline__ float sigmoidf_(float x){ return 1.0f/(1.0f+expf(-x)); }
__device__ __forceinline__ float invsigf_(float x){
  x = fminf(fmaxf(x,0.0f),1.0f);
  float lo = fmaxf(x,1e-5f), hi = fmaxf(1.0f-x,1e-5f);
  return logf(lo/hi);
}
__device__ __forceinline__ unsigned f2bf1(float x){
  unsigned u = __float_as_uint(x);
  return (u + 0x7fffu + ((u>>16)&1u)) >> 16;
}
__device__ __forceinline__ unsigned pk2(float a, float b){
  return f2bf1(a) | (f2bf1(b)<<16);
}
__device__ __forceinline__ float bf2f(unsigned u){ return __uint_as_float(u<<16); }
__device__ __forceinline__ ushort4 pk4(float4 y){
  ushort4 o; o.x=(ushort)f2bf1(y.x); o.y=(ushort)f2bf1(y.y);
  o.z=(ushort)f2bf1(y.z); o.w=(ushort)f2bf1(y.w); return o;
}

// ---------------------------------------------------------------------------
// fp32 GEMM (ref head only).
// ---------------------------------------------------------------------------
__global__ __launch_bounds__(256) void gemm_k(
    const float* __restrict__ A, int lda,
    const float* __restrict__ W, const float* __restrict__ B,
    float* __restrict__ Y, int M, int N, int K, int ldy, int act)
{
  __shared__ float As[2][32][66];
  __shared__ float Ws[2][32][66];
  const int t = threadIdx.x;
  const int m0 = blockIdx.x*64, n0 = blockIdx.y*64;
  const int lr = t >> 2, kq = (t & 3) << 3;
  const int tx = t & 15, ty = t >> 4;
  const bool aok = (m0 + lr) < M;
  const bool wok = (n0 + lr) < N;
  const float* ap  = A + (size_t)(m0+lr)*lda + kq;
  const float* wp  = W + (size_t)(n0+lr)*K + kq;
  float4 pa[2], pw[2];
  auto loadch = [&](int kc) {
    #pragma unroll
    for (int i=0;i<2;++i) {
      pa[i] = aok ? *(const float4*)(ap + kc + i*4) : make_float4(0,0,0,0);
      pw[i] = wok ? *(const float4*)(wp + kc + i*4) : make_float4(0,0,0,0);
    }
  };
  auto storech = [&](int bf) {
    #pragma unroll
    for (int i=0;i<2;++i) {
      const int kk = kq + i*4;
      As[bf][kk+0][lr]=pa[i].x; As[bf][kk+1][lr]=pa[i].y;
      As[bf][kk+2][lr]=pa[i].z; As[bf][kk+3][lr]=pa[i].w;
      Ws[bf][kk+0][lr]=pw[i].x; Ws[bf][kk+1][lr]=pw[i].y;
      Ws[bf][kk+2][lr]=pw[i].z; Ws[bf][kk+3][lr]=pw[i].w;
    }
  };
  float acc[4][4] = {};
  loadch(0); storech(0); __syncthreads();
  const int NC = K >> 5;
  for (int c=0; c<NC; ++c) {
    if (c+1 < NC) loadch((c+1) << 5);
    const int bf = c & 1;
    #pragma unroll
    for (int k=0;k<32;++k) {
      const float4 a4 = *(const float4*)&As[bf][k][ty<<2];
      const float4 w4 = *(const float4*)&Ws[bf][k][tx<<2];
      const float av[4] = {a4.x,a4.y,a4.z,a4.w};
      const float wv[4] = {w4.x,w4.y,w4.z,w4.w};
      #pragma unroll
      for (int r=0;r<4;++r)
        #pragma unroll
        for (int cc=0;cc<4;++cc) acc[r][cc] += av[r]*wv[cc];
    }
    if (c+1 < NC) { storech((c+1)&1); __syncthreads(); }
  }
  const int gn0 = n0 + (tx<<2);
  #pragma unroll
  for (int r=0;r<4;++r) {
    const int gm = m0 + (ty<<2) + r;
    if (gm >= M) continue;
    for (int cc=0; cc<4 && gn0+cc<N; ++cc) {
      float x = acc[r][cc] + (B ? B[gn0+cc] : 0.0f);
      if (act==1) x = fmaxf(x,0.0f);
      else if (act==2) x = sigmoidf_(x);
      Y[(size_t)gm*ldy + gn0+cc] = x;
    }
  }
}

// ---------------------------------------------------------------------------
// bf16 MFMA GEMM v3: templated BM (64 or 32), BN=64.
// Dual-A (select by n0<NA), dual-W (row split at NW), dual-bias (split NB),
// dual-Y (split NY, independent ld/dtype). ReLU applied iff col < reluN.
// ---------------------------------------------------------------------------
template<int BM>
__global__ __launch_bounds__(256) void gemmb_k(
    const ushort* __restrict__ A0, const ushort* __restrict__ A1, int NA, int lda,
    const ushort* __restrict__ W0, const ushort* __restrict__ W1, int NW,
    const float* __restrict__ B0, const float* __restrict__ B1, int NB,
    void* __restrict__ Y0, int ldy0, int obf0,
    void* __restrict__ Y1, int ldy1, int obf1, int NY,
    int M, int N, int K, int reluN)
{
  __shared__ ushort As[2][BM*32];
  __shared__ ushort Bs[2][2048];
  const int t = threadIdx.x;
  const int m0 = blockIdx.x*BM, n0 = blockIdx.y*64;
  const ushort* A = (n0 < NA) ? A0 : A1;
  const int srow = t>>2, scb = t&3;
  const int wrow = n0 + srow;
  const bool wok = wrow < N;
  const ushort* wp = (wrow < NW) ? (W0 + (size_t)wrow*K + scb*8)
                                 : (W1 + (size_t)(wrow-NW)*K + scb*8);
  bool aok; const ushort* ap;
  if constexpr (BM==64) { aok = (m0+srow)<M; }
  else { aok = (t<128) && (m0+srow)<M; }
  ap = A + (size_t)(m0 + (aok?srow:0))*lda + scb*8;
  const int sidx = srow*32 + ((scb ^ (srow&3))<<3);
  const bf16x8 zf = {0,0,0,0,0,0,0,0};

  bf16x8 pa, pw;
  auto loadg = [&](int kc){
    pa = aok ? *(const bf16x8*)(ap+kc) : zf;
    pw = wok ? *(const bf16x8*)(wp+kc) : zf;
  };
  auto writes = [&](int bf){
    if (BM==64 || t<128) *(bf16x8*)&As[bf][sidx] = pa;
    *(bf16x8*)&Bs[bf][sidx] = pw;
  };

  const int wv = t>>6, lane = t&63;
  const int fm = lane&15, kb = lane>>4;

  auto writeout = [&](float x, int row, int col){
    if (row >= M || col >= N) return;
    if (col < reluN) x = fmaxf(x, 0.0f);
    if (col < NY) {
      if (obf0) ((ushort*)Y0)[(size_t)row*ldy0 + col] = (ushort)f2bf1(x);
      else      ((float*)Y0)[(size_t)row*ldy0 + col] = x;
    } else {
      const int c2 = col - NY;
      if (obf1) ((ushort*)Y1)[(size_t)row*ldy1 + c2] = (ushort)f2bf1(x);
      else      ((float*)Y1)[(size_t)row*ldy1 + c2] = x;
    }
  };

  const int NS = K>>5;
  if constexpr (BM==64) {
    const int wr = wv>>1, wc = wv&1;
    const int arow0 = wr*32 + fm, arow1 = arow0 + 16;
    const int bcol0 = wc*32 + fm, bcol1 = bcol0 + 16;
    const int ai0 = arow0*32 + ((kb^(arow0&3))<<3);
    const int ai1 = arow1*32 + ((kb^(arow1&3))<<3);
    const int bi0 = bcol0*32 + ((kb^(bcol0&3))<<3);
    const int bi1 = bcol1*32 + ((kb^(bcol1&3))<<3);
    f32x4 acc00={0,0,0,0}, acc01={0,0,0,0}, acc10={0,0,0,0}, acc11={0,0,0,0};
    loadg(0); writes(0); __syncthreads();
    for (int s=0; s<NS; ++s) {
      if (s+1<NS) loadg((s+1)<<5);
      const int bf = s&1;
      bf16x8 a0 = *(bf16x8*)&As[bf][ai0];
      bf16x8 a1 = *(bf16x8*)&As[bf][ai1];
      bf16x8 b0 = *(bf16x8*)&Bs[bf][bi0];
      bf16x8 b1 = *(bf16x8*)&Bs[bf][bi1];
      acc00 = __builtin_amdgcn_mfma_f32_16x16x32_bf16(a0,b0,acc00,0,0,0);
      acc01 = __builtin_amdgcn_mfma_f32_16x16x32_bf16(a0,b1,acc01,0,0,0);
      acc10 = __builtin_amdgcn_mfma_f32_16x16x32_bf16(a1,b0,acc10,0,0,0);
      acc11 = __builtin_amdgcn_mfma_f32_16x16x32_bf16(a1,b1,acc11,0,0,0);
      if (s+1<NS) { __syncthreads(); writes((s+1)&1); __syncthreads(); }
    }
    #pragma unroll
    for (int fr=0; fr<2; ++fr)
      #pragma unroll
      for (int fc=0; fc<2; ++fc) {
        const f32x4 av = fr ? (fc ? acc11 : acc10) : (fc ? acc01 : acc00);
        const int col = n0 + wc*32 + fc*16 + fm;
        const float bias = (col<N) ? ((col<NB) ? B0[col] : B1[col-NB]) : 0.0f;
        #pragma unroll
        for (int r=0; r<4; ++r)
          writeout(av[r] + bias, m0 + wr*32 + fr*16 + kb*4 + r, col);
      }
  } else {
    const int ai0 = fm*32 + ((kb^(fm&3))<<3);
    const int ai1 = (fm+16)*32 + ((kb^(fm&3))<<3);
    const int bcol = wv*16 + fm;
    const int bi = bcol*32 + ((kb^(bcol&3))<<3);
    f32x4 acc0={0,0,0,0}, acc1={0,0,0,0};
    loadg(0); writes(0); __syncthreads();
    for (int s=0; s<NS; ++s) {
      if (s+1<NS) loadg((s+1)<<5);
      const int bf = s&1;
      bf16x8 a0 = *(bf16x8*)&As[bf][ai0];
      bf16x8 a1 = *(bf16x8*)&As[bf][ai1];
      bf16x8 b  = *(bf16x8*)&Bs[bf][bi];
      acc0 = __builtin_amdgcn_mfma_f32_16x16x32_bf16(a0,b,acc0,0,0,0);
      acc1 = __builtin_amdgcn_mfma_f32_16x16x32_bf16(a1,b,acc1,0,0,0);
      if (s+1<NS) { __syncthreads(); writes((s+1)&1); __syncthreads(); }
    }
    const int col = n0 + wv*16 + fm;
    const float bias = (col<N) ? ((col<NB) ? B0[col] : B1[col-NB]) : 0.0f;
    #pragma unroll
    for (int r=0; r<4; ++r) {
      writeout(acc0[r] + bias, m0 + kb*4 + r, col);
      writeout(acc1[r] + bias, m0 + 16 + kb*4 + r, col);
    }
  }
}

// ---------------------------------------------------------------------------
// MFMA bf16 flash attention, bf16 I/O.
// ---------------------------------------------------------------------------
__global__ __launch_bounds__(256) void attn3_k(
    const ushort* __restrict__ QKb, const ushort* __restrict__ Vb, ushort* __restrict__ Ob)
{
  const int b = blockIdx.x >> 3, h = blockIdx.x & 7;
  const int wv = threadIdx.x >> 6, lane = threadIdx.x & 63;
  const int qt = blockIdx.y*64 + wv*16;
  if (qt >= NQQ) return;
  const int lq = lane & 15, lg = lane >> 4;
  const int q = qt + lq;

  bf16x8 qf = *(const bf16x8*)(QKb + (size_t)(b*NQQ + min(q, NQQ-1))*512 + h*32 + lg*8);
  f32x4 ot0 = {0.f,0.f,0.f,0.f}, ot1 = {0.f,0.f,0.f,0.f};
  float m = -3e38f, l = 0.0f;

  const ushort* kb = QKb + (size_t)b*NQQ*512 + 256 + h*32 + lg*8;
  const ushort* vb = Vb  + (size_t)b*NQQ*256 + h*32;
  const int pbase = (lq + ((lg&1)<<5)) << 2;
  const bool hiC = (lg >> 1);

  for (int k0 = 0; k0 < NQQ; k0 += 32) {
    const int r0 = min(k0 + lq, NQQ-1), r1 = min(k0 + 16 + lq, NQQ-1);
    bf16x8 kf0 = *(const bf16x8*)(kb + (size_t)r0*512);
    bf16x8 kf1 = *(const bf16x8*)(kb + (size_t)r1*512);
    const f32x4 z = {0.f,0.f,0.f,0.f};
    f32x4 s0 = __builtin_amdgcn_mfma_f32_16x16x32_bf16(kf0, qf, z, 0, 0, 0);
    f32x4 s1 = __builtin_amdgcn_mfma_f32_16x16x32_bf16(kf1, qf, z, 0, 0, 0);
    const float sc = 0.17677669529663687f;
    float p0[4], p1[4];
    #pragma unroll
    for (int r=0;r<4;++r) { p0[r] = s0[r]*sc; p1[r] = s1[r]*sc; }
    if (k0 + 32 > NQQ) {
      #pragma unroll
      for (int r=0;r<4;++r) {
        if (k0 + 4*lg + r      >= NQQ) p0[r] = -3e38f;
        if (k0 + 16 + 4*lg + r >= NQQ) p1[r] = -3e38f;
      }
    }
    float cm = fmaxf(fmaxf(fmaxf(p0[0],p0[1]),fmaxf(p0[2],p0[3])),
                     fmaxf(fmaxf(p1[0],p1[1]),fmaxf(p1[2],p1[3])));
    cm = fmaxf(cm, __shfl_xor(cm, 16));
    cm = fmaxf(cm, __shfl_xor(cm, 32));
    const float mn = fmaxf(m, cm);
    const float corr = __expf(m - mn);
    m = mn;
    float rs = 0.0f;
    #pragma unroll
    for (int r=0;r<4;++r) { p0[r] = __expf(p0[r]-mn); rs += p0[r]; }
    #pragma unroll
    for (int r=0;r<4;++r) { p1[r] = __expf(p1[r]-mn); rs += p1[r]; }
    rs += __shfl_xor(rs, 16);
    rs += __shfl_xor(rs, 32);
    l = l*corr + rs;
    ot0 *= corr; ot1 *= corr;

    const int c00 = (int)pk2(p0[0],p0[1]), c01 = (int)pk2(p0[2],p0[3]);
    const int c10 = (int)pk2(p1[0],p1[1]), c11 = (int)pk2(p1[2],p1[3]);
    const int A0 = __builtin_amdgcn_ds_bpermute(pbase,    c00);
    const int B0 = __builtin_amdgcn_ds_bpermute(pbase,    c10);
    const int A1 = __builtin_amdgcn_ds_bpermute(pbase,    c01);
    const int B1 = __builtin_amdgcn_ds_bpermute(pbase,    c11);
    const int A2 = __builtin_amdgcn_ds_bpermute(pbase+64, c00);
    const int B2 = __builtin_amdgcn_ds_bpermute(pbase+64, c10);
    const int A3 = __builtin_amdgcn_ds_bpermute(pbase+64, c01);
    const int B3 = __builtin_amdgcn_ds_bpermute(pbase+64, c11);
    union { bf16x8 v; int u[4]; } pv;
    pv.u[0] = hiC ? B0 : A0; pv.u[1] = hiC ? B1 : A1;
    pv.u[2] = hiC ? B2 : A2; pv.u[3] = hiC ? B3 : A3;

    bf16x8 vf0, vf1;
    {
      union { bf16x8 v; unsigned u[4]; } u0, u1;
      const int kvb = k0 + 8*lg;
      #pragma unroll
      for (int jj=0;jj<4;++jj) {
        const int ra = min(kvb + 2*jj,   NQQ-1);
        const int rb = min(kvb + 2*jj+1, NQQ-1);
        u0.u[jj] = (unsigned)vb[(size_t)ra*256 + lq]      | ((unsigned)vb[(size_t)rb*256 + lq]<<16);
        u1.u[jj] = (unsigned)vb[(size_t)ra*256 + 16 + lq] | ((unsigned)vb[(size_t)rb*256 + 16 + lq]<<16);
      }
      vf0 = u0.v; vf1 = u1.v;
    }
    ot0 = __builtin_amdgcn_mfma_f32_16x16x32_bf16(vf0, pv.v, ot0, 0, 0, 0);
    ot1 = __builtin_amdgcn_mfma_f32_16x16x32_bf16(vf1, pv.v, ot1, 0, 0, 0);
  }
  if (q < NQQ) {
    const float inv = 1.0f / l;
    ushort* op = Ob + (size_t)(b*NQQ + q)*256 + h*32;
    uint2 w0, w1;
    w0.x = pk2(ot0[0]*inv, ot0[1]*inv); w0.y = pk2(ot0[2]*inv, ot0[3]*inv);
    w1.x = pk2(ot1[0]*inv, ot1[1]*inv); w1.y = pk2(ot1[2]*inv, ot1[3]*inv);
    *(uint2*)(op + 4*lg)      = w0;
    *(uint2*)(op + 16 + 4*lg) = w1;
  }
}

// ---------------------------------------------------------------------------
// LayerNorm: optional f32 out, bf16 out, bf16(out+qpos) out.
// ---------------------------------------------------------------------------
__global__ __launch_bounds__(256) void ln_k(
    const float* X, int xld, const float* R,
    const float* __restrict__ w, const float* __restrict__ b,
    float* Y, ushort* Yb, const float* qpos, ushort* Ypb, int relu)
{
  const int row = blockIdx.x*4 + (threadIdx.x>>6);
  const int lane = threadIdx.x & 63;
  if (row >= ROWS) return;
  float4 x = *(const float4*)(X + (size_t)row*xld + (lane<<2));
  if (R) { const float4 r = *(const float4*)(R + (size_t)row*256 + (lane<<2)); x.x+=r.x; x.y+=r.y; x.z+=r.z; x.w+=r.w; }
  float s = x.x+x.y+x.z+x.w;
  #pragma unroll
  for (int o=32;o>0;o>>=1) s += __shfl_xor(s,o);
  const float mean = s * (1.0f/256.0f);
  float4 d; d.x=x.x-mean; d.y=x.y-mean; d.z=x.z-mean; d.w=x.w-mean;
  float s2 = d.x*d.x+d.y*d.y+d.z*d.z+d.w*d.w;
  #pragma unroll
  for (int o=32;o>0;o>>=1) s2 += __shfl_xor(s2,o);
  const float rs = rsqrtf(s2*(1.0f/256.0f) + 1e-5f);
  const float4 wv = *(const float4*)(w + (lane<<2));
  const float4 bv = *(const float4*)(b + (lane<<2));
  float4 y;
  y.x = d.x*rs*wv.x + bv.x; y.y = d.y*rs*wv.y + bv.y;
  y.z = d.z*rs*wv.z + bv.z; y.w = d.w*rs*wv.w + bv.w;
  if (relu) { y.x=fmaxf(y.x,0.f); y.y=fmaxf(y.y,0.f); y.z=fmaxf(y.z,0.f); y.w=fmaxf(y.w,0.f); }
  if (Y)  *(float4*)(Y + (size_t)row*256 + (lane<<2)) = y;
  if (Yb) *(ushort4*)(Yb + (size_t)row*256 + (lane<<2)) = pk4(y);
  if (Ypb) {
    const float4 qp = *(const float4*)(qpos + (size_t)row*256 + (lane<<2));
    float4 z; z.x=y.x+qp.x; z.y=y.y+qp.y; z.z=y.z+qp.z; z.w=y.w+qp.w;
    *(ushort4*)(Ypb + (size_t)row*256 + (lane<<2)) = pk4(z);
  }
}

// ---------------------------------------------------------------------------
// Deformable gather over bf16 bev. Grid 3600, block 512 (wave = head).
// ---------------------------------------------------------------------------
__global__ __launch_bounds__(512) void gather_k(
    const ushort* __restrict__ bevb, const float* __restrict__ offaw,
    const float* __restrict__ ref, ushort* __restrict__ rr, float* __restrict__ sumw)
{
  const int row = blockIdx.x;
  const int h = threadIdx.x >> 6, lane = threadIdx.x & 63;
  const int b = row / NQQ;
  const float refx = ref[row*3+0], refy = ref[row*3+1];
  const float* oa = offaw + (size_t)row*96;
  float aw[4];
  {
    const float a0=oa[64+h*4+0], a1=oa[64+h*4+1], a2=oa[64+h*4+2], a3=oa[64+h*4+3];
    const float mx = fmaxf(fmaxf(a0,a1), fmaxf(a2,a3));
    const float e0=__expf(a0-mx), e1=__expf(a1-mx), e2=__expf(a2-mx), e3=__expf(a3-mx);
    const float inv = 1.0f/(e0+e1+e2+e3);
    aw[0]=e0*inv; aw[1]=e1*inv; aw[2]=e2*inv; aw[3]=e3*inv;
  }
  float r0=0.f, r1=0.f, r2=0.f, r3=0.f, sacc=0.f;
  const ushort* bb = bevb + (size_t)b*BEVH*BEVW*DD;
  #pragma unroll
  for (int p=0;p<4;++p) {
    const float ox = oa[h*8+p*2+0], oy = oa[h*8+p*2+1];
    const float x = (refx + ox*(1.0f/BEVW))*BEVW - 0.5f;
    const float y = (refy + oy*(1.0f/BEVH))*BEVH - 0.5f;
    const float x0f = floorf(x), y0f = floorf(y);
    const int x0 = (int)x0f, y0 = (int)y0f;
    const float fx = x - x0f, fy = y - y0f;
    #pragma unroll
    for (int dy=0;dy<2;++dy) {
      #pragma unroll
      for (int dx=0;dx<2;++dx) {
        const int xi = x0+dx, yi = y0+dy;
        if (xi < 0 || xi >= BEVW || yi < 0 || yi >= BEVH) continue;
        const float wgt = (dx ? fx : 1.0f-fx) * (dy ? fy : 1.0f-fy) * aw[p];
        const ushort4 g = *(const ushort4*)(bb + (size_t)(yi*BEVW + xi)*DD + (lane<<2));
        r0 += wgt*bf2f(g.x); r1 += wgt*bf2f(g.y);
        r2 += wgt*bf2f(g.z); r3 += wgt*bf2f(g.w);
        sacc += wgt;
      }
    }
  }
  ushort4 o;
  o.x = (ushort)f2bf1(r0); o.y = (ushort)f2bf1(r1);
  o.z = (ushort)f2bf1(r2); o.w = (ushort)f2bf1(r3);
  *(ushort4*)&rr[((size_t)h*ROWS + row)*256 + (lane<<2)] = o;
  if (lane == 0) sumw[h*ROWS + row] = sacc;
}

// ---------------------------------------------------------------------------
// Deformable projection -> bf16 samp.
// ---------------------------------------------------------------------------
__global__ __launch_bounds__(256) void proj_k(
    const ushort* __restrict__ rr, const float* __restrict__ sumw,
    const float* __restrict__ vpw, const float* __restrict__ vpb,
    ushort* __restrict__ sampb)
{
  const int h = blockIdx.y;
  __shared__ float Ws[32*257];
  for (int i=threadIdx.x; i<8192; i+=256) {
    const int c = i>>8, k = i&255;
    Ws[c*257+k] = vpw[(size_t)((h<<5)+c)*256 + k];
  }
  __syncthreads();
  const int wv = threadIdx.x>>6, lane = threadIdx.x&63;
  const int c = lane&31, half = lane>>5;
  const float bias = vpb[(h<<5)+c];
  #pragma unroll
  for (int j=0;j<8;++j) {
    const int r = blockIdx.x*32 + wv*8 + j;
    if (r >= ROWS) break;
    const ushort* rp = rr + ((size_t)h*ROWS + r)*256 + half*128;
    const float* wb = &Ws[c*257 + half*128];
    float acc = 0.0f;
    #pragma unroll
    for (int jj=0;jj<32;++jj) {
      const uint2 u = *(const uint2*)(rp + jj*4);
      acc += bf2f(u.x & 0xffffu) * wb[jj*4+0];
      acc += bf2f(u.x >> 16)     * wb[jj*4+1];
      acc += bf2f(u.y & 0xffffu) * wb[jj*4+2];
      acc += bf2f(u.y >> 16)     * wb[jj*4+3];
    }
    acc += __shfl_xor(acc, 32);
    if (half == 0) sampb[(size_t)r*256 + (h<<5) + c] = (ushort)f2bf1(acc + bias*sumw[h*ROWS + r]);
  }
}

// ---------------------------------------------------------------------------
// Fused cls-LN2 + reg3 + cls3 + ref update + output write.
// rc2: [ROWS][512] f32; cols 0-255 reg2 out (relu'd), 256-511 cls2 out (raw).
// ---------------------------------------------------------------------------
__global__ __launch_bounds__(256) void regcls3_k(
    const float* __restrict__ rc2,
    const float* __restrict__ lnw, const float* __restrict__ lnb,
    const float* __restrict__ rw3, const float* __restrict__ rb3,
    const float* __restrict__ cw3, const float* __restrict__ cb3,
    float* __restrict__ ref, float* __restrict__ outL)
{
  __shared__ float Wr[10*272];
  __shared__ float Wc[10*272];
  for (int i=threadIdx.x; i<2560; i+=256) {
    const int o = i>>8, k = i&255;
    const int si = o*272 + (k>>6)*68 + (k&63);
    Wr[si] = rw3[i]; Wc[si] = cw3[i];
  }
  __syncthreads();
  const int t = threadIdx.x;
  const int row = t>>3, g = (t>>2)&1, sl = t&3;
  const int R = blockIdx.x*32 + row;
  const bool act = R < ROWS;
  const float* base = rc2 + (size_t)(act?R:0)*512 + g*256 + sl*64;
  float4 v[16];
  #pragma unroll
  for (int jj=0;jj<16;++jj) v[jj] = *(const float4*)(base + 4*jj);
  // inline LN + relu for cls half
  float s1 = 0.f, s2 = 0.f;
  #pragma unroll
  for (int jj=0;jj<16;++jj) {
    s1 += v[jj].x+v[jj].y+v[jj].z+v[jj].w;
    s2 += v[jj].x*v[jj].x+v[jj].y*v[jj].y+v[jj].z*v[jj].z+v[jj].w*v[jj].w;
  }
  s1 += __shfl_xor(s1,1); s1 += __shfl_xor(s1,2);
  s2 += __shfl_xor(s2,1); s2 += __shfl_xor(s2,2);
  if (g) {
    const float mean = s1*(1.0f/256.0f);
    const float var = s2*(1.0f/256.0f) - mean*mean;
    const float rs = rsqrtf(var + 1e-5f);
    #pragma unroll
    for (int jj=0;jj<16;++jj) {
      const float4 w4 = *(const float4*)(lnw + sl*64 + 4*jj);
      const float4 b4 = *(const float4*)(lnb + sl*64 + 4*jj);
      v[jj].x = fmaxf((v[jj].x-mean)*rs*w4.x + b4.x, 0.f);
      v[jj].y = fmaxf((v[jj].y-mean)*rs*w4.y + b4.y, 0.f);
      v[jj].z = fmaxf((v[jj].z-mean)*rs*w4.z + b4.z, 0.f);
      v[jj].w = fmaxf((v[jj].w-mean)*rs*w4.w + b4.w, 0.f);
    }
  }
  const float* Wg = g ? Wc : Wr;
  float acc[10] = {};
  #pragma unroll
  for (int jj=0;jj<16;++jj) {
    #pragma unroll
    for (int o=0;o<10;++o) {
      const float4 w = *(const float4*)&Wg[o*272 + sl*68 + 4*jj];
      acc[o] += v[jj].x*w.x + v[jj].y*w.y + v[jj].z*w.z + v[jj].w*w.w;
    }
  }
  #pragma unroll
  for (int o=0;o<10;++o) {
    acc[o] += __shfl_xor(acc[o], 1);
    acc[o] += __shfl_xor(acc[o], 2);
  }
  if (act && sl == 0) {
    if (g) {
      float* oc = outL + (size_t)R*20;
      #pragma unroll
      for (int o=0;o<10;++o) oc[o] = acc[o] + cb3[o];
    } else {
      float tt[10];
      #pragma unroll
      for (int o=0;o<10;++o) tt[o] = acc[o] + rb3[o];
      const float rx = invsigf_(ref[R*3+0]);
      const float ry = invsigf_(ref[R*3+1]);
      const float rz = invsigf_(ref[R*3+2]);
      const float nx = sigmoidf_(tt[0]+rx);
      const float ny = sigmoidf_(tt[1]+ry);
      const float nz = sigmoidf_(tt[4]+rz);
      ref[R*3+0]=nx; ref[R*3+1]=ny; ref[R*3+2]=nz;
      float* o = outL + (size_t)R*20 + 10;
      o[0]=nx*102.4f-51.2f; o[1]=ny*102.4f-51.2f; o[2]=tt[2]; o[3]=tt[3];
      o[4]=nz*8.0f-5.0f; o[5]=tt[5]; o[6]=tt[6]; o[7]=tt[7]; o[8]=tt[8]; o[9]=tt[9];
    }
  }
}

__global__ void init_k(const float* __restrict__ qe, float* __restrict__ qpos,
                       float* __restrict__ q, ushort* __restrict__ qb, ushort* __restrict__ qpb)
{
  const int t = blockIdx.x*blockDim.x + threadIdx.x;
  const int row = t >> 6; const int cc = (t & 63) << 2;
  const int n = row % NQQ;
  const float4 vp = *(const float4*)(qe + (size_t)n*512 + cc);
  const float4 vq = *(const float4*)(qe + (size_t)n*512 + 256 + cc);
  *(float4*)(qpos + (size_t)row*256 + cc) = vp;
  *(float4*)(q    + (size_t)row*256 + cc) = vq;
  *(ushort4*)(qb  + (size_t)row*256 + cc) = pk4(vq);
  float4 s; s.x=vq.x+vp.x; s.y=vq.y+vp.y; s.z=vq.z+vp.z; s.w=vq.w+vp.w;
  *(ushort4*)(qpb + (size_t)row*256 + cc) = pk4(s);
}

__global__ void prep_k(const float* __restrict__ ow, const float* __restrict__ ob,
                       const float* __restrict__ aw, const float* __restrict__ ab,
                       const float* __restrict__ rw, const float* __restrict__ rb,
                       const float* __restrict__ cw, const float* __restrict__ cb,
                       ushort* cwAb, float* cbA, ushort* cwBb, float* cbB)
{
  const int i = blockIdx.x*blockDim.x + threadIdx.x;
  if (i < 6*96*256) {
    const int l = i/(96*256), r = (i/256)%96, k = i%256;
    const float v = (r<64) ? ow[((size_t)l*64 + r)*256 + k] : aw[((size_t)l*32 + (r-64))*256 + k];
    cwAb[i] = (ushort)f2bf1(v);
  }
  if (i < 576) { const int l = i/96, r = i%96; cbA[i] = (r<64) ? ob[l*64+r] : ab[l*32 + r-64]; }
  if (i < 6*512*256) {
    const int l = i/(512*256), r = (i/256)%512, k = i%256;
    const float v = (r<256) ? rw[((size_t)l*256+r)*256+k] : cw[((size_t)l*256 + (r-256))*256 + k];
    cwBb[i] = (ushort)f2bf1(v);
  }
  if (i < 3072) { const int l = i/512, r = i%512; cbB[i] = (r<256) ? rb[l*256+r] : cb[l*256 + r-256]; }
}

__global__ void cvtw_k(const float* __restrict__ s1, const float* __restrict__ s2,
                       const float* __restrict__ s3, const float* __restrict__ s4,
                       const float* __restrict__ s5, const float* __restrict__ s6,
                       const float* __restrict__ s7, ushort* __restrict__ dst)
{
  const int i4 = (blockIdx.x*256 + threadIdx.x)*4;
  if (i4 >= 4325376) return;
  const float* src; int lo;
  if      (i4 < 1179648) { src=s1; lo=i4; }
  else if (i4 < 1572864) { src=s2; lo=i4-1179648; }
  else if (i4 < 1966080) { src=s3; lo=i4-1572864; }
  else if (i4 < 2752512) { src=s4; lo=i4-1966080; }
  else if (i4 < 3538944) { src=s5; lo=i4-2752512; }
  else if (i4 < 3932160) { src=s6; lo=i4-3538944; }
  else                   { src=s7; lo=i4-3932160; }
  const float4 v = *(const float4*)(src+lo);
  *(ushort4*)(dst+i4) = pk4(v);
}

__global__ void cvtbev_k(const float* __restrict__ bev, ushort* __restrict__ bevb)
{
  const size_t i = ((size_t)blockIdx.x*256 + threadIdx.x)*8;
  const float4 a = *(const float4*)(bev+i);
  const float4 b = *(const float4*)(bev+i+4);
  *(ushort4*)(bevb+i)   = pk4(a);
  *(ushort4*)(bevb+i+4) = pk4(b);
}

extern "C" void kernel_launch(void* const* d_in, const int* in_sizes, int n_in,
                              void* d_out, int out_size, void* d_ws, size_t ws_size,
                              hipStream_t stream)
{
  const float* bev      = (const float*)d_in[0];
  const float* qe       = (const float*)d_in[1];
  const float* ref_w    = (const float*)d_in[2];
  const float* ref_b    = (const float*)d_in[3];
  const float* sa_in_w  = (const float*)d_in[4];
  const float* sa_in_b  = (const float*)d_in[5];
  const float* sa_out_w = (const float*)d_in[6];
  const float* sa_out_b = (const float*)d_in[7];
  const float* ln_w     = (const float*)d_in[8];
  const float* ln_b     = (const float*)d_in[9];
  const float* off_w    = (const float*)d_in[10];
  const float* off_b    = (const float*)d_in[11];
  const float* aw_w     = (const float*)d_in[12];
  const float* aw_b     = (const float*)d_in[13];
  const float* vproj_w  = (const float*)d_in[14];
  const float* vproj_b  = (const float*)d_in[15];
  const float* oproj_w  = (const float*)d_in[16];
  const float* oproj_b  = (const float*)d_in[17];
  const float* ffn_w1   = (const float*)d_in[18];
  const float* ffn_b1   = (const float*)d_in[19];
  const float* ffn_w2   = (const float*)d_in[20];
  const float* ffn_b2   = (const float*)d_in[21];
  const float* reg_w1   = (const float*)d_in[22];
  const float* reg_b1   = (const float*)d_in[23];
  const float* reg_w2   = (const float*)d_in[24];
  const float* reg_b2   = (const float*)d_in[25];
  const float* reg_w3   = (const float*)d_in[26];
  const float* reg_b3   = (const float*)d_in[27];
  const float* cls_w1   = (const float*)d_in[28];
  const float* cls_b1   = (const float*)d_in[29];
  const float* cls_w2   = (const float*)d_in[30];
  const float* cls_b2   = (const float*)d_in[31];
  const float* cls_w3   = (const float*)d_in[32];
  const float* cls_b3   = (const float*)d_in[33];
  const float* cls_ln_w = (const float*)d_in[34];
  const float* cls_ln_b = (const float*)d_in[35];
  float* out = (float*)d_out;

  float* ws    = (float*)d_ws;
  float* qpos  = ws;                    // 921600
  float* q     = qpos + 921600;
  float* tA    = q    + 921600;
  float* tB    = tA   + 921600;
  float* rc2   = tB   + 921600;         // 1843200
  float* cls1f = rc2  + 1843200;        // 921600
  float* offaw = cls1f+ 921600;         // 345600
  float* ref   = offaw+ 345600;         // 10800
  float* sumw  = ref  + 10800;          // 28800
  float* cbA   = sumw + 28800;          // 576
  float* cbB   = cbA  + 576;            // 3072
  // ushort region starts at 6840048 floats (16B aligned)
  ushort* usb  = (ushort*)(ws + 6840048);
  ushort* QKb  = usb;                   // 1843200
  ushort* Vb   = usb + 1843200;         // 921600
  ushort* tAb  = usb + 2764800;         // 921600
  ushort* W5b  = usb + 3686400;         // 1843200
  ushort* sampb= usb + 5529600;         // 921600
  ushort* qb   = usb + 6451200;         // 921600
  ushort* qpb  = usb + 7372800;         // 921600
  ushort* clsb = usb + 8294400;         // 921600
  ushort* regb = usb + 9216000;         // 921600
  ushort* rr   = usb + 10137600;        // 7372800
  ushort* bevb = usb + 17510400;        // 40960000
  ushort* wbf  = usb + 58470400;
  ushort* siwb = wbf;                   // 1179648
  ushort* sowb = wbf + 1179648;         // 393216
  ushort* opwb = wbf + 1572864;         // 393216
  ushort* f1wb = wbf + 1966080;         // 786432
  ushort* f2wb = wbf + 2752512;         // 786432
  ushort* r2wb = wbf + 3538944;         // 393216
  ushort* c2wb = wbf + 3932160;         // 393216
  ushort* cwAb = wbf + 4325376;         // 147456
  ushort* cwBb = wbf + 4472832;         // 786432

  auto G = [&](int BM, const ushort* A0, const ushort* A1, int NA, int lda,
               const ushort* W0, const ushort* W1, int NW,
               const float* B0, const float* B1, int NB,
               void* Y0, int ldy0, int obf0,
               void* Y1, int ldy1, int obf1, int NY,
               int M, int N, int K, int reluN) {
    dim3 grid((M+BM-1)/BM, (N+63)/64);
    if (BM==64)
      gemmb_k<64><<<grid, 256, 0, stream>>>(A0,A1,NA,lda,W0,W1,NW,B0,B1,NB,
                                            Y0,ldy0,obf0,Y1,ldy1,obf1,NY,M,N,K,reluN);
    else
      gemmb_k<32><<<grid, 256, 0, stream>>>(A0,A1,NA,lda,W0,W1,NW,B0,B1,NB,
                                            Y0,ldy0,obf0,Y1,ldy1,obf1,NY,M,N,K,reluN);
  };

  // one-time converts + prep
  cvtbev_k<<<20000, 256, 0, stream>>>(bev, bevb);
  cvtw_k<<<4224, 256, 0, stream>>>(sa_in_w, sa_out_w, oproj_w, ffn_w1, ffn_w2, reg_w2, cls_w2, wbf);
  prep_k<<<3072, 256, 0, stream>>>(off_w, off_b, aw_w, aw_b, reg_w1, reg_b1, cls_w1, cls_b1,
                                   cwAb, cbA, cwBb, cbB);
  init_k<<<900, 256, 0, stream>>>(qe, qpos, q, qb, qpb);
  {
    dim3 grid((ROWS+63)/64, 1);
    gemm_k<<<grid, 256, 0, stream>>>(qpos, 256, ref_w, ref_b, ref, ROWS, 3, 256, 3, 2);
  }

  for (int i=0;i<NLAYER;++i) {
    const float* sib = sa_in_b + (size_t)i*768;
    const ushort* siw = siwb + (size_t)i*196608;
    // ---- self-attention: fused QKV ----
    G(64, qpb, qb, 512, 256, siw, siw, BIGN, sib, sib, BIGN,
      QKb, 512, 1, Vb, 256, 1, 512, ROWS, 768, 256, 0);
    attn3_k<<<dim3(32,15), 256, 0, stream>>>(QKb, Vb, tAb);
    G(32, tAb, tAb, BIGN, 256, sowb + (size_t)i*65536, nullptr, BIGN,
      sa_out_b + (size_t)i*256, nullptr, BIGN,
      tB, 256, 0, nullptr, 0, 0, BIGN, ROWS, 256, 256, 0);
    ln_k<<<900, 256, 0, stream>>>(tB, 256, q, ln_w + (size_t)(i*3+0)*256, ln_b + (size_t)(i*3+0)*256,
                                  q, nullptr, qpos, qpb, 0);
    // ---- deformable cross-attention ----
    G(32, qpb, qpb, BIGN, 256, cwAb + (size_t)i*24576, nullptr, BIGN,
      cbA + i*96, nullptr, BIGN,
      offaw, 96, 0, nullptr, 0, 0, BIGN, ROWS, 96, 256, 0);
    gather_k<<<ROWS, 512, 0, stream>>>(bevb, offaw, ref, rr, sumw);
    proj_k<<<dim3(113,8), 256, 0, stream>>>(rr, sumw,
        vproj_w + (size_t)i*65536, vproj_b + (size_t)i*256, sampb);
    G(32, sampb, sampb, BIGN, 256, opwb + (size_t)i*65536, nullptr, BIGN,
      oproj_b + (size_t)i*256, nullptr, BIGN,
      tA, 256, 0, nullptr, 0, 0, BIGN, ROWS, 256, 256, 0);
    ln_k<<<900, 256, 0, stream>>>(tA, 256, q, ln_w + (size_t)(i*3+1)*256, ln_b + (size_t)(i*3+1)*256,
                                  q, qb, nullptr, nullptr, 0);
    // ---- FFN ----
    G(64, qb, qb, BIGN, 256, f1wb + (size_t)i*131072, nullptr, BIGN,
      ffn_b1 + (size_t)i*512, nullptr, BIGN,
      W5b, 512, 1, nullptr, 0, 0, BIGN, ROWS, 512, 256, 512);
    G(32, W5b, W5b, BIGN, 512, f2wb + (size_t)i*131072, nullptr, BIGN,
      ffn_b2 + (size_t)i*256, nullptr, BIGN,
      tA, 256, 0, nullptr, 0, 0, BIGN, ROWS, 256, 512, 0);
    ln_k<<<900, 256, 0, stream>>>(tA, 256, q, ln_w + (size_t)(i*3+2)*256, ln_b + (size_t)(i*3+2)*256,
                                  q, qb, qpos, qpb, 0);
    // ---- reg1|cls1 dual-output ----
    G(64, qb, qb, BIGN, 256, cwBb + (size_t)i*131072, nullptr, BIGN,
      cbB + i*512, nullptr, BIGN,
      regb, 256, 1, cls1f, 256, 0, 256, ROWS, 512, 256, 256);
    ln_k<<<900, 256, 0, stream>>>(cls1f, 256, nullptr,
                                  cls_ln_w + (size_t)(i*2+0)*256, cls_ln_b + (size_t)(i*2+0)*256,
                                  nullptr, clsb, nullptr, nullptr, 1);
    // ---- reg2|cls2 merged ----
    G(64, regb, clsb, 256, 256,
      r2wb + (size_t)i*65536, c2wb + (size_t)i*65536, 256,
      reg_b2 + (size_t)i*256, cls_b2 + (size_t)i*256, 256,
      rc2, 512, 0, nullptr, 0, 0, BIGN, ROWS, 512, 256, 256);
    // ---- fused clsLN2 + reg3 + cls3 + refupdate + output ----
    regcls3_k<<<(ROWS+31)/32, 256, 0, stream>>>(rc2,
        cls_ln_w + (size_t)(i*2+1)*256, cls_ln_b + (size_t)(i*2+1)*256,
        reg_w3 + (size_t)i*2560, reg_b3 + (size_t)i*10,
        cls_w3 + (size_t)i*2560, cls_b3 + (size_t)i*10,
        ref, out + (size_t)i*ROWS*20);
  }
}

// Round 8
// 1165.948 us; speedup vs baseline: 3.6338x; 1.1837x over previous
//
#include <hip/hip_runtime.h>
#include <math.h>

#define DD 256
#define NQQ 900
#define NBS 4
#define NLAYER 6
#define BEVH 200
#define BEVW 200
#define ROWS (NBS*NQQ)   // 3600
#define BIGN (1<<30)
#define KDEF 2080        // deform fused K: 2048 + 8 sacc + 24 zero

typedef __attribute__((ext_vector_type(8))) short bf16x8;
typedef __attribute__((ext_vector_type(4))) float f32x4;

__device__ __forceinline__ float sigmoidf_(float x){ return 1.0f/(1.0f+expf(-x)); }
__device__ __forceinline__ float invsigf_(float x){
  x = fminf(fmaxf(x,0.0f),1.0f);
  float lo = fmaxf(x,1e-5f), hi = fmaxf(1.0f-x,1e-5f);
  return logf(lo/hi);
}
__device__ __forceinline__ unsigned f2bf1(float x){
  unsigned u = __float_as_uint(x);
  return (u + 0x7fffu + ((u>>16)&1u)) >> 16;
}
__device__ __forceinline__ unsigned pk2(float a, float b){
  return f2bf1(a) | (f2bf1(b)<<16);
}
__device__ __forceinline__ float bf2f(unsigned u){ return __uint_as_float(u<<16); }
__device__ __forceinline__ ushort4 pk4(float4 y){
  ushort4 o; o.x=(ushort)f2bf1(y.x); o.y=(ushort)f2bf1(y.y);
  o.z=(ushort)f2bf1(y.z); o.w=(ushort)f2bf1(y.w); return o;
}

// ---------------------------------------------------------------------------
// fp32 GEMM (ref head only).
// ---------------------------------------------------------------------------
__global__ __launch_bounds__(256) void gemm_k(
    const float* __restrict__ A, int lda,
    const float* __restrict__ W, const float* __restrict__ B,
    float* __restrict__ Y, int M, int N, int K, int ldy, int act)
{
  __shared__ float As[2][32][66];
  __shared__ float Ws[2][32][66];
  const int t = threadIdx.x;
  const int m0 = blockIdx.x*64, n0 = blockIdx.y*64;
  const int lr = t >> 2, kq = (t & 3) << 3;
  const int tx = t & 15, ty = t >> 4;
  const bool aok = (m0 + lr) < M;
  const bool wok = (n0 + lr) < N;
  const float* ap  = A + (size_t)(m0+lr)*lda + kq;
  const float* wp  = W + (size_t)(n0+lr)*K + kq;
  float4 pa[2], pw[2];
  auto loadch = [&](int kc) {
    #pragma unroll
    for (int i=0;i<2;++i) {
      pa[i] = aok ? *(const float4*)(ap + kc + i*4) : make_float4(0,0,0,0);
      pw[i] = wok ? *(const float4*)(wp + kc + i*4) : make_float4(0,0,0,0);
    }
  };
  auto storech = [&](int bf) {
    #pragma unroll
    for (int i=0;i<2;++i) {
      const int kk = kq + i*4;
      As[bf][kk+0][lr]=pa[i].x; As[bf][kk+1][lr]=pa[i].y;
      As[bf][kk+2][lr]=pa[i].z; As[bf][kk+3][lr]=pa[i].w;
      Ws[bf][kk+0][lr]=pw[i].x; Ws[bf][kk+1][lr]=pw[i].y;
      Ws[bf][kk+2][lr]=pw[i].z; Ws[bf][kk+3][lr]=pw[i].w;
    }
  };
  float acc[4][4] = {};
  loadch(0); storech(0); __syncthreads();
  const int NC = K >> 5;
  for (int c=0; c<NC; ++c) {
    if (c+1 < NC) loadch((c+1) << 5);
    const int bf = c & 1;
    #pragma unroll
    for (int k=0;k<32;++k) {
      const float4 a4 = *(const float4*)&As[bf][k][ty<<2];
      const float4 w4 = *(const float4*)&Ws[bf][k][tx<<2];
      const float av[4] = {a4.x,a4.y,a4.z,a4.w};
      const float wv[4] = {w4.x,w4.y,w4.z,w4.w};
      #pragma unroll
      for (int r=0;r<4;++r)
        #pragma unroll
        for (int cc=0;cc<4;++cc) acc[r][cc] += av[r]*wv[cc];
    }
    if (c+1 < NC) { storech((c+1)&1); __syncthreads(); }
  }
  const int gn0 = n0 + (tx<<2);
  #pragma unroll
  for (int r=0;r<4;++r) {
    const int gm = m0 + (ty<<2) + r;
    if (gm >= M) continue;
    for (int cc=0; cc<4 && gn0+cc<N; ++cc) {
      float x = acc[r][cc] + (B ? B[gn0+cc] : 0.0f);
      if (act==1) x = fmaxf(x,0.0f);
      else if (act==2) x = sigmoidf_(x);
      Y[(size_t)gm*ldy + gn0+cc] = x;
    }
  }
}

// ---------------------------------------------------------------------------
// bf16 MFMA GEMM v3: templated BM (64 or 32), BN=64. Dual-A/W/bias/Y.
// ---------------------------------------------------------------------------
template<int BM>
__global__ __launch_bounds__(256) void gemmb_k(
    const ushort* __restrict__ A0, const ushort* __restrict__ A1, int NA, int lda,
    const ushort* __restrict__ W0, const ushort* __restrict__ W1, int NW,
    const float* __restrict__ B0, const float* __restrict__ B1, int NB,
    void* __restrict__ Y0, int ldy0, int obf0,
    void* __restrict__ Y1, int ldy1, int obf1, int NY,
    int M, int N, int K, int reluN)
{
  __shared__ ushort As[2][BM*32];
  __shared__ ushort Bs[2][2048];
  const int t = threadIdx.x;
  const int m0 = blockIdx.x*BM, n0 = blockIdx.y*64;
  const ushort* A = (n0 < NA) ? A0 : A1;
  const int srow = t>>2, scb = t&3;
  const int wrow = n0 + srow;
  const bool wok = wrow < N;
  const ushort* wp = (wrow < NW) ? (W0 + (size_t)wrow*K + scb*8)
                                 : (W1 + (size_t)(wrow-NW)*K + scb*8);
  bool aok; const ushort* ap;
  if constexpr (BM==64) { aok = (m0+srow)<M; }
  else { aok = (t<128) && (m0+srow)<M; }
  ap = A + (size_t)(m0 + (aok?srow:0))*lda + scb*8;
  const int sidx = srow*32 + ((scb ^ (srow&3))<<3);
  const bf16x8 zf = {0,0,0,0,0,0,0,0};

  bf16x8 pa, pw;
  auto loadg = [&](int kc){
    pa = aok ? *(const bf16x8*)(ap+kc) : zf;
    pw = wok ? *(const bf16x8*)(wp+kc) : zf;
  };
  auto writes = [&](int bf){
    if (BM==64 || t<128) *(bf16x8*)&As[bf][sidx] = pa;
    *(bf16x8*)&Bs[bf][sidx] = pw;
  };

  const int wv = t>>6, lane = t&63;
  const int fm = lane&15, kb = lane>>4;

  auto writeout = [&](float x, int row, int col){
    if (row >= M || col >= N) return;
    if (col < reluN) x = fmaxf(x, 0.0f);
    if (col < NY) {
      if (obf0) ((ushort*)Y0)[(size_t)row*ldy0 + col] = (ushort)f2bf1(x);
      else      ((float*)Y0)[(size_t)row*ldy0 + col] = x;
    } else {
      const int c2 = col - NY;
      if (obf1) ((ushort*)Y1)[(size_t)row*ldy1 + c2] = (ushort)f2bf1(x);
      else      ((float*)Y1)[(size_t)row*ldy1 + c2] = x;
    }
  };

  const int NS = K>>5;
  if constexpr (BM==64) {
    const int wr = wv>>1, wc = wv&1;
    const int arow0 = wr*32 + fm, arow1 = arow0 + 16;
    const int bcol0 = wc*32 + fm, bcol1 = bcol0 + 16;
    const int ai0 = arow0*32 + ((kb^(arow0&3))<<3);
    const int ai1 = arow1*32 + ((kb^(arow1&3))<<3);
    const int bi0 = bcol0*32 + ((kb^(bcol0&3))<<3);
    const int bi1 = bcol1*32 + ((kb^(bcol1&3))<<3);
    f32x4 acc00={0,0,0,0}, acc01={0,0,0,0}, acc10={0,0,0,0}, acc11={0,0,0,0};
    loadg(0); writes(0); __syncthreads();
    for (int s=0; s<NS; ++s) {
      if (s+1<NS) loadg((s+1)<<5);
      const int bf = s&1;
      bf16x8 a0 = *(bf16x8*)&As[bf][ai0];
      bf16x8 a1 = *(bf16x8*)&As[bf][ai1];
      bf16x8 b0 = *(bf16x8*)&Bs[bf][bi0];
      bf16x8 b1 = *(bf16x8*)&Bs[bf][bi1];
      acc00 = __builtin_amdgcn_mfma_f32_16x16x32_bf16(a0,b0,acc00,0,0,0);
      acc01 = __builtin_amdgcn_mfma_f32_16x16x32_bf16(a0,b1,acc01,0,0,0);
      acc10 = __builtin_amdgcn_mfma_f32_16x16x32_bf16(a1,b0,acc10,0,0,0);
      acc11 = __builtin_amdgcn_mfma_f32_16x16x32_bf16(a1,b1,acc11,0,0,0);
      if (s+1<NS) { __syncthreads(); writes((s+1)&1); __syncthreads(); }
    }
    #pragma unroll
    for (int fr=0; fr<2; ++fr)
      #pragma unroll
      for (int fc=0; fc<2; ++fc) {
        const f32x4 av = fr ? (fc ? acc11 : acc10) : (fc ? acc01 : acc00);
        const int col = n0 + wc*32 + fc*16 + fm;
        const float bias = (col<N) ? ((col<NB) ? B0[col] : B1[col-NB]) : 0.0f;
        #pragma unroll
        for (int r=0; r<4; ++r)
          writeout(av[r] + bias, m0 + wr*32 + fr*16 + kb*4 + r, col);
      }
  } else {
    const int ai0 = fm*32 + ((kb^(fm&3))<<3);
    const int ai1 = (fm+16)*32 + ((kb^(fm&3))<<3);
    const int bcol = wv*16 + fm;
    const int bi = bcol*32 + ((kb^(bcol&3))<<3);
    f32x4 acc0={0,0,0,0}, acc1={0,0,0,0};
    loadg(0); writes(0); __syncthreads();
    for (int s=0; s<NS; ++s) {
      if (s+1<NS) loadg((s+1)<<5);
      const int bf = s&1;
      bf16x8 a0 = *(bf16x8*)&As[bf][ai0];
      bf16x8 a1 = *(bf16x8*)&As[bf][ai1];
      bf16x8 b  = *(bf16x8*)&Bs[bf][bi];
      acc0 = __builtin_amdgcn_mfma_f32_16x16x32_bf16(a0,b,acc0,0,0,0);
      acc1 = __builtin_amdgcn_mfma_f32_16x16x32_bf16(a1,b,acc1,0,0,0);
      if (s+1<NS) { __syncthreads(); writes((s+1)&1); __syncthreads(); }
    }
    const int col = n0 + wv*16 + fm;
    const float bias = (col<N) ? ((col<NB) ? B0[col] : B1[col-NB]) : 0.0f;
    #pragma unroll
    for (int r=0; r<4; ++r) {
      writeout(acc0[r] + bias, m0 + kb*4 + r, col);
      writeout(acc1[r] + bias, m0 + 16 + kb*4 + r, col);
    }
  }
}

// ---------------------------------------------------------------------------
// MFMA bf16 flash attention v2: block-shared LDS K/V staging (4 waves share
// one (b,h)); K row-major pitch 40, V transposed pitch 34; double-buffered.
// ---------------------------------------------------------------------------
__global__ __launch_bounds__(256) void attn3_k(
    const ushort* __restrict__ QKb, const ushort* __restrict__ Vb, ushort* __restrict__ Ob)
{
  const int b = blockIdx.x >> 3, h = blockIdx.x & 7;
  const int wv = threadIdx.x >> 6, lane = threadIdx.x & 63;
  const int t = threadIdx.x;
  const int qt = blockIdx.y*64 + wv*16;
  const int lq = lane & 15, lg = lane >> 4;
  const int q = qt + lq;

  __shared__ ushort Ks[2][32*40];
  __shared__ ushort Vt[2][32*34];

  bf16x8 qf = *(const bf16x8*)(QKb + (size_t)(b*NQQ + min(q, NQQ-1))*512 + h*32 + lg*8);
  f32x4 ot0 = {0.f,0.f,0.f,0.f}, ot1 = {0.f,0.f,0.f,0.f};
  float m = -3e38f, l = 0.0f;

  const ushort* kg = QKb + (size_t)b*NQQ*512 + 256 + h*32;
  const ushort* vg = Vb  + (size_t)b*NQQ*256 + h*32;
  const int srow = t>>3, sc4 = (t&7)*4;

  ushort4 kv, vv;
  auto sload = [&](int k0){
    const int gr = min(k0 + srow, NQQ-1);
    kv = *(const ushort4*)(kg + (size_t)gr*512 + sc4);
    vv = *(const ushort4*)(vg + (size_t)gr*256 + sc4);
  };
  auto swrite = [&](int bf){
    *(ushort4*)&Ks[bf][srow*40 + sc4] = kv;
    Vt[bf][(sc4+0)*34 + srow] = vv.x;
    Vt[bf][(sc4+1)*34 + srow] = vv.y;
    Vt[bf][(sc4+2)*34 + srow] = vv.z;
    Vt[bf][(sc4+3)*34 + srow] = vv.w;
  };

  const int pbase = (lq + ((lg&1)<<5)) << 2;
  const bool hiC = (lg >> 1);
  const int NC = (NQQ + 31) >> 5;   // 29

  sload(0); swrite(0); __syncthreads();
  for (int c = 0; c < NC; ++c) {
    const int k0 = c<<5;
    if (c+1 < NC) sload((c+1)<<5);
    const int bf = c&1;
    bf16x8 kf0 = *(bf16x8*)&Ks[bf][lq*40 + lg*8];
    bf16x8 kf1 = *(bf16x8*)&Ks[bf][(16+lq)*40 + lg*8];
    const f32x4 z = {0.f,0.f,0.f,0.f};
    f32x4 s0 = __builtin_amdgcn_mfma_f32_16x16x32_bf16(kf0, qf, z, 0, 0, 0);
    f32x4 s1 = __builtin_amdgcn_mfma_f32_16x16x32_bf16(kf1, qf, z, 0, 0, 0);
    const float sc = 0.17677669529663687f;
    float p0[4], p1[4];
    #pragma unroll
    for (int r=0;r<4;++r) { p0[r] = s0[r]*sc; p1[r] = s1[r]*sc; }
    if (k0 + 32 > NQQ) {
      #pragma unroll
      for (int r=0;r<4;++r) {
        if (k0 + 4*lg + r      >= NQQ) p0[r] = -3e38f;
        if (k0 + 16 + 4*lg + r >= NQQ) p1[r] = -3e38f;
      }
    }
    float cm = fmaxf(fmaxf(fmaxf(p0[0],p0[1]),fmaxf(p0[2],p0[3])),
                     fmaxf(fmaxf(p1[0],p1[1]),fmaxf(p1[2],p1[3])));
    cm = fmaxf(cm, __shfl_xor(cm, 16));
    cm = fmaxf(cm, __shfl_xor(cm, 32));
    const float mn = fmaxf(m, cm);
    const float corr = __expf(m - mn);
    m = mn;
    float rs = 0.0f;
    #pragma unroll
    for (int r=0;r<4;++r) { p0[r] = __expf(p0[r]-mn); rs += p0[r]; }
    #pragma unroll
    for (int r=0;r<4;++r) { p1[r] = __expf(p1[r]-mn); rs += p1[r]; }
    rs += __shfl_xor(rs, 16);
    rs += __shfl_xor(rs, 32);
    l = l*corr + rs;
    ot0 *= corr; ot1 *= corr;

    const int c00 = (int)pk2(p0[0],p0[1]), c01 = (int)pk2(p0[2],p0[3]);
    const int c10 = (int)pk2(p1[0],p1[1]), c11 = (int)pk2(p1[2],p1[3]);
    const int A0 = __builtin_amdgcn_ds_bpermute(pbase,    c00);
    const int B0 = __builtin_amdgcn_ds_bpermute(pbase,    c10);
    const int A1 = __builtin_amdgcn_ds_bpermute(pbase,    c01);
    const int B1 = __builtin_amdgcn_ds_bpermute(pbase,    c11);
    const int A2 = __builtin_amdgcn_ds_bpermute(pbase+64, c00);
    const int B2 = __builtin_amdgcn_ds_bpermute(pbase+64, c10);
    const int A3 = __builtin_amdgcn_ds_bpermute(pbase+64, c01);
    const int B3 = __builtin_amdgcn_ds_bpermute(pbase+64, c11);
    union { bf16x8 v; int u[4]; } pv;
    pv.u[0] = hiC ? B0 : A0; pv.u[1] = hiC ? B1 : A1;
    pv.u[2] = hiC ? B2 : A2; pv.u[3] = hiC ? B3 : A3;

    bf16x8 vf0, vf1;
    {
      union { bf16x8 v; unsigned u[4]; } u0, u1;
      const int rb = 8*lg;
      #pragma unroll
      for (int jj=0;jj<4;++jj) {
        u0.u[jj] = *(const unsigned*)&Vt[bf][lq*34 + rb + 2*jj];
        u1.u[jj] = *(const unsigned*)&Vt[bf][(16+lq)*34 + rb + 2*jj];
      }
      vf0 = u0.v; vf1 = u1.v;
    }
    ot0 = __builtin_amdgcn_mfma_f32_16x16x32_bf16(vf0, pv.v, ot0, 0, 0, 0);
    ot1 = __builtin_amdgcn_mfma_f32_16x16x32_bf16(vf1, pv.v, ot1, 0, 0, 0);
    if (c+1 < NC) { __syncthreads(); swrite((c+1)&1); __syncthreads(); }
  }
  if (q < NQQ && qt < NQQ) {
    const float inv = 1.0f / l;
    ushort* op = Ob + (size_t)(b*NQQ + q)*256 + h*32;
    uint2 w0, w1;
    w0.x = pk2(ot0[0]*inv, ot0[1]*inv); w0.y = pk2(ot0[2]*inv, ot0[3]*inv);
    w1.x = pk2(ot1[0]*inv, ot1[1]*inv); w1.y = pk2(ot1[2]*inv, ot1[3]*inv);
    *(uint2*)(op + 4*lg)      = w0;
    *(uint2*)(op + 16 + 4*lg) = w1;
  }
}

// ---------------------------------------------------------------------------
// LayerNorm: optional f32 out, bf16 out, bf16(out+qpos) out.
// ---------------------------------------------------------------------------
__global__ __launch_bounds__(256) void ln_k(
    const float* X, int xld, const float* R,
    const float* __restrict__ w, const float* __restrict__ b,
    float* Y, ushort* Yb, const float* qpos, ushort* Ypb, int relu)
{
  const int row = blockIdx.x*4 + (threadIdx.x>>6);
  const int lane = threadIdx.x & 63;
  if (row >= ROWS) return;
  float4 x = *(const float4*)(X + (size_t)row*xld + (lane<<2));
  if (R) { const float4 r = *(const float4*)(R + (size_t)row*256 + (lane<<2)); x.x+=r.x; x.y+=r.y; x.z+=r.z; x.w+=r.w; }
  float s = x.x+x.y+x.z+x.w;
  #pragma unroll
  for (int o=32;o>0;o>>=1) s += __shfl_xor(s,o);
  const float mean = s * (1.0f/256.0f);
  float4 d; d.x=x.x-mean; d.y=x.y-mean; d.z=x.z-mean; d.w=x.w-mean;
  float s2 = d.x*d.x+d.y*d.y+d.z*d.z+d.w*d.w;
  #pragma unroll
  for (int o=32;o>0;o>>=1) s2 += __shfl_xor(s2,o);
  const float rs = rsqrtf(s2*(1.0f/256.0f) + 1e-5f);
  const float4 wv = *(const float4*)(w + (lane<<2));
  const float4 bv = *(const float4*)(b + (lane<<2));
  float4 y;
  y.x = d.x*rs*wv.x + bv.x; y.y = d.y*rs*wv.y + bv.y;
  y.z = d.z*rs*wv.z + bv.z; y.w = d.w*rs*wv.w + bv.w;
  if (relu) { y.x=fmaxf(y.x,0.f); y.y=fmaxf(y.y,0.f); y.z=fmaxf(y.z,0.f); y.w=fmaxf(y.w,0.f); }
  if (Y)  *(float4*)(Y + (size_t)row*256 + (lane<<2)) = y;
  if (Yb) *(ushort4*)(Yb + (size_t)row*256 + (lane<<2)) = pk4(y);
  if (Ypb) {
    const float4 qp = *(const float4*)(qpos + (size_t)row*256 + (lane<<2));
    float4 zz; zz.x=y.x+qp.x; zz.y=y.y+qp.y; zz.z=y.z+qp.z; zz.w=y.w+qp.w;
    *(ushort4*)(Ypb + (size_t)row*256 + (lane<<2)) = pk4(zz);
  }
}

// ---------------------------------------------------------------------------
// Deformable gather -> rr row-major [row][2080] bf16 (2048 feat | 8 sacc | 24 z)
// ---------------------------------------------------------------------------
__global__ __launch_bounds__(512) void gather_k(
    const ushort* __restrict__ bevb, const float* __restrict__ offaw,
    const float* __restrict__ ref, ushort* __restrict__ rr)
{
  const int row = blockIdx.x;
  const int h = threadIdx.x >> 6, lane = threadIdx.x & 63;
  const int b = row / NQQ;
  const float refx = ref[row*3+0], refy = ref[row*3+1];
  const float* oa = offaw + (size_t)row*96;
  float aw[4];
  {
    const float a0=oa[64+h*4+0], a1=oa[64+h*4+1], a2=oa[64+h*4+2], a3=oa[64+h*4+3];
    const float mx = fmaxf(fmaxf(a0,a1), fmaxf(a2,a3));
    const float e0=__expf(a0-mx), e1=__expf(a1-mx), e2=__expf(a2-mx), e3=__expf(a3-mx);
    const float inv = 1.0f/(e0+e1+e2+e3);
    aw[0]=e0*inv; aw[1]=e1*inv; aw[2]=e2*inv; aw[3]=e3*inv;
  }
  float r0=0.f, r1=0.f, r2=0.f, r3=0.f, sacc=0.f;
  const ushort* bb = bevb + (size_t)b*BEVH*BEVW*DD;
  #pragma unroll
  for (int p=0;p<4;++p) {
    const float ox = oa[h*8+p*2+0], oy = oa[h*8+p*2+1];
    const float x = (refx + ox*(1.0f/BEVW))*BEVW - 0.5f;
    const float y = (refy + oy*(1.0f/BEVH))*BEVH - 0.5f;
    const float x0f = floorf(x), y0f = floorf(y);
    const int x0 = (int)x0f, y0 = (int)y0f;
    const float fx = x - x0f, fy = y - y0f;
    #pragma unroll
    for (int dy=0;dy<2;++dy) {
      #pragma unroll
      for (int dx=0;dx<2;++dx) {
        const int xi = x0+dx, yi = y0+dy;
        if (xi < 0 || xi >= BEVW || yi < 0 || yi >= BEVH) continue;
        const float wgt = (dx ? fx : 1.0f-fx) * (dy ? fy : 1.0f-fy) * aw[p];
        const ushort4 g = *(const ushort4*)(bb + (size_t)(yi*BEVW + xi)*DD + (lane<<2));
        r0 += wgt*bf2f(g.x); r1 += wgt*bf2f(g.y);
        r2 += wgt*bf2f(g.z); r3 += wgt*bf2f(g.w);
        sacc += wgt;
      }
    }
  }
  ushort4 o;
  o.x = (ushort)f2bf1(r0); o.y = (ushort)f2bf1(r1);
  o.z = (ushort)f2bf1(r2); o.w = (ushort)f2bf1(r3);
  ushort* rrow = rr + (size_t)row*KDEF;
  *(ushort4*)&rrow[h*256 + (lane<<2)] = o;
  if (lane == 0) rrow[2048 + h] = (ushort)f2bf1(sacc);
  else if (lane < 4) rrow[2048 + lane*8 + h] = 0;
}

// ---------------------------------------------------------------------------
// One-time: Wfull[l][c][2080] = [ oproj@blockdiag(vproj) | Bmat | 0 ] in bf16
// ---------------------------------------------------------------------------
__global__ __launch_bounds__(256) void wcomb_k(
    const float* __restrict__ opw, const float* __restrict__ vpw,
    ushort* __restrict__ Wfull)
{
  const int l = blockIdx.z, h = blockIdx.y;
  const int ct = blockIdx.x & 3, kt = blockIdx.x >> 2;
  __shared__ float Ao[64][33];
  __shared__ float Bo[32][65];
  const int t = threadIdx.x;
  for (int i=t; i<2048; i+=256) {
    const int r = i>>5, j = i&31;
    Ao[r][j] = opw[(size_t)l*65536 + (size_t)(ct*64 + r)*256 + h*32 + j];
  }
  for (int i=t; i<2048; i+=256) {
    const int j = i>>6, kk = i&63;
    Bo[j][kk] = vpw[(size_t)l*65536 + (size_t)(h*32 + j)*256 + kt*64 + kk];
  }
  __syncthreads();
  const int tx = t&15, ty = t>>4;
  float acc[4][4] = {};
  for (int j=0;j<32;++j) {
    float a[4], bv[4];
    #pragma unroll
    for (int r=0;r<4;++r) a[r] = Ao[ty*4+r][j];
    #pragma unroll
    for (int cc=0;cc<4;++cc) bv[cc] = Bo[j][tx*4+cc];
    #pragma unroll
    for (int r=0;r<4;++r)
      #pragma unroll
      for (int cc=0;cc<4;++cc) acc[r][cc] += a[r]*bv[cc];
  }
  #pragma unroll
  for (int r=0;r<4;++r)
    #pragma unroll
    for (int cc=0;cc<4;++cc)
      Wfull[((size_t)l*256 + ct*64+ty*4+r)*KDEF + h*256 + kt*64 + tx*4+cc] = (ushort)f2bf1(acc[r][cc]);
}

__global__ void wcombB_k(const float* __restrict__ opw, const float* __restrict__ vpb,
                         ushort* __restrict__ Wfull)
{
  const int l = blockIdx.x; const int c = threadIdx.x;
  ushort* wr = Wfull + ((size_t)l*256 + c)*KDEF;
  for (int h=0; h<8; ++h) {
    float s = 0.f;
    for (int j=0;j<32;++j) s += opw[(size_t)l*65536 + (size_t)c*256 + h*32+j] * vpb[l*256 + h*32+j];
    wr[2048 + h] = (ushort)f2bf1(s);
  }
  for (int zz=2056; zz<KDEF; ++zz) wr[zz] = 0;
}

// ---------------------------------------------------------------------------
// Fused cls-LN2 + reg3 + cls3 + ref update + output write.
// ---------------------------------------------------------------------------
__global__ __launch_bounds__(256) void regcls3_k(
    const float* __restrict__ rc2,
    const float* __restrict__ lnw, const float* __restrict__ lnb,
    const float* __restrict__ rw3, const float* __restrict__ rb3,
    const float* __restrict__ cw3, const float* __restrict__ cb3,
    float* __restrict__ ref, float* __restrict__ outL)
{
  __shared__ float Wr[10*272];
  __shared__ float Wc[10*272];
  for (int i=threadIdx.x; i<2560; i+=256) {
    const int o = i>>8, k = i&255;
    const int si = o*272 + (k>>6)*68 + (k&63);
    Wr[si] = rw3[i]; Wc[si] = cw3[i];
  }
  __syncthreads();
  const int t = threadIdx.x;
  const int row = t>>3, g = (t>>2)&1, sl = t&3;
  const int R = blockIdx.x*32 + row;
  const bool act = R < ROWS;
  const float* base = rc2 + (size_t)(act?R:0)*512 + g*256 + sl*64;
  float4 v[16];
  #pragma unroll
  for (int jj=0;jj<16;++jj) v[jj] = *(const float4*)(base + 4*jj);
  float s1 = 0.f, s2 = 0.f;
  #pragma unroll
  for (int jj=0;jj<16;++jj) {
    s1 += v[jj].x+v[jj].y+v[jj].z+v[jj].w;
    s2 += v[jj].x*v[jj].x+v[jj].y*v[jj].y+v[jj].z*v[jj].z+v[jj].w*v[jj].w;
  }
  s1 += __shfl_xor(s1,1); s1 += __shfl_xor(s1,2);
  s2 += __shfl_xor(s2,1); s2 += __shfl_xor(s2,2);
  if (g) {
    const float mean = s1*(1.0f/256.0f);
    const float var = s2*(1.0f/256.0f) - mean*mean;
    const float rs = rsqrtf(var + 1e-5f);
    #pragma unroll
    for (int jj=0;jj<16;++jj) {
      const float4 w4 = *(const float4*)(lnw + sl*64 + 4*jj);
      const float4 b4 = *(const float4*)(lnb + sl*64 + 4*jj);
      v[jj].x = fmaxf((v[jj].x-mean)*rs*w4.x + b4.x, 0.f);
      v[jj].y = fmaxf((v[jj].y-mean)*rs*w4.y + b4.y, 0.f);
      v[jj].z = fmaxf((v[jj].z-mean)*rs*w4.z + b4.z, 0.f);
      v[jj].w = fmaxf((v[jj].w-mean)*rs*w4.w + b4.w, 0.f);
    }
  }
  const float* Wg = g ? Wc : Wr;
  float acc[10] = {};
  #pragma unroll
  for (int jj=0;jj<16;++jj) {
    #pragma unroll
    for (int o=0;o<10;++o) {
      const float4 w = *(const float4*)&Wg[o*272 + sl*68 + 4*jj];
      acc[o] += v[jj].x*w.x + v[jj].y*w.y + v[jj].z*w.z + v[jj].w*w.w;
    }
  }
  #pragma unroll
  for (int o=0;o<10;++o) {
    acc[o] += __shfl_xor(acc[o], 1);
    acc[o] += __shfl_xor(acc[o], 2);
  }
  if (act && sl == 0) {
    if (g) {
      float* oc = outL + (size_t)R*20;
      #pragma unroll
      for (int o=0;o<10;++o) oc[o] = acc[o] + cb3[o];
    } else {
      float tt[10];
      #pragma unroll
      for (int o=0;o<10;++o) tt[o] = acc[o] + rb3[o];
      const float rx = invsigf_(ref[R*3+0]);
      const float ry = invsigf_(ref[R*3+1]);
      const float rz = invsigf_(ref[R*3+2]);
      const float nx = sigmoidf_(tt[0]+rx);
      const float ny = sigmoidf_(tt[1]+ry);
      const float nz = sigmoidf_(tt[4]+rz);
      ref[R*3+0]=nx; ref[R*3+1]=ny; ref[R*3+2]=nz;
      float* o = outL + (size_t)R*20 + 10;
      o[0]=nx*102.4f-51.2f; o[1]=ny*102.4f-51.2f; o[2]=tt[2]; o[3]=tt[3];
      o[4]=nz*8.0f-5.0f; o[5]=tt[5]; o[6]=tt[6]; o[7]=tt[7]; o[8]=tt[8]; o[9]=tt[9];
    }
  }
}

__global__ void init_k(const float* __restrict__ qe, float* __restrict__ qpos,
                       float* __restrict__ q, ushort* __restrict__ qb, ushort* __restrict__ qpb)
{
  const int t = blockIdx.x*blockDim.x + threadIdx.x;
  const int row = t >> 6; const int cc = (t & 63) << 2;
  const int n = row % NQQ;
  const float4 vp = *(const float4*)(qe + (size_t)n*512 + cc);
  const float4 vq = *(const float4*)(qe + (size_t)n*512 + 256 + cc);
  *(float4*)(qpos + (size_t)row*256 + cc) = vp;
  *(float4*)(q    + (size_t)row*256 + cc) = vq;
  *(ushort4*)(qb  + (size_t)row*256 + cc) = pk4(vq);
  float4 s; s.x=vq.x+vp.x; s.y=vq.y+vp.y; s.z=vq.z+vp.z; s.w=vq.w+vp.w;
  *(ushort4*)(qpb + (size_t)row*256 + cc) = pk4(s);
}

__global__ void prep_k(const float* __restrict__ ow, const float* __restrict__ ob,
                       const float* __restrict__ aw, const float* __restrict__ ab,
                       const float* __restrict__ rw, const float* __restrict__ rb,
                       const float* __restrict__ cw, const float* __restrict__ cb,
                       ushort* cwAb, float* cbA, ushort* cwBb, float* cbB)
{
  const int i = blockIdx.x*blockDim.x + threadIdx.x;
  if (i < 6*96*256) {
    const int l = i/(96*256), r = (i/256)%96, k = i%256;
    const float v = (r<64) ? ow[((size_t)l*64 + r)*256 + k] : aw[((size_t)l*32 + (r-64))*256 + k];
    cwAb[i] = (ushort)f2bf1(v);
  }
  if (i < 576) { const int l = i/96, r = i%96; cbA[i] = (r<64) ? ob[l*64+r] : ab[l*32 + r-64]; }
  if (i < 6*512*256) {
    const int l = i/(512*256), r = (i/256)%512, k = i%256;
    const float v = (r<256) ? rw[((size_t)l*256+r)*256+k] : cw[((size_t)l*256 + (r-256))*256 + k];
    cwBb[i] = (ushort)f2bf1(v);
  }
  if (i < 3072) { const int l = i/512, r = i%512; cbB[i] = (r<256) ? rb[l*256+r] : cb[l*256 + r-256]; }
}

__global__ void cvtw_k(const float* __restrict__ s1, const float* __restrict__ s2,
                       const float* __restrict__ s3, const float* __restrict__ s4,
                       const float* __restrict__ s5, const float* __restrict__ s6,
                       const float* __restrict__ s7, ushort* __restrict__ dst)
{
  const int i4 = (blockIdx.x*256 + threadIdx.x)*4;
  if (i4 >= 4325376) return;
  const float* src; int lo;
  if      (i4 < 1179648) { src=s1; lo=i4; }
  else if (i4 < 1572864) { src=s2; lo=i4-1179648; }
  else if (i4 < 1966080) { src=s3; lo=i4-1572864; }
  else if (i4 < 2752512) { src=s4; lo=i4-1966080; }
  else if (i4 < 3538944) { src=s5; lo=i4-2752512; }
  else if (i4 < 3932160) { src=s6; lo=i4-3538944; }
  else                   { src=s7; lo=i4-3932160; }
  const float4 v = *(const float4*)(src+lo);
  *(ushort4*)(dst+i4) = pk4(v);
}

__global__ void cvtbev_k(const float* __restrict__ bev, ushort* __restrict__ bevb)
{
  const size_t i = ((size_t)blockIdx.x*256 + threadIdx.x)*8;
  const float4 a = *(const float4*)(bev+i);
  const float4 b = *(const float4*)(bev+i+4);
  *(ushort4*)(bevb+i)   = pk4(a);
  *(ushort4*)(bevb+i+4) = pk4(b);
}

extern "C" void kernel_launch(void* const* d_in, const int* in_sizes, int n_in,
                              void* d_out, int out_size, void* d_ws, size_t ws_size,
                              hipStream_t stream)
{
  const float* bev      = (const float*)d_in[0];
  const float* qe       = (const float*)d_in[1];
  const float* ref_w    = (const float*)d_in[2];
  const float* ref_b    = (const float*)d_in[3];
  const float* sa_in_w  = (const float*)d_in[4];
  const float* sa_in_b  = (const float*)d_in[5];
  const float* sa_out_w = (const float*)d_in[6];
  const float* sa_out_b = (const float*)d_in[7];
  const float* ln_w     = (const float*)d_in[8];
  const float* ln_b     = (const float*)d_in[9];
  const float* off_w    = (const float*)d_in[10];
  const float* off_b    = (const float*)d_in[11];
  const float* aw_w     = (const float*)d_in[12];
  const float* aw_b     = (const float*)d_in[13];
  const float* vproj_w  = (const float*)d_in[14];
  const float* vproj_b  = (const float*)d_in[15];
  const float* oproj_w  = (const float*)d_in[16];
  const float* oproj_b  = (const float*)d_in[17];
  const float* ffn_w1   = (const float*)d_in[18];
  const float* ffn_b1   = (const float*)d_in[19];
  const float* ffn_w2   = (const float*)d_in[20];
  const float* ffn_b2   = (const float*)d_in[21];
  const float* reg_w1   = (const float*)d_in[22];
  const float* reg_b1   = (const float*)d_in[23];
  const float* reg_w2   = (const float*)d_in[24];
  const float* reg_b2   = (const float*)d_in[25];
  const float* reg_w3   = (const float*)d_in[26];
  const float* reg_b3   = (const float*)d_in[27];
  const float* cls_w1   = (const float*)d_in[28];
  const float* cls_b1   = (const float*)d_in[29];
  const float* cls_w2   = (const float*)d_in[30];
  const float* cls_b2   = (const float*)d_in[31];
  const float* cls_w3   = (const float*)d_in[32];
  const float* cls_b3   = (const float*)d_in[33];
  const float* cls_ln_w = (const float*)d_in[34];
  const float* cls_ln_b = (const float*)d_in[35];
  float* out = (float*)d_out;

  float* ws    = (float*)d_ws;
  float* qpos  = ws;                    // 921600
  float* q     = qpos + 921600;
  float* tA    = q    + 921600;
  float* tB    = tA   + 921600;
  float* rc2   = tB   + 921600;         // 1843200
  float* cls1f = rc2  + 1843200;        // 921600
  float* offaw = cls1f+ 921600;         // 345600
  float* ref   = offaw+ 345600;         // 10800
  float* cbA   = ref  + 10800;          // 576
  float* cbB   = cbA  + 576;            // 3072
  // ushort region (16B aligned)
  ushort* usb  = (ushort*)(ws + 6811248);
  // aliased block: rr overlays per-layer transients (all dead during deform)
  ushort* rr   = usb;                   // 7488000 = 3600*2080
  ushort* QKb  = usb;                   // 1843200
  ushort* Vb   = usb + 1843200;         // 921600
  ushort* tAb  = usb + 2764800;         // 921600
  ushort* W5b  = usb + 3686400;         // 1843200
  ushort* clsb = usb + 5529600;         // 921600
  ushort* regb = usb + 6451200;         // 921600 (+115200 pad)
  ushort* qb   = usb + 7488000;         // 921600
  ushort* qpb  = usb + 8409600;         // 921600
  ushort* bevb = usb + 9331200;         // 40960000
  ushort* wbf  = usb + 50291200;        // 5259264
  ushort* siwb = wbf;                   // 1179648
  ushort* sowb = wbf + 1179648;         // 393216
  ushort* f1wb = wbf + 1966080;         // 786432
  ushort* f2wb = wbf + 2752512;         // 786432
  ushort* r2wb = wbf + 3538944;         // 393216
  ushort* c2wb = wbf + 3932160;         // 393216
  ushort* cwAb = wbf + 4325376;         // 147456
  ushort* cwBb = wbf + 4472832;         // 786432
  ushort* Wfull= wbf + 5259264;         // 3194880 = 6*256*2080

  auto G = [&](int BM, const ushort* A0, const ushort* A1, int NA, int lda,
               const ushort* W0, const ushort* W1, int NW,
               const float* B0, const float* B1, int NB,
               void* Y0, int ldy0, int obf0,
               void* Y1, int ldy1, int obf1, int NY,
               int M, int N, int K, int reluN) {
    dim3 grid((M+BM-1)/BM, (N+63)/64);
    if (BM==64)
      gemmb_k<64><<<grid, 256, 0, stream>>>(A0,A1,NA,lda,W0,W1,NW,B0,B1,NB,
                                            Y0,ldy0,obf0,Y1,ldy1,obf1,NY,M,N,K,reluN);
    else
      gemmb_k<32><<<grid, 256, 0, stream>>>(A0,A1,NA,lda,W0,W1,NW,B0,B1,NB,
                                            Y0,ldy0,obf0,Y1,ldy1,obf1,NY,M,N,K,reluN);
  };

  // one-time converts + prep
  cvtbev_k<<<20000, 256, 0, stream>>>(bev, bevb);
  cvtw_k<<<4224, 256, 0, stream>>>(sa_in_w, sa_out_w, oproj_w, ffn_w1, ffn_w2, reg_w2, cls_w2, wbf);
  prep_k<<<3072, 256, 0, stream>>>(off_w, off_b, aw_w, aw_b, reg_w1, reg_b1, cls_w1, cls_b1,
                                   cwAb, cbA, cwBb, cbB);
  wcomb_k<<<dim3(16,8,6), 256, 0, stream>>>(oproj_w, vproj_w, Wfull);
  wcombB_k<<<6, 256, 0, stream>>>(oproj_w, vproj_b, Wfull);
  init_k<<<900, 256, 0, stream>>>(qe, qpos, q, qb, qpb);
  {
    dim3 grid((ROWS+63)/64, 1);
    gemm_k<<<grid, 256, 0, stream>>>(qpos, 256, ref_w, ref_b, ref, ROWS, 3, 256, 3, 2);
  }

  for (int i=0;i<NLAYER;++i) {
    const float* sib = sa_in_b + (size_t)i*768;
    const ushort* siw = siwb + (size_t)i*196608;
    // ---- self-attention: fused QKV ----
    G(64, qpb, qb, 512, 256, siw, siw, BIGN, sib, sib, BIGN,
      QKb, 512, 1, Vb, 256, 1, 512, ROWS, 768, 256, 0);
    attn3_k<<<dim3(32,15), 256, 0, stream>>>(QKb, Vb, tAb);
    G(32, tAb, tAb, BIGN, 256, sowb + (size_t)i*65536, nullptr, BIGN,
      sa_out_b + (size_t)i*256, nullptr, BIGN,
      tB, 256, 0, nullptr, 0, 0, BIGN, ROWS, 256, 256, 0);
    ln_k<<<900, 256, 0, stream>>>(tB, 256, q, ln_w + (size_t)(i*3+0)*256, ln_b + (size_t)(i*3+0)*256,
                                  q, nullptr, qpos, qpb, 0);
    // ---- deformable cross-attention (gather + fused Wcomb gemm) ----
    G(32, qpb, qpb, BIGN, 256, cwAb + (size_t)i*24576, nullptr, BIGN,
      cbA + i*96, nullptr, BIGN,
      offaw, 96, 0, nullptr, 0, 0, BIGN, ROWS, 96, 256, 0);
    gather_k<<<ROWS, 512, 0, stream>>>(bevb, offaw, ref, rr);
    G(32, rr, rr, BIGN, KDEF, Wfull + (size_t)i*256*KDEF, nullptr, BIGN,
      oproj_b + (size_t)i*256, nullptr, BIGN,
      tA, 256, 0, nullptr, 0, 0, BIGN, ROWS, 256, KDEF, 0);
    ln_k<<<900, 256, 0, stream>>>(tA, 256, q, ln_w + (size_t)(i*3+1)*256, ln_b + (size_t)(i*3+1)*256,
                                  q, qb, nullptr, nullptr, 0);
    // ---- FFN ----
    G(64, qb, qb, BIGN, 256, f1wb + (size_t)i*131072, nullptr, BIGN,
      ffn_b1 + (size_t)i*512, nullptr, BIGN,
      W5b, 512, 1, nullptr, 0, 0, BIGN, ROWS, 512, 256, 512);
    G(32, W5b, W5b, BIGN, 512, f2wb + (size_t)i*131072, nullptr, BIGN,
      ffn_b2 + (size_t)i*256, nullptr, BIGN,
      tA, 256, 0, nullptr, 0, 0, BIGN, ROWS, 256, 512, 0);
    ln_k<<<900, 256, 0, stream>>>(tA, 256, q, ln_w + (size_t)(i*3+2)*256, ln_b + (size_t)(i*3+2)*256,
                                  q, qb, qpos, qpb, 0);
    // ---- reg1|cls1 dual-output ----
    G(64, qb, qb, BIGN, 256, cwBb + (size_t)i*131072, nullptr, BIGN,
      cbB + i*512, nullptr, BIGN,
      regb, 256, 1, cls1f, 256, 0, 256, ROWS, 512, 256, 256);
    ln_k<<<900, 256, 0, stream>>>(cls1f, 256, nullptr,
                                  cls_ln_w + (size_t)(i*2+0)*256, cls_ln_b + (size_t)(i*2+0)*256,
                                  nullptr, clsb, nullptr, nullptr, 1);
    // ---- reg2|cls2 merged ----
    G(64, regb, clsb, 256, 256,
      r2wb + (size_t)i*65536, c2wb + (size_t)i*65536, 256,
      reg_b2 + (size_t)i*256, cls_b2 + (size_t)i*256, 256,
      rc2, 512, 0, nullptr, 0, 0, BIGN, ROWS, 512, 256, 256);
    // ---- fused clsLN2 + reg3 + cls3 + refupdate + output ----
    regcls3_k<<<(ROWS+31)/32, 256, 0, stream>>>(rc2,
        cls_ln_w + (size_t)(i*2+1)*256, cls_ln_b + (size_t)(i*2+1)*256,
        reg_w3 + (size_t)i*2560, reg_b3 + (size_t)i*10,
        cls_w3 + (size_t)i*2560, cls_b3 + (size_t)i*10,
        ref, out + (size_t)i*ROWS*20);
  }
}